// Round 1
// baseline (3799.774 us; speedup 1.0000x reference)
//
#include <hip/hip_runtime.h>
#include <hip/hip_bf16.h>

// SpatialNCA, MI355X. R9: replace the 4x recompute chain with staged raw
// activations in workspace (t1/t2/t3 pre-BN, BN affine applied at load from
// the previous launch's stats). t1/t3 alias => 2 staging buffers. Runtime
// dispatch on ws_size: f32 staging (>=~540MB) > bf16 staging (>=~284MB) >
// legacy recompute chain (unchanged fallback). Same 63-trace fail-closed
// diagnostics, same stats layout, same k_scale/k_upd/k_final epilogue.

#define EMBD 128
#define TE 32
#define KC 32
#define BN_EPS 1e-5f

typedef unsigned int u32;
typedef unsigned short u16;

__device__ __forceinline__ bool finitef(float f) {
    union { float f; u32 i; } v; v.f = f;
    return ((v.i >> 23) & 0xFFu) != 0xFFu;
}
__device__ __forceinline__ float sane(float f, float lim) {
    if (!finitef(f)) return 0.f;
    return fminf(fmaxf(f, -lim), lim);
}
__device__ __forceinline__ void trace_mark(float* tp, float bit) {
    if (blockIdx.x == 0 && threadIdx.x == 0) atomicAdd(tp, bit);
}

// ------------------------------------------------- staging-type helpers
struct bf4 { u16 x, y, z, w; };

__device__ __forceinline__ float4 ld4s(const float* p) { return *(const float4*)p; }
__device__ __forceinline__ void st4s(float* p, float4 v) { *(float4*)p = v; }

__device__ __forceinline__ float bf2f(u16 b) {
    union { u32 i; float f; } v; v.i = (u32)b << 16; return v.f;
}
__device__ __forceinline__ u16 f2bf(float f) {
    union { float f; u32 i; } v; v.f = f;
    u32 r = v.i + 0x7FFFu + ((v.i >> 16) & 1u);   // RNE
    return (u16)(r >> 16);
}
__device__ __forceinline__ float4 ld4s(const u16* p) {
    bf4 b = *(const bf4*)p;
    return make_float4(bf2f(b.x), bf2f(b.y), bf2f(b.z), bf2f(b.w));
}
__device__ __forceinline__ void st4s(u16* p, float4 v) {
    bf4 b; b.x = f2bf(v.x); b.y = f2bf(v.y); b.z = f2bf(v.z); b.w = f2bf(v.w);
    *(bf4*)p = b;
}

// ---------------------------------------------------------------- sentinel
__global__ __launch_bounds__(256) void k_fill(float* out, float val, int n) {
    int i = blockIdx.x * 256 + threadIdx.x;
    if (i < n) out[i] = val;
}

#define STAGE_W(WPTR, K0) { \
        const float* wp = (WPTR) + (size_t)((K0) + kw) * EMBD + cw; \
        float4 wa = *(const float4*)wp; \
        float4 wb = *(const float4*)(wp + 4); \
        float4 wc = *(const float4*)(wp + 8); \
        float4 wdv = *(const float4*)(wp + 12); \
        float* wd = &Ws[kw][cw]; \
        *(float4*)(wd + 0) = wa; *(float4*)(wd + 4) = wb; \
        *(float4*)(wd + 8) = wc; *(float4*)(wd + 12) = wdv; }

// =============================================================== staged g1
// t1_raw = [h_i, h_j, dist] @ W1 ; stats1 atomics ; cnt atomics ; store t1.
template<typename ST>
__global__ __launch_bounds__(256) void k_g1(
    const float* h, const float* pos, const int* srcI, const int* dstI,
    const float* W1, float* stats_out, float* cnt, ST* t1,
    float* trace, float bit, int E, int Nn)
{
    trace_mark(trace, bit);

    __shared__ float XsT[KC][TE];
    __shared__ float Ws[KC][EMBD];
    __shared__ float part_s[8][EMBD];
    __shared__ float part_q[8][EMBD];
    __shared__ int dst_s[TE];
    __shared__ int src_s[TE];
    __shared__ float dist_s[TE];

    const int tid = threadIdx.x;
    const int r0 = blockIdx.x * TE;
    int valid = E - r0; if (valid > TE) valid = TE;

    if (tid < TE) {
        int e = r0 + tid; bool v = tid < valid; if (e >= E) e = E - 1;
        int dj = srcI[e], di = dstI[e];
        if ((u32)dj >= (u32)Nn) dj = 0;
        if ((u32)di >= (u32)Nn) di = 0;
        dst_s[tid] = di; src_s[tid] = dj;
        float2 pj = *(const float2*)(pos + (size_t)dj * 2);
        float2 pi = *(const float2*)(pos + (size_t)di * 2);
        float dx = pj.x - pi.x, dy = pj.y - pi.y;
        dist_s[tid] = sqrtf(dx * dx + dy * dy);
        if (v) atomicAdd(&cnt[di], 1.0f);
    }
    __syncthreads();

    const int e_st = tid >> 3, kl = (tid & 7) << 2;
    const int kw = tid >> 3, cw = (tid & 7) << 4;
    const int e4 = (tid >> 5) << 2, c4 = (tid & 31) << 2;
    const int grp = tid >> 5;

    float acc[4][4];
#pragma unroll
    for (int i = 0; i < 4; ++i)
#pragma unroll
        for (int j = 0; j < 4; ++j) acc[i][j] = 0.f;

    for (int k0 = 0; k0 < 2 * EMBD; k0 += KC) {
        {
            float4 x = make_float4(0.f, 0.f, 0.f, 0.f);
            if (e_st < valid) {
                int k = k0 + kl;
                const float* base = (k < EMBD)
                    ? h + (size_t)dst_s[e_st] * EMBD + k
                    : h + (size_t)src_s[e_st] * EMBD + (k - EMBD);
                x = *(const float4*)base;
            }
            XsT[kl + 0][e_st] = x.x; XsT[kl + 1][e_st] = x.y;
            XsT[kl + 2][e_st] = x.z; XsT[kl + 3][e_st] = x.w;
        }
        STAGE_W(W1, k0);
        __syncthreads();
#pragma unroll 8
        for (int kk = 0; kk < KC; ++kk) {
            float4 xv4 = *(const float4*)&XsT[kk][e4];
            float4 wv4 = *(const float4*)&Ws[kk][c4];
            float xv[4] = {xv4.x, xv4.y, xv4.z, xv4.w};
            float wv[4] = {wv4.x, wv4.y, wv4.z, wv4.w};
#pragma unroll
            for (int i = 0; i < 4; ++i)
#pragma unroll
                for (int j = 0; j < 4; ++j) acc[i][j] = fmaf(xv[i], wv[j], acc[i][j]);
        }
        __syncthreads();
    }
    {   // dist column (row 256 of W1)
        float4 wd = *(const float4*)(W1 + (size_t)(2 * EMBD) * EMBD + c4);
        float wdv[4] = {wd.x, wd.y, wd.z, wd.w};
#pragma unroll
        for (int i = 0; i < 4; ++i) {
            float d = dist_s[e4 + i];
#pragma unroll
            for (int j = 0; j < 4; ++j) acc[i][j] = fmaf(d, wdv[j], acc[i][j]);
        }
    }

    // stats
    __syncthreads();
#pragma unroll
    for (int j = 0; j < 4; ++j) {
        float s = 0.f, q = 0.f;
#pragma unroll
        for (int i = 0; i < 4; ++i)
            if (e4 + i < valid) { float a = acc[i][j]; s += a; q += a * a; }
        part_s[grp][c4 + j] = s; part_q[grp][c4 + j] = q;
    }
    __syncthreads();
    if (tid < EMBD) {
        float S = 0.f, Q = 0.f;
        for (int g = 0; g < 8; ++g) { S += part_s[g][tid]; Q += part_q[g][tid]; }
        atomicAdd(&stats_out[tid], S);
        atomicAdd(&stats_out[EMBD + tid], Q);
    }

    // store raw t1
#pragma unroll
    for (int i = 0; i < 4; ++i)
        if (e4 + i < valid)
            st4s(t1 + (size_t)(r0 + e4 + i) * EMBD + c4,
                 make_float4(acc[i][0], acc[i][1], acc[i][2], acc[i][3]));
}

// ============================================================= staged mid
// tout_raw = relu(bn(tin_raw; stats_base)) @ W ; stats atomics ; optional
// h_aggr scatter of the post-BN input values (each loaded exactly once).
template<typename ST>
__global__ __launch_bounds__(256) void k_gmid(
    const ST* tin, const float* W, const float* g1, const float* b1,
    const float* stats_base, float* stats_out,
    const int* dstI, float* h_aggr, int do_aggr,
    ST* tout, float* trace, float bit, int E, int Nn)
{
    trace_mark(trace, bit);

    __shared__ float XsT[KC][TE];
    __shared__ float Ws[KC][EMBD];
    __shared__ float part_s[8][EMBD];
    __shared__ float part_q[8][EMBD];
    __shared__ float sA_s[EMBD], sA_c[EMBD];
    __shared__ int dst_s[TE];

    const int tid = threadIdx.x;
    const int r0 = blockIdx.x * TE;
    int valid = E - r0; if (valid > TE) valid = TE;

    if (tid < EMBD) {
        const float invE = 1.f / (float)E;
        float m = stats_base[tid] * invE;
        float v = fmaxf(stats_base[EMBD + tid] * invE - m * m, 0.f);
        float s = g1[tid] * rsqrtf(v + BN_EPS);
        sA_s[tid] = s; sA_c[tid] = b1[tid] - m * s;
    }
    if (do_aggr && tid < TE) {
        int e = r0 + tid; if (e >= E) e = E - 1;
        int di = dstI[e];
        if ((u32)di >= (u32)Nn) di = 0;
        dst_s[tid] = di;
    }
    __syncthreads();

    const int e_st = tid >> 3, kl = (tid & 7) << 2;
    const int kw = tid >> 3, cw = (tid & 7) << 4;
    const int e4 = (tid >> 5) << 2, c4 = (tid & 31) << 2;
    const int grp = tid >> 5;

    float acc[4][4];
#pragma unroll
    for (int i = 0; i < 4; ++i)
#pragma unroll
        for (int j = 0; j < 4; ++j) acc[i][j] = 0.f;

    for (int k0 = 0; k0 < EMBD; k0 += KC) {
        {
            int e = r0 + e_st; if (e >= E) e = E - 1;
            int k = k0 + kl;
            float4 x = ld4s(tin + (size_t)e * EMBD + k);
            float v0 = fmaxf(fmaf(x.x, sA_s[k + 0], sA_c[k + 0]), 0.f);
            float v1 = fmaxf(fmaf(x.y, sA_s[k + 1], sA_c[k + 1]), 0.f);
            float v2 = fmaxf(fmaf(x.z, sA_s[k + 2], sA_c[k + 2]), 0.f);
            float v3 = fmaxf(fmaf(x.w, sA_s[k + 3], sA_c[k + 3]), 0.f);
            if (do_aggr && e_st < valid) {
                float* hp = h_aggr + (size_t)dst_s[e_st] * EMBD + k;
                atomicAdd(hp + 0, v0); atomicAdd(hp + 1, v1);
                atomicAdd(hp + 2, v2); atomicAdd(hp + 3, v3);
            }
            XsT[kl + 0][e_st] = v0; XsT[kl + 1][e_st] = v1;
            XsT[kl + 2][e_st] = v2; XsT[kl + 3][e_st] = v3;
        }
        STAGE_W(W, k0);
        __syncthreads();
#pragma unroll 8
        for (int kk = 0; kk < KC; ++kk) {
            float4 xv4 = *(const float4*)&XsT[kk][e4];
            float4 wv4 = *(const float4*)&Ws[kk][c4];
            float xv[4] = {xv4.x, xv4.y, xv4.z, xv4.w};
            float wv[4] = {wv4.x, wv4.y, wv4.z, wv4.w};
#pragma unroll
            for (int i = 0; i < 4; ++i)
#pragma unroll
                for (int j = 0; j < 4; ++j) acc[i][j] = fmaf(xv[i], wv[j], acc[i][j]);
        }
        __syncthreads();
    }

    // stats
    __syncthreads();
#pragma unroll
    for (int j = 0; j < 4; ++j) {
        float s = 0.f, q = 0.f;
#pragma unroll
        for (int i = 0; i < 4; ++i)
            if (e4 + i < valid) { float a = acc[i][j]; s += a; q += a * a; }
        part_s[grp][c4 + j] = s; part_q[grp][c4 + j] = q;
    }
    __syncthreads();
    if (tid < EMBD) {
        float S = 0.f, Q = 0.f;
        for (int g = 0; g < 8; ++g) { S += part_s[g][tid]; Q += part_q[g][tid]; }
        atomicAdd(&stats_out[tid], S);
        atomicAdd(&stats_out[EMBD + tid], Q);
    }

    // store raw tout
#pragma unroll
    for (int i = 0; i < 4; ++i)
        if (e4 + i < valid)
            st4s(tout + (size_t)(r0 + e4 + i) * EMBD + c4,
                 make_float4(acc[i][0], acc[i][1], acc[i][2], acc[i][3]));
}

// ============================================================== staged dot
// t4 = relu(bn(t3_raw; stats_base)) . Wp2 ; scalar stats atomics.
template<typename ST>
__global__ __launch_bounds__(256) void k_dot(
    const ST* t3, const float* Wp2, const float* g3, const float* b3,
    const float* stats_base, float* stats_out, float* t4,
    float* trace, float bit, int E)
{
    trace_mark(trace, bit);

    __shared__ float sC_s[EMBD], sC_c[EMBD];
    __shared__ float red[256];
    __shared__ float dotbuf[TE];

    const int tid = threadIdx.x;
    const int r0 = blockIdx.x * TE;
    int valid = E - r0; if (valid > TE) valid = TE;

    if (tid < EMBD) {
        const float invE = 1.f / (float)E;
        float m = stats_base[tid] * invE;
        float v = fmaxf(stats_base[EMBD + tid] * invE - m * m, 0.f);
        float s = g3[tid] * rsqrtf(v + BN_EPS);
        sC_s[tid] = s; sC_c[tid] = b3[tid] - m * s;
    }
    __syncthreads();

    const int row = tid >> 3, c0 = (tid & 7) << 4;
    int e = r0 + row; if (e >= E) e = E - 1;
    const ST* tp = t3 + (size_t)e * EMBD + c0;

    float part = 0.f;
#pragma unroll
    for (int q = 0; q < 4; ++q) {
        float4 x = ld4s(tp + q * 4);
        float4 w = *(const float4*)(Wp2 + c0 + q * 4);
        int c = c0 + q * 4;
        part = fmaf(fmaxf(fmaf(x.x, sC_s[c + 0], sC_c[c + 0]), 0.f), w.x, part);
        part = fmaf(fmaxf(fmaf(x.y, sC_s[c + 1], sC_c[c + 1]), 0.f), w.y, part);
        part = fmaf(fmaxf(fmaf(x.z, sC_s[c + 2], sC_c[c + 2]), 0.f), w.z, part);
        part = fmaf(fmaxf(fmaf(x.w, sC_s[c + 3], sC_c[c + 3]), 0.f), w.w, part);
    }
    red[tid] = part;
    __syncthreads();
    if ((tid & 7) == 0) {
        float dot = red[tid] + red[tid+1] + red[tid+2] + red[tid+3]
                  + red[tid+4] + red[tid+5] + red[tid+6] + red[tid+7];
        dotbuf[row] = dot;
        if (row < valid) t4[r0 + row] = dot;
    }
    __syncthreads();
    if (tid == 0) {
        float S = 0.f, Q = 0.f;
        for (int r = 0; r < valid; ++r) { float d = dotbuf[r]; S += d; Q += d * d; }
        atomicAdd(&stats_out[0], S);
        atomicAdd(&stats_out[EMBD], Q);
    }
}

// =============================================================== chain kernel
// LEGACY FALLBACK (small workspace). Unchanged from R8.
__global__ __launch_bounds__(256) void k_chain(
    const float* h, const float* pos, const int* srcI, const int* dstI,
    const float* W1, const float* W2, const float* W3, const float* Wp2,
    const float* g1, const float* b1, const float* g2, const float* b2,
    const float* g3, const float* b3,
    const float* stats_base, float* stats_out,
    float* cnt, float* h_aggr, float* t4_out,
    float* trace, float bit, int depth, int E, int Nn)
{
    trace_mark(trace, bit);

    __shared__ float XsT[KC][TE];
    __shared__ float Ws[KC][EMBD];
    __shared__ float A[TE][EMBD + 4];
    __shared__ float part_s[8][EMBD];
    __shared__ float part_q[8][EMBD];
    __shared__ float red[256];
    __shared__ float dotbuf[TE];
    __shared__ float sA_s[EMBD], sA_c[EMBD];
    __shared__ float sB_s[EMBD], sB_c[EMBD];
    __shared__ float sC_s[EMBD], sC_c[EMBD];
    __shared__ int dst_s[TE];
    __shared__ int src_s[TE];
    __shared__ float dist_s[TE];

    const int tid = threadIdx.x;
    const int r0 = blockIdx.x * TE;
    int valid = E - r0; if (valid > TE) valid = TE;

    if (depth >= 2 && tid < EMBD) {
        const float invE = 1.f / (float)E;
        float m = stats_base[tid] * invE;
        float v = fmaxf(stats_base[EMBD + tid] * invE - m * m, 0.f);
        float s = g1[tid] * rsqrtf(v + BN_EPS);
        sA_s[tid] = s; sA_c[tid] = b1[tid] - m * s;
        if (depth >= 3) {
            m = stats_base[256 + tid] * invE;
            v = fmaxf(stats_base[256 + EMBD + tid] * invE - m * m, 0.f);
            s = g2[tid] * rsqrtf(v + BN_EPS);
            sB_s[tid] = s; sB_c[tid] = b2[tid] - m * s;
        }
        if (depth >= 4) {
            m = stats_base[512 + tid] * invE;
            v = fmaxf(stats_base[512 + EMBD + tid] * invE - m * m, 0.f);
            s = g3[tid] * rsqrtf(v + BN_EPS);
            sC_s[tid] = s; sC_c[tid] = b3[tid] - m * s;
        }
    }

    if (tid < TE) {
        int e = r0 + tid; bool v = tid < valid; if (e >= E) e = E - 1;
        int dj = srcI[e], di = dstI[e];
        if ((u32)dj >= (u32)Nn) dj = 0;
        if ((u32)di >= (u32)Nn) di = 0;
        dst_s[tid] = di; src_s[tid] = dj;
        float2 pj = *(const float2*)(pos + (size_t)dj * 2);
        float2 pi = *(const float2*)(pos + (size_t)di * 2);
        float dx = pj.x - pi.x, dy = pj.y - pi.y;
        dist_s[tid] = sqrtf(dx * dx + dy * dy);
        if (depth == 1 && v) atomicAdd(&cnt[di], 1.0f);
    }
    __syncthreads();

    const int e_st = tid >> 3, kl = (tid & 7) << 2;
    const int kw = tid >> 3, cw = (tid & 7) << 4;
    const int e4 = (tid >> 5) << 2, c4 = (tid & 31) << 2;
    const int grp = tid >> 5;

    float acc[4][4];
#pragma unroll
    for (int i = 0; i < 4; ++i)
#pragma unroll
        for (int j = 0; j < 4; ++j) acc[i][j] = 0.f;

    // ---------------- GEMM1: t1 = [h_i, h_j] @ W1 (+dist col) ----------
    for (int k0 = 0; k0 < 2 * EMBD; k0 += KC) {
        {
            float4 x = make_float4(0.f, 0.f, 0.f, 0.f);
            if (e_st < valid) {
                int k = k0 + kl;
                const float* base = (k < EMBD)
                    ? h + (size_t)dst_s[e_st] * EMBD + k
                    : h + (size_t)src_s[e_st] * EMBD + (k - EMBD);
                x = *(const float4*)base;
            }
            XsT[kl + 0][e_st] = x.x; XsT[kl + 1][e_st] = x.y;
            XsT[kl + 2][e_st] = x.z; XsT[kl + 3][e_st] = x.w;
        }
        STAGE_W(W1, k0);
        __syncthreads();
#pragma unroll 8
        for (int kk = 0; kk < KC; ++kk) {
            float4 xv4 = *(const float4*)&XsT[kk][e4];
            float4 wv4 = *(const float4*)&Ws[kk][c4];
            float xv[4] = {xv4.x, xv4.y, xv4.z, xv4.w};
            float wv[4] = {wv4.x, wv4.y, wv4.z, wv4.w};
#pragma unroll
            for (int i = 0; i < 4; ++i)
#pragma unroll
                for (int j = 0; j < 4; ++j) acc[i][j] = fmaf(xv[i], wv[j], acc[i][j]);
        }
        __syncthreads();
    }
    {   // dist column (row 256 of W1)
        float4 wd = *(const float4*)(W1 + (size_t)(2 * EMBD) * EMBD + c4);
        float wdv[4] = {wd.x, wd.y, wd.z, wd.w};
#pragma unroll
        for (int i = 0; i < 4; ++i) {
            float d = dist_s[e4 + i];
#pragma unroll
            for (int j = 0; j < 4; ++j) acc[i][j] = fmaf(d, wdv[j], acc[i][j]);
        }
    }

#define STATS_128() { \
        __syncthreads(); \
        for (int j = 0; j < 4; ++j) { \
            float s = 0.f, q = 0.f; \
            for (int i = 0; i < 4; ++i) \
                if (e4 + i < valid) { float a = acc[i][j]; s += a; q += a * a; } \
            part_s[grp][c4 + j] = s; part_q[grp][c4 + j] = q; \
        } \
        __syncthreads(); \
        if (tid < EMBD) { \
            float S = 0.f, Q = 0.f; \
            for (int g = 0; g < 8; ++g) { S += part_s[g][tid]; Q += part_q[g][tid]; } \
            atomicAdd(&stats_out[tid], S); \
            atomicAdd(&stats_out[EMBD + tid], Q); } }

    if (depth == 1) { STATS_128(); return; }

#pragma unroll
    for (int i = 0; i < 4; ++i) {
        float4 o;
#pragma unroll
        for (int j = 0; j < 4; ++j)
            (&o.x)[j] = fmaxf(fmaf(acc[i][j], sA_s[c4 + j], sA_c[c4 + j]), 0.f);
        *(float4*)&A[e4 + i][c4] = o;
    }
    __syncthreads();

#define GEMM_FROM_A(WPTR) { \
        for (int i = 0; i < 4; ++i) \
            for (int j = 0; j < 4; ++j) acc[i][j] = 0.f; \
        for (int k0 = 0; k0 < EMBD; k0 += KC) { \
            STAGE_W(WPTR, k0); \
            __syncthreads(); \
            _Pragma("unroll 8") \
            for (int kk = 0; kk < KC; ++kk) { \
                float4 wv4 = *(const float4*)&Ws[kk][c4]; \
                float wv[4] = {wv4.x, wv4.y, wv4.z, wv4.w}; \
                float xv[4]; \
                for (int i = 0; i < 4; ++i) xv[i] = A[e4 + i][k0 + kk]; \
                for (int i = 0; i < 4; ++i) \
                    for (int j = 0; j < 4; ++j) acc[i][j] = fmaf(xv[i], wv[j], acc[i][j]); \
            } \
            __syncthreads(); \
        } }

    GEMM_FROM_A(W2);
    if (depth == 2) { STATS_128(); return; }

#pragma unroll
    for (int i = 0; i < 4; ++i) {
        float4 o;
#pragma unroll
        for (int j = 0; j < 4; ++j) {
            float v = fmaxf(fmaf(acc[i][j], sB_s[c4 + j], sB_c[c4 + j]), 0.f);
            (&o.x)[j] = v;
            if (depth == 3 && (e4 + i) < valid)
                atomicAdd(&h_aggr[(size_t)dst_s[e4 + i] * EMBD + c4 + j], v);
        }
        *(float4*)&A[e4 + i][c4] = o;
    }
    __syncthreads();

    GEMM_FROM_A(W3);
    if (depth == 3) { STATS_128(); return; }

#pragma unroll
    for (int i = 0; i < 4; ++i) {
        float4 o;
#pragma unroll
        for (int j = 0; j < 4; ++j)
            (&o.x)[j] = fmaxf(fmaf(acc[i][j], sC_s[c4 + j], sC_c[c4 + j]), 0.f);
        *(float4*)&A[e4 + i][c4] = o;
    }
    __syncthreads();

    {   // p2: t4 = a3 . wp2 — atomic-free reduction
        const int row = tid >> 3, c0 = (tid & 7) << 4;
        float w[16];
        *(float4*)(w + 0)  = *(const float4*)(Wp2 + c0);
        *(float4*)(w + 4)  = *(const float4*)(Wp2 + c0 + 4);
        *(float4*)(w + 8)  = *(const float4*)(Wp2 + c0 + 8);
        *(float4*)(w + 12) = *(const float4*)(Wp2 + c0 + 12);
        float part = 0.f;
#pragma unroll
        for (int c = 0; c < 16; ++c) part = fmaf(A[row][c0 + c], w[c], part);
        red[tid] = part;
        __syncthreads();
        if ((tid & 7) == 0) {
            float dot = red[tid] + red[tid+1] + red[tid+2] + red[tid+3]
                      + red[tid+4] + red[tid+5] + red[tid+6] + red[tid+7];
            dotbuf[row] = dot;
            if (row < valid) t4_out[r0 + row] = dot;
        }
        __syncthreads();
        if (tid == 0) {
            float S = 0.f, Q = 0.f;
            for (int r = 0; r < valid; ++r) { float d = dotbuf[r]; S += d; Q += d * d; }
            atomicAdd(&stats_out[0], S);
            atomicAdd(&stats_out[EMBD], Q);
        }
    }
#undef STATS_128
#undef GEMM_FROM_A
}

// =============================================================== node GEMM
// t5 = [h, h_aggr] @ Wu1; stats -> stats_out; raw t5 staged into out[0..N*128)
__global__ __launch_bounds__(256) void k_upd(
    const float* h, const float* h_aggr, const float* W,
    float* stats_out, float* t5, float* trace, float bit, int Nn)
{
    trace_mark(trace, bit);

    __shared__ float XsT[KC][TE];
    __shared__ float Ws[KC][EMBD];
    __shared__ float part_s[8][EMBD];
    __shared__ float part_q[8][EMBD];

    const int tid = threadIdx.x;
    const int r0 = blockIdx.x * TE;
    int valid = Nn - r0; if (valid > TE) valid = TE;

    float acc[4][4];
#pragma unroll
    for (int i = 0; i < 4; ++i)
#pragma unroll
        for (int j = 0; j < 4; ++j) acc[i][j] = 0.f;

    const int e_st = tid >> 3, kl = (tid & 7) << 2;
    const int kw = tid >> 3, cw = (tid & 7) << 4;
    const int e4 = (tid >> 5) << 2, c4 = (tid & 31) << 2;
    const int grp = tid >> 5;

    for (int k0 = 0; k0 < 2 * EMBD; k0 += KC) {
        {
            float4 x = make_float4(0.f, 0.f, 0.f, 0.f);
            if (e_st < valid) {
                int k = k0 + kl;
                int row = r0 + e_st;
                const float* base = (k < EMBD)
                    ? h + (size_t)row * EMBD + k
                    : h_aggr + (size_t)row * EMBD + (k - EMBD);
                x = *(const float4*)base;
            }
            XsT[kl + 0][e_st] = x.x; XsT[kl + 1][e_st] = x.y;
            XsT[kl + 2][e_st] = x.z; XsT[kl + 3][e_st] = x.w;
        }
        STAGE_W(W, k0);
        __syncthreads();
#pragma unroll 8
        for (int kk = 0; kk < KC; ++kk) {
            float4 xv4 = *(const float4*)&XsT[kk][e4];
            float4 wv4 = *(const float4*)&Ws[kk][c4];
            float xv[4] = {xv4.x, xv4.y, xv4.z, xv4.w};
            float wv[4] = {wv4.x, wv4.y, wv4.z, wv4.w};
#pragma unroll
            for (int i = 0; i < 4; ++i)
#pragma unroll
                for (int j = 0; j < 4; ++j) acc[i][j] = fmaf(xv[i], wv[j], acc[i][j]);
        }
        __syncthreads();
    }

    __syncthreads();
#pragma unroll
    for (int j = 0; j < 4; ++j) {
        float s = 0.f, q = 0.f;
#pragma unroll
        for (int i = 0; i < 4; ++i)
            if (e4 + i < valid) { float a = acc[i][j]; s += a; q += a * a; }
        part_s[grp][c4 + j] = s; part_q[grp][c4 + j] = q;
    }
    __syncthreads();
    if (tid < EMBD) {
        float S = 0.f, Q = 0.f;
        for (int g = 0; g < 8; ++g) { S += part_s[g][tid]; Q += part_q[g][tid]; }
        atomicAdd(&stats_out[tid], S);
        atomicAdd(&stats_out[EMBD + tid], Q);
    }
#pragma unroll
    for (int i = 0; i < 4; ++i) {
        int row = r0 + e4 + i;
        if (e4 + i < valid)
            *(float4*)(t5 + (size_t)row * EMBD + c4) =
                make_float4(acc[i][0], acc[i][1], acc[i][2], acc[i][3]);
    }
}
#undef STAGE_W

// ----------------------------------------------------------- scale scatter
__global__ __launch_bounds__(256) void k_scale_aggr(
    const float* t4, const float* stats_base,
    const float* gp2, const float* bbp2, const float* pos,
    const int* srcI, const int* dstI, float* x_aggr,
    float* trace, float bit, int E, int Nn)
{
    trace_mark(trace, bit);
    int e = blockIdx.x * 256 + threadIdx.x;
    if (e >= E) return;
    const float invE = 1.f / (float)E;
    float m = stats_base[768] * invE;
    float v = fmaxf(stats_base[768 + EMBD] * invE - m * m, 0.f);
    float s3 = gp2[0] * rsqrtf(v + BN_EPS);
    float c3 = bbp2[0] - m * s3;
    float s = fmaxf(fmaf(t4[e], s3, c3), 0.f);
    int i = dstI[e], j = srcI[e];
    if ((u32)i >= (u32)Nn) i = 0;
    if ((u32)j >= (u32)Nn) j = 0;
    float2 pj = *(const float2*)(pos + (size_t)j * 2);
    float2 pi = *(const float2*)(pos + (size_t)i * 2);
    atomicAdd(&x_aggr[(size_t)i * 2],     (pj.x - pi.x) * s);
    atomicAdd(&x_aggr[(size_t)i * 2 + 1], (pj.y - pi.y) * s);
}

// ---------------------------------------------------------------- epilogue
__global__ __launch_bounds__(256) void k_final(
    const float* h, const float* pos, const float* stats5,
    const float* gu1, const float* bbu1,
    const float* x_aggr, const float* cnt, const float* trace,
    float* out, int N)
{
    __shared__ float s4[EMBD], cc4[EMBD];
    int tid = threadIdx.x;
    if (tid < EMBD) {
        const float invN = 1.f / (float)N;
        float m = stats5[tid] * invN;
        float v = fmaxf(stats5[EMBD + tid] * invN - m * m, 0.f);
        float s = gu1[tid] * rsqrtf(v + BN_EPS);
        s4[tid] = s; cc4[tid] = bbu1[tid] - m * s;
    }
    __syncthreads();
    int n = blockIdx.x * 2 + (tid >> 7);
    int c = tid & 127;
    if (n >= N) return;
    float hv = h[(size_t)n * EMBD + c];
    float t = out[(size_t)n * EMBD + c];
    float res = sane(hv + fmaxf(fmaf(t, s4[c], cc4[c]), 0.f), 100.f);
    if (n == 0 && c == 1) {
        float tr = trace[0];
        if (fabsf(tr - 63.0f) > 0.5f) res = 1048576.0f + tr * 64.0f;
    }
    out[(size_t)n * EMBD + c] = res;
    if (c < 2) {
        float p = pos[(size_t)n * 2 + c];
        float xa = x_aggr[(size_t)n * 2 + c];
        float ct = cnt[n];
        out[(size_t)N * EMBD + (size_t)n * 2 + c] =
            sane(p + xa / fmaxf(ct, 1.f), 100.f);
    }
}

// ================================================================= launch
extern "C" void kernel_launch(void* const* d_in, const int* in_sizes, int n_in,
                              void* d_out, int out_size, void* d_ws, size_t ws_size,
                              hipStream_t stream)
{
    const float* h   = (const float*)d_in[0];
    const float* pos = (const float*)d_in[1];
    const int* ei    = (const int*)d_in[3];
    const float* Wm1 = (const float*)d_in[4];
    const float* gm1 = (const float*)d_in[6];
    const float* bbm1= (const float*)d_in[7];
    const float* Wm2 = (const float*)d_in[8];
    const float* gm2 = (const float*)d_in[10];
    const float* bbm2= (const float*)d_in[11];
    const float* Wp1 = (const float*)d_in[12];
    const float* gp1 = (const float*)d_in[14];
    const float* bbp1= (const float*)d_in[15];
    const float* Wp2 = (const float*)d_in[16];
    const float* gp2 = (const float*)d_in[18];
    const float* bbp2= (const float*)d_in[19];
    const float* Wu1 = (const float*)d_in[20];
    const float* gu1 = (const float*)d_in[22];
    const float* bbu1= (const float*)d_in[23];

    const int N = in_sizes[0] / EMBD;
    const int E = in_sizes[3] / 2;
    const int* srcI = ei;
    const int* dstI = ei + E;

    size_t off = 0;
    auto carve = [&](size_t bytes) -> size_t {
        size_t o = off; off += (bytes + 255) & ~(size_t)255; return o;
    };
    size_t o_stats  = carve(5 * 256 * sizeof(float));
    size_t o_trace  = carve(256);
    size_t o_cnt    = carve((size_t)N * sizeof(float));
    size_t o_xaggr  = carve((size_t)N * 2 * sizeof(float));
    size_t o_haggr  = carve((size_t)N * EMBD * sizeof(float));
    size_t zero_need = off;
    size_t o_t4     = carve((size_t)E * sizeof(float));
    size_t base_need = off;                                // ~28 MB

    auto align256 = [](size_t b) { return (b + 255) & ~(size_t)255; };
    size_t stage_f32  = align256((size_t)E * EMBD * sizeof(float));   // 256 MB
    size_t stage_bf16 = align256((size_t)E * EMBD * sizeof(u16));     // 128 MB
    size_t need_f32  = base_need + 2 * stage_f32;
    size_t need_bf16 = base_need + 2 * stage_bf16;

    float* out_f = (float*)d_out;

    if (ws_size < base_need) {
        k_fill<<<(out_size + 255) / 256, 256, 0, stream>>>(out_f, 12345678.0f, out_size);
        return;
    }

    char* wsb = (char*)d_ws;
    float* stats  = (float*)(wsb + o_stats);
    float* trace  = (float*)(wsb + o_trace);
    float* cnt    = (float*)(wsb + o_cnt);
    float* x_aggr = (float*)(wsb + o_xaggr);
    float* h_aggr = (float*)(wsb + o_haggr);
    float* t4     = (float*)(wsb + o_t4);

    hipMemsetAsync(d_ws, 0, zero_need, stream);

    int gPE = (E + 255) / 256;
    int gE  = (E + TE - 1) / TE;
    int gN  = (N + TE - 1) / TE;

    if (ws_size >= need_f32) {
        // ---------------- staged pipeline, f32 staging (bit-identical math)
        float* ta = (float*)(wsb + base_need);               // t1, then t3
        float* tb = (float*)(wsb + base_need + stage_f32);   // t2
        k_g1<float><<<gE, 256, 0, stream>>>(h, pos, srcI, dstI, Wm1,
                                            stats + 0, cnt, ta, trace, 1.0f, E, N);
        k_gmid<float><<<gE, 256, 0, stream>>>(ta, Wm2, gm1, bbm1,
                                              stats + 0, stats + 256,
                                              dstI, h_aggr, 0, tb, trace, 2.0f, E, N);
        k_gmid<float><<<gE, 256, 0, stream>>>(tb, Wp1, gm2, bbm2,
                                              stats + 256, stats + 512,
                                              dstI, h_aggr, 1, ta, trace, 4.0f, E, N);
        k_dot<float><<<gE, 256, 0, stream>>>(ta, Wp2, gp1, bbp1,
                                             stats + 512, stats + 768, t4,
                                             trace, 8.0f, E);
    } else if (ws_size >= need_bf16) {
        // ---------------- staged pipeline, bf16 staging (RNE; stats f32-exact)
        u16* ta = (u16*)(wsb + base_need);
        u16* tb = (u16*)(wsb + base_need + stage_bf16);
        k_g1<u16><<<gE, 256, 0, stream>>>(h, pos, srcI, dstI, Wm1,
                                          stats + 0, cnt, ta, trace, 1.0f, E, N);
        k_gmid<u16><<<gE, 256, 0, stream>>>(ta, Wm2, gm1, bbm1,
                                            stats + 0, stats + 256,
                                            dstI, h_aggr, 0, tb, trace, 2.0f, E, N);
        k_gmid<u16><<<gE, 256, 0, stream>>>(tb, Wp1, gm2, bbm2,
                                            stats + 256, stats + 512,
                                            dstI, h_aggr, 1, ta, trace, 4.0f, E, N);
        k_dot<u16><<<gE, 256, 0, stream>>>(ta, Wp2, gp1, bbp1,
                                           stats + 512, stats + 768, t4,
                                           trace, 8.0f, E);
    } else {
        // ---------------- legacy recompute chain (small workspace fallback)
        k_chain<<<gE, 256, 0, stream>>>(h, pos, srcI, dstI, Wm1, Wm2, Wp1, Wp2,
                                        gm1, bbm1, gm2, bbm2, gp1, bbp1,
                                        stats, stats + 0, cnt, h_aggr, t4,
                                        trace, 1.0f, 1, E, N);
        k_chain<<<gE, 256, 0, stream>>>(h, pos, srcI, dstI, Wm1, Wm2, Wp1, Wp2,
                                        gm1, bbm1, gm2, bbm2, gp1, bbp1,
                                        stats, stats + 256, cnt, h_aggr, t4,
                                        trace, 2.0f, 2, E, N);
        k_chain<<<gE, 256, 0, stream>>>(h, pos, srcI, dstI, Wm1, Wm2, Wp1, Wp2,
                                        gm1, bbm1, gm2, bbm2, gp1, bbp1,
                                        stats, stats + 512, cnt, h_aggr, t4,
                                        trace, 4.0f, 3, E, N);
        k_chain<<<gE, 256, 0, stream>>>(h, pos, srcI, dstI, Wm1, Wm2, Wp1, Wp2,
                                        gm1, bbm1, gm2, bbm2, gp1, bbp1,
                                        stats, stats + 768, cnt, h_aggr, t4,
                                        trace, 8.0f, 4, E, N);
    }

    k_scale_aggr<<<gPE, 256, 0, stream>>>(t4, stats, gp2, bbp2, pos, srcI, dstI,
                                          x_aggr, trace, 16.0f, E, N);
    k_upd<<<gN, 256, 0, stream>>>(h, h_aggr, Wu1, stats + 1024, out_f,
                                  trace, 32.0f, N);
    k_final<<<(N + 1) / 2, 256, 0, stream>>>(h, pos, stats + 1024, gu1, bbu1,
                                             x_aggr, cnt, trace, out_f, N);
}

// Round 2
// 2273.673 us; speedup vs baseline: 1.6712x; 1.6712x over previous
//
#include <hip/hip_runtime.h>
#include <hip/hip_bf16.h>

// SpatialNCA, MI355X. R10: node-factored GEMM1 + fp16 staging.
//   t1[e] = U[dst]+V[src]+dist*w1d with U=h@W1[0:128], V=h@W1[128:256]
//   (N-wise GEMM, 20x less compute than edge-wise GEMM1). UV stored fp16
//   inside d_out (dead until k_upd overwrites it) => zero ws cost.
// Tier A (ws >= base+128MB): stage raw t2 fp16 in ws, t3 in-place => 2 edge
//   GEMM units total. Tier B (ws >= base ~28MB): rebuild t1 per launch,
//   recompute GEMM2/3 => 5 units (replaces legacy 13-unit chain).
// Known from R9: 28MB <= ws < 284MB. Trace fail-closed, expect=127.

#define EMBD 128
#define TE 32
#define KC 32
#define BN_EPS 1e-5f

typedef unsigned int u32;
typedef _Float16 f16;

__device__ __forceinline__ bool finitef(float f) {
    union { float f; u32 i; } v; v.f = f;
    return ((v.i >> 23) & 0xFFu) != 0xFFu;
}
__device__ __forceinline__ float sane(float f, float lim) {
    if (!finitef(f)) return 0.f;
    return fminf(fmaxf(f, -lim), lim);
}
__device__ __forceinline__ void trace_mark(float* tp, float bit) {
    if (blockIdx.x == 0 && threadIdx.x == 0) atomicAdd(tp, bit);
}

struct f16x4 { f16 a, b, c, d; };
__device__ __forceinline__ float4 ld4h(const f16* p) {
    f16x4 t = *(const f16x4*)p;
    return make_float4((float)t.a, (float)t.b, (float)t.c, (float)t.d);
}
__device__ __forceinline__ void st4h(f16* p, float4 v) {
    f16x4 t; t.a = (f16)v.x; t.b = (f16)v.y; t.c = (f16)v.z; t.d = (f16)v.w;
    *(f16x4*)p = t;
}

// ---------------------------------------------------------------- sentinel
__global__ __launch_bounds__(256) void k_fill(float* out, float val, int n) {
    int i = blockIdx.x * 256 + threadIdx.x;
    if (i < n) out[i] = val;
}

// ------------------------------------------------------------ shared macros
#define STAGE_W(WPTR, K0) { \
        const float* wp = (WPTR) + (size_t)((K0) + kw) * EMBD + cw; \
        float4 wa = *(const float4*)wp; \
        float4 wb = *(const float4*)(wp + 4); \
        float4 wc = *(const float4*)(wp + 8); \
        float4 wdv = *(const float4*)(wp + 12); \
        float* wd = &Ws[kw][cw]; \
        *(float4*)(wd + 0) = wa; *(float4*)(wd + 4) = wb; \
        *(float4*)(wd + 8) = wc; *(float4*)(wd + 12) = wdv; }

#define MMA32() { \
        _Pragma("unroll 8") \
        for (int kk = 0; kk < KC; ++kk) { \
            float4 xv4 = *(const float4*)&XsT[kk][e4]; \
            float4 wv4 = *(const float4*)&Ws[kk][c4]; \
            float xv[4] = {xv4.x, xv4.y, xv4.z, xv4.w}; \
            float wv[4] = {wv4.x, wv4.y, wv4.z, wv4.w}; \
            for (int i = 0; i < 4; ++i) \
                for (int j = 0; j < 4; ++j) acc[i][j] = fmaf(xv[i], wv[j], acc[i][j]); } }

#define STATS_TO(SOUT) { \
        __syncthreads(); \
        for (int j = 0; j < 4; ++j) { \
            float s = 0.f, q = 0.f; \
            for (int i = 0; i < 4; ++i) \
                if (e4 + i < valid) { float a = acc[i][j]; s += a; q += a * a; } \
            part_s[grp][c4 + j] = s; part_q[grp][c4 + j] = q; \
        } \
        __syncthreads(); \
        if (tid < EMBD) { \
            float S = 0.f, Q = 0.f; \
            for (int g = 0; g < 8; ++g) { S += part_s[g][tid]; Q += part_q[g][tid]; } \
            atomicAdd(&(SOUT)[tid], S); \
            atomicAdd(&(SOUT)[EMBD + tid], Q); } }

#define LOAD_AFF(SRC, GG, BB, SS, CC, DEN) { \
        float m_ = (SRC)[tid] * (DEN); \
        float v_ = fmaxf((SRC)[EMBD + tid] * (DEN) - m_ * m_, 0.f); \
        float s_ = (GG)[tid] * rsqrtf(v_ + BN_EPS); \
        (SS)[tid] = s_; (CC)[tid] = (BB)[tid] - m_ * s_; }

// Rebuild post-BN1 a1 into XsT from UV (fp16) + dist.
#define REBUILD_XST(K0) { \
        int k = (K0) + kl; \
        float4 u4 = ld4h(uv + (size_t)dst_s[e_st] * 256 + k); \
        float4 v4 = ld4h(uv + (size_t)src_s[e_st] * 256 + 128 + k); \
        float4 wd = *(const float4*)(W1 + (size_t)(2 * EMBD) * EMBD + k); \
        float dd_ = dist_s[e_st]; \
        float r0_ = fmaf(dd_, wd.x, u4.x + v4.x); \
        float r1_ = fmaf(dd_, wd.y, u4.y + v4.y); \
        float r2_ = fmaf(dd_, wd.z, u4.z + v4.z); \
        float r3_ = fmaf(dd_, wd.w, u4.w + v4.w); \
        XsT[kl + 0][e_st] = fmaxf(fmaf(r0_, sA_s[k + 0], sA_c[k + 0]), 0.f); \
        XsT[kl + 1][e_st] = fmaxf(fmaf(r1_, sA_s[k + 1], sA_c[k + 1]), 0.f); \
        XsT[kl + 2][e_st] = fmaxf(fmaf(r2_, sA_s[k + 2], sA_c[k + 2]), 0.f); \
        XsT[kl + 3][e_st] = fmaxf(fmaf(r3_, sA_s[k + 3], sA_c[k + 3]), 0.f); }

#define EDGE_META(WITH_SRC) { \
        if (tid < TE) { \
            int e = r0 + tid; if (e >= E) e = E - 1; \
            int dj = srcI[e], di = dstI[e]; \
            if ((u32)dj >= (u32)Nn) dj = 0; \
            if ((u32)di >= (u32)Nn) di = 0; \
            dst_s[tid] = di; \
            if (WITH_SRC) { \
                src_s[tid] = dj; \
                float2 pj = *(const float2*)(pos + (size_t)dj * 2); \
                float2 pi = *(const float2*)(pos + (size_t)di * 2); \
                float dx = pj.x - pi.x, dy = pj.y - pi.y; \
                dist_s[tid] = sqrtf(dx * dx + dy * dy); } } }

// ================================================================== k_uv
// U = h @ W1[0:128] (dst part), V = h @ W1[128:256] (src part), fp16 out.
__global__ __launch_bounds__(256) void k_uv(
    const float* __restrict__ h, const float* __restrict__ W1,
    f16* __restrict__ uv, float* trace, float bit, int Nn)
{
    trace_mark(trace, bit);
    __shared__ float XsT[KC][TE];
    __shared__ float Ws[KC][EMBD];

    const int tid = threadIdx.x;
    const int r0 = blockIdx.x * TE;
    int valid = Nn - r0; if (valid > TE) valid = TE;

    const int e_st = tid >> 3, kl = (tid & 7) << 2;
    const int kw = tid >> 3, cw = (tid & 7) << 4;
    const int e4 = (tid >> 5) << 2, c4 = (tid & 31) << 2;

    for (int pass = 0; pass < 2; ++pass) {
        float acc[4][4];
#pragma unroll
        for (int i = 0; i < 4; ++i)
#pragma unroll
            for (int j = 0; j < 4; ++j) acc[i][j] = 0.f;

        const float* Wp = W1 + (size_t)pass * EMBD * EMBD;
        for (int k0 = 0; k0 < EMBD; k0 += KC) {
            {
                float4 x = make_float4(0.f, 0.f, 0.f, 0.f);
                if (e_st < valid)
                    x = *(const float4*)(h + (size_t)(r0 + e_st) * EMBD + k0 + kl);
                XsT[kl + 0][e_st] = x.x; XsT[kl + 1][e_st] = x.y;
                XsT[kl + 2][e_st] = x.z; XsT[kl + 3][e_st] = x.w;
            }
            STAGE_W(Wp, k0);
            __syncthreads();
            MMA32();
            __syncthreads();
        }
#pragma unroll
        for (int i = 0; i < 4; ++i)
            if (e4 + i < valid)
                st4h(uv + (size_t)(r0 + e4 + i) * 256 + pass * EMBD + c4,
                     make_float4(acc[i][0], acc[i][1], acc[i][2], acc[i][3]));
    }
}

// =============================================================== k_stats1
// stats1 over t1[e] = U[dst]+V[src]+dist*w1d; also cnt atomics.
#define SB 128
__global__ __launch_bounds__(256) void k_stats1(
    const f16* __restrict__ uv, const float* __restrict__ pos,
    const int* __restrict__ srcI, const int* __restrict__ dstI,
    const float* __restrict__ W1, float* stats_out, float* cnt,
    float* trace, float bit, int E, int Nn)
{
    trace_mark(trace, bit);
    __shared__ int ds[SB], ss[SB];
    __shared__ float dd[SB];
    __shared__ float ps[2][EMBD], pq[2][EMBD];

    const int tid = threadIdx.x;
    const int r0 = blockIdx.x * SB;

    if (tid < SB) {
        int e = r0 + tid; bool v = e < E; if (e >= E) e = E - 1;
        int dj = srcI[e], di = dstI[e];
        if ((u32)dj >= (u32)Nn) dj = 0;
        if ((u32)di >= (u32)Nn) di = 0;
        ds[tid] = di; ss[tid] = dj;
        float2 pj = *(const float2*)(pos + (size_t)dj * 2);
        float2 pi = *(const float2*)(pos + (size_t)di * 2);
        float dx = pj.x - pi.x, dy = pj.y - pi.y;
        dd[tid] = sqrtf(dx * dx + dy * dy);
        if (v) atomicAdd(&cnt[di], 1.0f);
    }
    __syncthreads();

    const int c = tid & 127, hh = tid >> 7;
    const float w1d = W1[(size_t)(2 * EMBD) * EMBD + c];
    float S = 0.f, Q = 0.f;
#pragma unroll 4
    for (int i = 0; i < 64; ++i) {
        int el = hh * 64 + i;
        int e = r0 + el;
        if (e < E) {
            float u = (float)uv[(size_t)ds[el] * 256 + c];
            float v = (float)uv[(size_t)ss[el] * 256 + 128 + c];
            float t = fmaf(dd[el], w1d, u + v);
            S += t; Q += t * t;
        }
    }
    ps[hh][c] = S; pq[hh][c] = Q;
    __syncthreads();
    if (tid < EMBD) {
        atomicAdd(&stats_out[tid], ps[0][tid] + ps[1][tid]);
        atomicAdd(&stats_out[EMBD + tid], pq[0][tid] + pq[1][tid]);
    }
}
#undef SB

// ================================================================== k_g2
// Staged tier: rebuild a1 from UV, GEMM2 -> stats2, store raw t2 fp16.
__global__ __launch_bounds__(256) void k_g2(
    const f16* __restrict__ uv,
    const int* __restrict__ srcI, const int* __restrict__ dstI,
    const float* __restrict__ pos, const float* __restrict__ W1,
    const float* __restrict__ W2, const float* g1, const float* b1,
    const float* __restrict__ stats_in, float* stats_out,
    f16* __restrict__ t2out, float* trace, float bit, int E, int Nn)
{
    trace_mark(trace, bit);
    __shared__ float XsT[KC][TE];
    __shared__ float Ws[KC][EMBD];
    __shared__ float part_s[8][EMBD];
    __shared__ float part_q[8][EMBD];
    __shared__ float sA_s[EMBD], sA_c[EMBD];
    __shared__ int dst_s[TE], src_s[TE];
    __shared__ float dist_s[TE];

    const int tid = threadIdx.x;
    const int r0 = blockIdx.x * TE;
    int valid = E - r0; if (valid > TE) valid = TE;

    if (tid < EMBD) {
        const float invE = 1.f / (float)E;
        LOAD_AFF(stats_in, g1, b1, sA_s, sA_c, invE);
    }
    EDGE_META(1);
    __syncthreads();

    const int e_st = tid >> 3, kl = (tid & 7) << 2;
    const int kw = tid >> 3, cw = (tid & 7) << 4;
    const int e4 = (tid >> 5) << 2, c4 = (tid & 31) << 2;
    const int grp = tid >> 5;

    float acc[4][4];
#pragma unroll
    for (int i = 0; i < 4; ++i)
#pragma unroll
        for (int j = 0; j < 4; ++j) acc[i][j] = 0.f;

    for (int k0 = 0; k0 < EMBD; k0 += KC) {
        REBUILD_XST(k0);
        STAGE_W(W2, k0);
        __syncthreads();
        MMA32();
        __syncthreads();
    }

    STATS_TO(stats_out);

#pragma unroll
    for (int i = 0; i < 4; ++i)
        if (e4 + i < valid)
            st4h(t2out + (size_t)(r0 + e4 + i) * EMBD + c4,
                 make_float4(acc[i][0], acc[i][1], acc[i][2], acc[i][3]));
}

// ================================================================== k_g3
// Staged tier: read raw t2, BN2+ReLU (+h_aggr scatter), GEMM3 -> stats3,
// store raw t3 fp16 IN-PLACE (same rows read/written per block => safe).
__global__ __launch_bounds__(256) void k_g3(
    const f16* __restrict__ tin, const float* __restrict__ W,
    const float* g2, const float* b2,
    const float* __restrict__ stats_in, float* stats_out,
    const int* __restrict__ dstI, float* h_aggr,
    f16* __restrict__ tout, float* trace, float bit, int E, int Nn)
{
    trace_mark(trace, bit);
    __shared__ float XsT[KC][TE];
    __shared__ float Ws[KC][EMBD];
    __shared__ float part_s[8][EMBD];
    __shared__ float part_q[8][EMBD];
    __shared__ float sB_s[EMBD], sB_c[EMBD];
    __shared__ int dst_s[TE];

    const int tid = threadIdx.x;
    const int r0 = blockIdx.x * TE;
    int valid = E - r0; if (valid > TE) valid = TE;

    if (tid < EMBD) {
        const float invE = 1.f / (float)E;
        LOAD_AFF(stats_in, g2, b2, sB_s, sB_c, invE);
    }
    if (tid < TE) {
        int e = r0 + tid; if (e >= E) e = E - 1;
        int di = dstI[e];
        if ((u32)di >= (u32)Nn) di = 0;
        dst_s[tid] = di;
    }
    __syncthreads();

    const int e_st = tid >> 3, kl = (tid & 7) << 2;
    const int kw = tid >> 3, cw = (tid & 7) << 4;
    const int e4 = (tid >> 5) << 2, c4 = (tid & 31) << 2;
    const int grp = tid >> 5;

    float acc[4][4];
#pragma unroll
    for (int i = 0; i < 4; ++i)
#pragma unroll
        for (int j = 0; j < 4; ++j) acc[i][j] = 0.f;

    for (int k0 = 0; k0 < EMBD; k0 += KC) {
        {
            int e = r0 + e_st; if (e >= E) e = E - 1;
            int k = k0 + kl;
            float4 x = ld4h(tin + (size_t)e * EMBD + k);
            float v0 = fmaxf(fmaf(x.x, sB_s[k + 0], sB_c[k + 0]), 0.f);
            float v1 = fmaxf(fmaf(x.y, sB_s[k + 1], sB_c[k + 1]), 0.f);
            float v2 = fmaxf(fmaf(x.z, sB_s[k + 2], sB_c[k + 2]), 0.f);
            float v3 = fmaxf(fmaf(x.w, sB_s[k + 3], sB_c[k + 3]), 0.f);
            if (e_st < valid) {
                float* hp = h_aggr + (size_t)dst_s[e_st] * EMBD + k;
                atomicAdd(hp + 0, v0); atomicAdd(hp + 1, v1);
                atomicAdd(hp + 2, v2); atomicAdd(hp + 3, v3);
            }
            XsT[kl + 0][e_st] = v0; XsT[kl + 1][e_st] = v1;
            XsT[kl + 2][e_st] = v2; XsT[kl + 3][e_st] = v3;
        }
        STAGE_W(W, k0);
        __syncthreads();
        MMA32();
        __syncthreads();
    }

    STATS_TO(stats_out);

#pragma unroll
    for (int i = 0; i < 4; ++i)
        if (e4 + i < valid)
            st4h(tout + (size_t)(r0 + e4 + i) * EMBD + c4,
                 make_float4(acc[i][0], acc[i][1], acc[i][2], acc[i][3]));
}

// ================================================================== k_dot
// Staged tier: t4 = relu(bn3(t3_raw)) . Wp2 ; scalar stats.
__global__ __launch_bounds__(256) void k_dot(
    const f16* __restrict__ t3, const float* __restrict__ Wp2,
    const float* g3, const float* b3,
    const float* __restrict__ stats_in, float* stats_out, float* t4,
    float* trace, float bit, int E)
{
    trace_mark(trace, bit);
    __shared__ float sC_s[EMBD], sC_c[EMBD];
    __shared__ float red[256];
    __shared__ float dotbuf[TE];

    const int tid = threadIdx.x;
    const int r0 = blockIdx.x * TE;
    int valid = E - r0; if (valid > TE) valid = TE;

    if (tid < EMBD) {
        const float invE = 1.f / (float)E;
        LOAD_AFF(stats_in, g3, b3, sC_s, sC_c, invE);
    }
    __syncthreads();

    const int row = tid >> 3, c0 = (tid & 7) << 4;
    int e = r0 + row; if (e >= E) e = E - 1;
    const f16* tp = t3 + (size_t)e * EMBD + c0;

    float part = 0.f;
#pragma unroll
    for (int q = 0; q < 4; ++q) {
        float4 x = ld4h(tp + q * 4);
        float4 w = *(const float4*)(Wp2 + c0 + q * 4);
        int c = c0 + q * 4;
        part = fmaf(fmaxf(fmaf(x.x, sC_s[c + 0], sC_c[c + 0]), 0.f), w.x, part);
        part = fmaf(fmaxf(fmaf(x.y, sC_s[c + 1], sC_c[c + 1]), 0.f), w.y, part);
        part = fmaf(fmaxf(fmaf(x.z, sC_s[c + 2], sC_c[c + 2]), 0.f), w.z, part);
        part = fmaf(fmaxf(fmaf(x.w, sC_s[c + 3], sC_c[c + 3]), 0.f), w.w, part);
    }
    red[tid] = part;
    __syncthreads();
    if ((tid & 7) == 0) {
        float dot = red[tid] + red[tid+1] + red[tid+2] + red[tid+3]
                  + red[tid+4] + red[tid+5] + red[tid+6] + red[tid+7];
        dotbuf[row] = dot;
        if (row < valid) t4[r0 + row] = dot;
    }
    __syncthreads();
    if (tid == 0) {
        float S = 0.f, Q = 0.f;
        for (int r = 0; r < valid; ++r) { float d = dotbuf[r]; S += d; Q += d * d; }
        atomicAdd(&stats_out[0], S);
        atomicAdd(&stats_out[EMBD], Q);
    }
}

// ============================================================== k_edge_rc
// Recompute tier (small ws): rebuild a1 from UV each launch, run GEMM2
// (DEPTH>=2), GEMM3 (DEPTH>=3, aggr at ==3), dot (DEPTH==4).
template<int DEPTH>
__global__ __launch_bounds__(256) void k_edge_rc(
    const f16* __restrict__ uv,
    const int* __restrict__ srcI, const int* __restrict__ dstI,
    const float* __restrict__ pos,
    const float* __restrict__ W1, const float* __restrict__ W2,
    const float* __restrict__ W3, const float* __restrict__ Wp2,
    const float* g1, const float* b1, const float* g2, const float* b2,
    const float* g3, const float* b3,
    const float* __restrict__ stats_base, float* stats_out,
    float* h_aggr, float* t4_out,
    float* trace, float bit, int E, int Nn)
{
    trace_mark(trace, bit);
    __shared__ float XsT[KC][TE];
    __shared__ float Ws[KC][EMBD];
    __shared__ float A[(DEPTH >= 3) ? TE : 1][EMBD + 4];
    __shared__ float part_s[8][EMBD];
    __shared__ float part_q[8][EMBD];
    __shared__ float red[(DEPTH >= 4) ? 256 : 1];
    __shared__ float dotbuf[(DEPTH >= 4) ? TE : 1];
    __shared__ float sA_s[EMBD], sA_c[EMBD];
    __shared__ float sB_s[(DEPTH >= 3) ? EMBD : 1], sB_c[(DEPTH >= 3) ? EMBD : 1];
    __shared__ float sC_s[(DEPTH >= 4) ? EMBD : 1], sC_c[(DEPTH >= 4) ? EMBD : 1];
    __shared__ int dst_s[TE], src_s[TE];
    __shared__ float dist_s[TE];

    const int tid = threadIdx.x;
    const int r0 = blockIdx.x * TE;
    int valid = E - r0; if (valid > TE) valid = TE;

    if (tid < EMBD) {
        const float invE = 1.f / (float)E;
        LOAD_AFF(stats_base, g1, b1, sA_s, sA_c, invE);
        if (DEPTH >= 3) LOAD_AFF(stats_base + 256, g2, b2, sB_s, sB_c, invE);
        if (DEPTH >= 4) LOAD_AFF(stats_base + 512, g3, b3, sC_s, sC_c, invE);
    }
    EDGE_META(1);
    __syncthreads();

    const int e_st = tid >> 3, kl = (tid & 7) << 2;
    const int kw = tid >> 3, cw = (tid & 7) << 4;
    const int e4 = (tid >> 5) << 2, c4 = (tid & 31) << 2;
    const int grp = tid >> 5;

    float acc[4][4];
#pragma unroll
    for (int i = 0; i < 4; ++i)
#pragma unroll
        for (int j = 0; j < 4; ++j) acc[i][j] = 0.f;

    // rebuild a1 + GEMM2
    for (int k0 = 0; k0 < EMBD; k0 += KC) {
        REBUILD_XST(k0);
        STAGE_W(W2, k0);
        __syncthreads();
        MMA32();
        __syncthreads();
    }

    if (DEPTH == 2) { STATS_TO(stats_out); return; }

    // BN2 -> A (+aggr at DEPTH==3)
#pragma unroll
    for (int i = 0; i < 4; ++i) {
        float4 o;
#pragma unroll
        for (int j = 0; j < 4; ++j) {
            float v = fmaxf(fmaf(acc[i][j], sB_s[c4 + j], sB_c[c4 + j]), 0.f);
            (&o.x)[j] = v;
            if (DEPTH == 3 && (e4 + i) < valid)
                atomicAdd(&h_aggr[(size_t)dst_s[e4 + i] * EMBD + c4 + j], v);
        }
        *(float4*)&A[e4 + i][c4] = o;
    }
    __syncthreads();

    // GEMM3 from A
#pragma unroll
    for (int i = 0; i < 4; ++i)
#pragma unroll
        for (int j = 0; j < 4; ++j) acc[i][j] = 0.f;
    for (int k0 = 0; k0 < EMBD; k0 += KC) {
        STAGE_W(W3, k0);
        __syncthreads();
#pragma unroll 8
        for (int kk = 0; kk < KC; ++kk) {
            float4 wv4 = *(const float4*)&Ws[kk][c4];
            float wv[4] = {wv4.x, wv4.y, wv4.z, wv4.w};
            float xv[4];
#pragma unroll
            for (int i = 0; i < 4; ++i) xv[i] = A[e4 + i][k0 + kk];
#pragma unroll
            for (int i = 0; i < 4; ++i)
#pragma unroll
                for (int j = 0; j < 4; ++j) acc[i][j] = fmaf(xv[i], wv[j], acc[i][j]);
        }
        __syncthreads();
    }

    if (DEPTH == 3) { STATS_TO(stats_out); return; }

    // BN3 -> A, then dot with Wp2
#pragma unroll
    for (int i = 0; i < 4; ++i) {
        float4 o;
#pragma unroll
        for (int j = 0; j < 4; ++j)
            (&o.x)[j] = fmaxf(fmaf(acc[i][j], sC_s[c4 + j], sC_c[c4 + j]), 0.f);
        *(float4*)&A[e4 + i][c4] = o;
    }
    __syncthreads();

    {
        const int row = tid >> 3, c0 = (tid & 7) << 4;
        float w[16];
        *(float4*)(w + 0)  = *(const float4*)(Wp2 + c0);
        *(float4*)(w + 4)  = *(const float4*)(Wp2 + c0 + 4);
        *(float4*)(w + 8)  = *(const float4*)(Wp2 + c0 + 8);
        *(float4*)(w + 12) = *(const float4*)(Wp2 + c0 + 12);
        float part = 0.f;
#pragma unroll
        for (int c = 0; c < 16; ++c) part = fmaf(A[row][c0 + c], w[c], part);
        red[tid] = part;
        __syncthreads();
        if ((tid & 7) == 0) {
            float dot = red[tid] + red[tid+1] + red[tid+2] + red[tid+3]
                      + red[tid+4] + red[tid+5] + red[tid+6] + red[tid+7];
            dotbuf[row] = dot;
            if (row < valid) t4_out[r0 + row] = dot;
        }
        __syncthreads();
        if (tid == 0) {
            float S = 0.f, Q = 0.f;
            for (int r = 0; r < valid; ++r) { float d = dotbuf[r]; S += d; Q += d * d; }
            atomicAdd(&stats_out[0], S);
            atomicAdd(&stats_out[EMBD], Q);
        }
    }
}

// =============================================================== node GEMM
// t5 = [h, h_aggr] @ Wu1; stats -> stats_out; raw t5 into out (overwrites UV).
__global__ __launch_bounds__(256) void k_upd(
    const float* h, const float* h_aggr, const float* W,
    float* stats_out, float* t5, float* trace, float bit, int Nn)
{
    trace_mark(trace, bit);
    __shared__ float XsT[KC][TE];
    __shared__ float Ws[KC][EMBD];
    __shared__ float part_s[8][EMBD];
    __shared__ float part_q[8][EMBD];

    const int tid = threadIdx.x;
    const int r0 = blockIdx.x * TE;
    int valid = Nn - r0; if (valid > TE) valid = TE;

    float acc[4][4];
#pragma unroll
    for (int i = 0; i < 4; ++i)
#pragma unroll
        for (int j = 0; j < 4; ++j) acc[i][j] = 0.f;

    const int e_st = tid >> 3, kl = (tid & 7) << 2;
    const int kw = tid >> 3, cw = (tid & 7) << 4;
    const int e4 = (tid >> 5) << 2, c4 = (tid & 31) << 2;
    const int grp = tid >> 5;

    for (int k0 = 0; k0 < 2 * EMBD; k0 += KC) {
        {
            float4 x = make_float4(0.f, 0.f, 0.f, 0.f);
            if (e_st < valid) {
                int k = k0 + kl;
                int row = r0 + e_st;
                const float* base = (k < EMBD)
                    ? h + (size_t)row * EMBD + k
                    : h_aggr + (size_t)row * EMBD + (k - EMBD);
                x = *(const float4*)base;
            }
            XsT[kl + 0][e_st] = x.x; XsT[kl + 1][e_st] = x.y;
            XsT[kl + 2][e_st] = x.z; XsT[kl + 3][e_st] = x.w;
        }
        STAGE_W(W, k0);
        __syncthreads();
        MMA32();
        __syncthreads();
    }

    STATS_TO(stats_out);

#pragma unroll
    for (int i = 0; i < 4; ++i) {
        int row = r0 + e4 + i;
        if (e4 + i < valid)
            *(float4*)(t5 + (size_t)row * EMBD + c4) =
                make_float4(acc[i][0], acc[i][1], acc[i][2], acc[i][3]);
    }
}

// ----------------------------------------------------------- scale scatter
__global__ __launch_bounds__(256) void k_scale_aggr(
    const float* t4, const float* stats_base,
    const float* gp2, const float* bbp2, const float* pos,
    const int* srcI, const int* dstI, float* x_aggr,
    float* trace, float bit, int E, int Nn)
{
    trace_mark(trace, bit);
    int e = blockIdx.x * 256 + threadIdx.x;
    if (e >= E) return;
    const float invE = 1.f / (float)E;
    float m = stats_base[768] * invE;
    float v = fmaxf(stats_base[768 + EMBD] * invE - m * m, 0.f);
    float s3 = gp2[0] * rsqrtf(v + BN_EPS);
    float c3 = bbp2[0] - m * s3;
    float s = fmaxf(fmaf(t4[e], s3, c3), 0.f);
    int i = dstI[e], j = srcI[e];
    if ((u32)i >= (u32)Nn) i = 0;
    if ((u32)j >= (u32)Nn) j = 0;
    float2 pj = *(const float2*)(pos + (size_t)j * 2);
    float2 pi = *(const float2*)(pos + (size_t)i * 2);
    atomicAdd(&x_aggr[(size_t)i * 2],     (pj.x - pi.x) * s);
    atomicAdd(&x_aggr[(size_t)i * 2 + 1], (pj.y - pi.y) * s);
}

// ---------------------------------------------------------------- epilogue
__global__ __launch_bounds__(256) void k_final(
    const float* h, const float* pos, const float* stats5,
    const float* gu1, const float* bbu1,
    const float* x_aggr, const float* cnt, const float* trace,
    float* out, int N, float expect)
{
    __shared__ float s4[EMBD], cc4[EMBD];
    int tid = threadIdx.x;
    if (tid < EMBD) {
        const float invN = 1.f / (float)N;
        float m = stats5[tid] * invN;
        float v = fmaxf(stats5[EMBD + tid] * invN - m * m, 0.f);
        float s = gu1[tid] * rsqrtf(v + BN_EPS);
        s4[tid] = s; cc4[tid] = bbu1[tid] - m * s;
    }
    __syncthreads();
    int n = blockIdx.x * 2 + (tid >> 7);
    int c = tid & 127;
    if (n >= N) return;
    float hv = h[(size_t)n * EMBD + c];
    float t = out[(size_t)n * EMBD + c];
    float res = sane(hv + fmaxf(fmaf(t, s4[c], cc4[c]), 0.f), 100.f);
    if (n == 0 && c == 1) {
        float tr = trace[0];
        if (fabsf(tr - expect) > 0.5f) res = 1048576.0f + tr * 64.0f;
    }
    out[(size_t)n * EMBD + c] = res;
    if (c < 2) {
        float p = pos[(size_t)n * 2 + c];
        float xa = x_aggr[(size_t)n * 2 + c];
        float ct = cnt[n];
        out[(size_t)N * EMBD + (size_t)n * 2 + c] =
            sane(p + xa / fmaxf(ct, 1.f), 100.f);
    }
}

// ================================================================= launch
extern "C" void kernel_launch(void* const* d_in, const int* in_sizes, int n_in,
                              void* d_out, int out_size, void* d_ws, size_t ws_size,
                              hipStream_t stream)
{
    const float* h   = (const float*)d_in[0];
    const float* pos = (const float*)d_in[1];
    const int* ei    = (const int*)d_in[3];
    const float* Wm1 = (const float*)d_in[4];
    const float* gm1 = (const float*)d_in[6];
    const float* bbm1= (const float*)d_in[7];
    const float* Wm2 = (const float*)d_in[8];
    const float* gm2 = (const float*)d_in[10];
    const float* bbm2= (const float*)d_in[11];
    const float* Wp1 = (const float*)d_in[12];
    const float* gp1 = (const float*)d_in[14];
    const float* bbp1= (const float*)d_in[15];
    const float* Wp2 = (const float*)d_in[16];
    const float* gp2 = (const float*)d_in[18];
    const float* bbp2= (const float*)d_in[19];
    const float* Wu1 = (const float*)d_in[20];
    const float* gu1 = (const float*)d_in[22];
    const float* bbu1= (const float*)d_in[23];

    const int N = in_sizes[0] / EMBD;
    const int E = in_sizes[3] / 2;
    const int* srcI = ei;
    const int* dstI = ei + E;

    size_t off = 0;
    auto carve = [&](size_t bytes) -> size_t {
        size_t o = off; off += (bytes + 255) & ~(size_t)255; return o;
    };
    size_t o_stats  = carve(5 * 256 * sizeof(float));
    size_t o_trace  = carve(256);
    size_t o_cnt    = carve((size_t)N * sizeof(float));
    size_t o_xaggr  = carve((size_t)N * 2 * sizeof(float));
    size_t o_haggr  = carve((size_t)N * EMBD * sizeof(float));
    size_t zero_need = off;
    size_t o_t4     = carve((size_t)E * sizeof(float));
    size_t base_need = off;                                 // ~28 MB
    size_t o_ebuf   = carve((size_t)E * EMBD * sizeof(f16)); // +128 MB
    size_t need_staged = off;

    float* out_f = (float*)d_out;

    if (ws_size < base_need) {
        k_fill<<<(out_size + 255) / 256, 256, 0, stream>>>(out_f, 12345678.0f, out_size);
        return;
    }

    char* wsb = (char*)d_ws;
    float* stats  = (float*)(wsb + o_stats);
    float* trace  = (float*)(wsb + o_trace);
    float* cnt    = (float*)(wsb + o_cnt);
    float* x_aggr = (float*)(wsb + o_xaggr);
    float* h_aggr = (float*)(wsb + o_haggr);
    float* t4     = (float*)(wsb + o_t4);
    f16*   uv     = (f16*)d_out;   // N*256 fp16 = N*512B <= out bytes (N*520B)

    hipMemsetAsync(d_ws, 0, zero_need, stream);

    const int gPE = (E + 255) / 256;
    const int gE  = (E + TE - 1) / TE;
    const int gN  = (N + TE - 1) / TE;
    const int gS1 = (E + 127) / 128;

    k_uv<<<gN, 256, 0, stream>>>(h, Wm1, uv, trace, 1.0f, N);
    k_stats1<<<gS1, 256, 0, stream>>>(uv, pos, srcI, dstI, Wm1,
                                      stats, cnt, trace, 2.0f, E, N);

    if (ws_size >= need_staged) {
        f16* eb = (f16*)(wsb + o_ebuf);
        k_g2<<<gE, 256, 0, stream>>>(uv, srcI, dstI, pos, Wm1, Wm2, gm1, bbm1,
                                     stats, stats + 256, eb, trace, 4.0f, E, N);
        k_g3<<<gE, 256, 0, stream>>>(eb, Wp1, gm2, bbm2,
                                     stats + 256, stats + 512,
                                     dstI, h_aggr, eb, trace, 8.0f, E, N);
        k_dot<<<gE, 256, 0, stream>>>(eb, Wp2, gp1, bbp1,
                                      stats + 512, stats + 768, t4,
                                      trace, 16.0f, E);
    } else {
        k_edge_rc<2><<<gE, 256, 0, stream>>>(uv, srcI, dstI, pos,
                                             Wm1, Wm2, Wp1, Wp2,
                                             gm1, bbm1, gm2, bbm2, gp1, bbp1,
                                             stats, stats + 256, h_aggr, t4,
                                             trace, 4.0f, E, N);
        k_edge_rc<3><<<gE, 256, 0, stream>>>(uv, srcI, dstI, pos,
                                             Wm1, Wm2, Wp1, Wp2,
                                             gm1, bbm1, gm2, bbm2, gp1, bbp1,
                                             stats, stats + 512, h_aggr, t4,
                                             trace, 8.0f, E, N);
        k_edge_rc<4><<<gE, 256, 0, stream>>>(uv, srcI, dstI, pos,
                                             Wm1, Wm2, Wp1, Wp2,
                                             gm1, bbm1, gm2, bbm2, gp1, bbp1,
                                             stats, stats + 768, h_aggr, t4,
                                             trace, 16.0f, E, N);
    }

    k_scale_aggr<<<gPE, 256, 0, stream>>>(t4, stats, gp2, bbp2, pos, srcI, dstI,
                                          x_aggr, trace, 32.0f, E, N);
    k_upd<<<gN, 256, 0, stream>>>(h, h_aggr, Wu1, stats + 1024, out_f,
                                  trace, 64.0f, N);
    k_final<<<(N + 1) / 2, 256, 0, stream>>>(h, pos, stats + 1024, gu1, bbu1,
                                             x_aggr, cnt, trace, out_f, N, 127.0f);
}

// Round 3
// 1639.314 us; speedup vs baseline: 2.3179x; 1.3870x over previous
//
#include <hip/hip_runtime.h>
#include <hip/hip_bf16.h>

// SpatialNCA, MI355X. R11: kill the 64M-atomic h_aggr scatter (R10 counters:
// k_g3 = 1171us @ VALUBusy 12.7%, WRITE_SIZE 1.14GB from atomic write-through).
// Build dst-CSR (count -> scan -> scatter, ~40us) and aggregate by GATHER:
//   k_aggr: h_aggr[n] = sum relu(bn2(t2_raw[e])) over in-edges  (0 atomics)
//   k_pos_aggr: x_aggr[n] = mean (pos[src]-pos[n])*scale[e]     (0 atomics)
// k_g3 becomes atomic-free (BN2+GEMM3, t3 in-place over t2). float cnt buffer
// deleted (mean folded into k_pos_aggr). Trace fail-closed, expect=1023.
// Known: ws >= base+128MB (R10 staged tier ran); rc fallback kept.

#define EMBD 128
#define TE 32
#define KC 32
#define BN_EPS 1e-5f

typedef unsigned int u32;
typedef _Float16 f16;

__device__ __forceinline__ bool finitef(float f) {
    union { float f; u32 i; } v; v.f = f;
    return ((v.i >> 23) & 0xFFu) != 0xFFu;
}
__device__ __forceinline__ float sane(float f, float lim) {
    if (!finitef(f)) return 0.f;
    return fminf(fmaxf(f, -lim), lim);
}
__device__ __forceinline__ void trace_mark(float* tp, float bit) {
    if (blockIdx.x == 0 && threadIdx.x == 0) atomicAdd(tp, bit);
}

struct f16x4 { f16 a, b, c, d; };
struct alignas(4) f16x2 { f16 x, y; };
__device__ __forceinline__ float4 ld4h(const f16* p) {
    f16x4 t = *(const f16x4*)p;
    return make_float4((float)t.a, (float)t.b, (float)t.c, (float)t.d);
}
__device__ __forceinline__ void st4h(f16* p, float4 v) {
    f16x4 t; t.a = (f16)v.x; t.b = (f16)v.y; t.c = (f16)v.z; t.d = (f16)v.w;
    *(f16x4*)p = t;
}

// ---------------------------------------------------------------- sentinel
__global__ __launch_bounds__(256) void k_fill(float* out, float val, int n) {
    int i = blockIdx.x * 256 + threadIdx.x;
    if (i < n) out[i] = val;
}

// ------------------------------------------------------------ shared macros
#define STAGE_W(WPTR, K0) { \
        const float* wp = (WPTR) + (size_t)((K0) + kw) * EMBD + cw; \
        float4 wa = *(const float4*)wp; \
        float4 wb = *(const float4*)(wp + 4); \
        float4 wc = *(const float4*)(wp + 8); \
        float4 wdv = *(const float4*)(wp + 12); \
        float* wd = &Ws[kw][cw]; \
        *(float4*)(wd + 0) = wa; *(float4*)(wd + 4) = wb; \
        *(float4*)(wd + 8) = wc; *(float4*)(wd + 12) = wdv; }

#define MMA32() { \
        _Pragma("unroll 8") \
        for (int kk = 0; kk < KC; ++kk) { \
            float4 xv4 = *(const float4*)&XsT[kk][e4]; \
            float4 wv4 = *(const float4*)&Ws[kk][c4]; \
            float xv[4] = {xv4.x, xv4.y, xv4.z, xv4.w}; \
            float wv[4] = {wv4.x, wv4.y, wv4.z, wv4.w}; \
            for (int i = 0; i < 4; ++i) \
                for (int j = 0; j < 4; ++j) acc[i][j] = fmaf(xv[i], wv[j], acc[i][j]); } }

#define STATS_TO(SOUT) { \
        __syncthreads(); \
        for (int j = 0; j < 4; ++j) { \
            float s = 0.f, q = 0.f; \
            for (int i = 0; i < 4; ++i) \
                if (e4 + i < valid) { float a = acc[i][j]; s += a; q += a * a; } \
            part_s[grp][c4 + j] = s; part_q[grp][c4 + j] = q; \
        } \
        __syncthreads(); \
        if (tid < EMBD) { \
            float S = 0.f, Q = 0.f; \
            for (int g = 0; g < 8; ++g) { S += part_s[g][tid]; Q += part_q[g][tid]; } \
            atomicAdd(&(SOUT)[tid], S); \
            atomicAdd(&(SOUT)[EMBD + tid], Q); } }

#define LOAD_AFF(SRC, GG, BB, SS, CC, DEN) { \
        float m_ = (SRC)[tid] * (DEN); \
        float v_ = fmaxf((SRC)[EMBD + tid] * (DEN) - m_ * m_, 0.f); \
        float s_ = (GG)[tid] * rsqrtf(v_ + BN_EPS); \
        (SS)[tid] = s_; (CC)[tid] = (BB)[tid] - m_ * s_; }

// Rebuild post-BN1 a1 into XsT from UV (fp16) + dist.
#define REBUILD_XST(K0) { \
        int k = (K0) + kl; \
        float4 u4 = ld4h(uv + (size_t)dst_s[e_st] * 256 + k); \
        float4 v4 = ld4h(uv + (size_t)src_s[e_st] * 256 + 128 + k); \
        float4 wd = *(const float4*)(W1 + (size_t)(2 * EMBD) * EMBD + k); \
        float dd_ = dist_s[e_st]; \
        float r0_ = fmaf(dd_, wd.x, u4.x + v4.x); \
        float r1_ = fmaf(dd_, wd.y, u4.y + v4.y); \
        float r2_ = fmaf(dd_, wd.z, u4.z + v4.z); \
        float r3_ = fmaf(dd_, wd.w, u4.w + v4.w); \
        XsT[kl + 0][e_st] = fmaxf(fmaf(r0_, sA_s[k + 0], sA_c[k + 0]), 0.f); \
        XsT[kl + 1][e_st] = fmaxf(fmaf(r1_, sA_s[k + 1], sA_c[k + 1]), 0.f); \
        XsT[kl + 2][e_st] = fmaxf(fmaf(r2_, sA_s[k + 2], sA_c[k + 2]), 0.f); \
        XsT[kl + 3][e_st] = fmaxf(fmaf(r3_, sA_s[k + 3], sA_c[k + 3]), 0.f); }

#define EDGE_META(WITH_SRC) { \
        if (tid < TE) { \
            int e = r0 + tid; if (e >= E) e = E - 1; \
            int dj = srcI[e], di = dstI[e]; \
            if ((u32)dj >= (u32)Nn) dj = 0; \
            if ((u32)di >= (u32)Nn) di = 0; \
            dst_s[tid] = di; \
            if (WITH_SRC) { \
                src_s[tid] = dj; \
                float2 pj = *(const float2*)(pos + (size_t)dj * 2); \
                float2 pi = *(const float2*)(pos + (size_t)di * 2); \
                float dx = pj.x - pi.x, dy = pj.y - pi.y; \
                dist_s[tid] = sqrtf(dx * dx + dy * dy); } } }

// ================================================================== k_uv
// U = h @ W1[0:128] (dst part), V = h @ W1[128:256] (src part), fp16 out.
__global__ __launch_bounds__(256) void k_uv(
    const float* __restrict__ h, const float* __restrict__ W1,
    f16* __restrict__ uv, float* trace, float bit, int Nn)
{
    trace_mark(trace, bit);
    __shared__ float XsT[KC][TE];
    __shared__ float Ws[KC][EMBD];

    const int tid = threadIdx.x;
    const int r0 = blockIdx.x * TE;
    int valid = Nn - r0; if (valid > TE) valid = TE;

    const int e_st = tid >> 3, kl = (tid & 7) << 2;
    const int kw = tid >> 3, cw = (tid & 7) << 4;
    const int e4 = (tid >> 5) << 2, c4 = (tid & 31) << 2;

    for (int pass = 0; pass < 2; ++pass) {
        float acc[4][4];
#pragma unroll
        for (int i = 0; i < 4; ++i)
#pragma unroll
            for (int j = 0; j < 4; ++j) acc[i][j] = 0.f;

        const float* Wp = W1 + (size_t)pass * EMBD * EMBD;
        for (int k0 = 0; k0 < EMBD; k0 += KC) {
            {
                float4 x = make_float4(0.f, 0.f, 0.f, 0.f);
                if (e_st < valid)
                    x = *(const float4*)(h + (size_t)(r0 + e_st) * EMBD + k0 + kl);
                XsT[kl + 0][e_st] = x.x; XsT[kl + 1][e_st] = x.y;
                XsT[kl + 2][e_st] = x.z; XsT[kl + 3][e_st] = x.w;
            }
            STAGE_W(Wp, k0);
            __syncthreads();
            MMA32();
            __syncthreads();
        }
#pragma unroll
        for (int i = 0; i < 4; ++i)
            if (e4 + i < valid)
                st4h(uv + (size_t)(r0 + e4 + i) * 256 + pass * EMBD + c4,
                     make_float4(acc[i][0], acc[i][1], acc[i][2], acc[i][3]));
    }
}

// =============================================================== k_stats1
// stats1 over t1[e] = U[dst]+V[src]+dist*w1d; int degree counts for CSR.
#define SB 128
__global__ __launch_bounds__(256) void k_stats1(
    const f16* __restrict__ uv, const float* __restrict__ pos,
    const int* __restrict__ srcI, const int* __restrict__ dstI,
    const float* __restrict__ W1, float* stats_out, int* cnti,
    float* trace, float bit, int E, int Nn)
{
    trace_mark(trace, bit);
    __shared__ int ds[SB], ss[SB];
    __shared__ float dd[SB];
    __shared__ float ps[2][EMBD], pq[2][EMBD];

    const int tid = threadIdx.x;
    const int r0 = blockIdx.x * SB;

    if (tid < SB) {
        int e = r0 + tid; bool v = e < E; if (e >= E) e = E - 1;
        int dj = srcI[e], di = dstI[e];
        if ((u32)dj >= (u32)Nn) dj = 0;
        if ((u32)di >= (u32)Nn) di = 0;
        ds[tid] = di; ss[tid] = dj;
        float2 pj = *(const float2*)(pos + (size_t)dj * 2);
        float2 pi = *(const float2*)(pos + (size_t)di * 2);
        float dx = pj.x - pi.x, dy = pj.y - pi.y;
        dd[tid] = sqrtf(dx * dx + dy * dy);
        if (v) atomicAdd(&cnti[di], 1);
    }
    __syncthreads();

    const int c = tid & 127, hh = tid >> 7;
    const float w1d = W1[(size_t)(2 * EMBD) * EMBD + c];
    float S = 0.f, Q = 0.f;
#pragma unroll 4
    for (int i = 0; i < 64; ++i) {
        int el = hh * 64 + i;
        int e = r0 + el;
        if (e < E) {
            float u = (float)uv[(size_t)ds[el] * 256 + c];
            float v = (float)uv[(size_t)ss[el] * 256 + 128 + c];
            float t = fmaf(dd[el], w1d, u + v);
            S += t; Q += t * t;
        }
    }
    ps[hh][c] = S; pq[hh][c] = Q;
    __syncthreads();
    if (tid < EMBD) {
        atomicAdd(&stats_out[tid], ps[0][tid] + ps[1][tid]);
        atomicAdd(&stats_out[EMBD + tid], pq[0][tid] + pq[1][tid]);
    }
}
#undef SB

// ================================================================== k_scan
// Exclusive prefix sum of degree counts -> offs[0..N], cursor copy. 1 block.
__global__ __launch_bounds__(1024) void k_scan(
    const int* __restrict__ cnti, int* __restrict__ offs,
    int* __restrict__ cursor, float* trace, float bit, int Nn)
{
    trace_mark(trace, bit);
    __shared__ int buf[1024];
    __shared__ int carry_s;
    const int tid = threadIdx.x;
    if (tid == 0) carry_s = 0;
    __syncthreads();
    for (int base = 0; base < Nn; base += 1024) {
        int i = base + tid;
        int v = (i < Nn) ? cnti[i] : 0;
        buf[tid] = v;
        __syncthreads();
        for (int d = 1; d < 1024; d <<= 1) {
            int t = (tid >= d) ? buf[tid - d] : 0;
            __syncthreads();
            buf[tid] += t;
            __syncthreads();
        }
        int exc = buf[tid] - v + carry_s;
        if (i < Nn) { offs[i] = exc; cursor[i] = exc; }
        int total = buf[1023];
        __syncthreads();
        if (tid == 0) carry_s += total;
        __syncthreads();
    }
    if (tid == 0) offs[Nn] = carry_s;
}

// =============================================================== k_scatter
// eidx[cursor[dst]++] = e  (int atomics only, ~10-way contention).
__global__ __launch_bounds__(256) void k_scatter(
    const int* __restrict__ dstI, int* __restrict__ cursor,
    int* __restrict__ eidx, float* trace, float bit, int E, int Nn)
{
    trace_mark(trace, bit);
    int e = blockIdx.x * 256 + threadIdx.x;
    if (e >= E) return;
    int di = dstI[e];
    if ((u32)di >= (u32)Nn) di = 0;
    int p = atomicAdd(&cursor[di], 1);
    eidx[p] = e;
}

// ================================================================== k_g2
// Staged tier: rebuild a1 from UV, GEMM2 -> stats2, store raw t2 fp16.
__global__ __launch_bounds__(256) void k_g2(
    const f16* __restrict__ uv,
    const int* __restrict__ srcI, const int* __restrict__ dstI,
    const float* __restrict__ pos, const float* __restrict__ W1,
    const float* __restrict__ W2, const float* g1, const float* b1,
    const float* __restrict__ stats_in, float* stats_out,
    f16* __restrict__ t2out, float* trace, float bit, int E, int Nn)
{
    trace_mark(trace, bit);
    __shared__ float XsT[KC][TE];
    __shared__ float Ws[KC][EMBD];
    __shared__ float part_s[8][EMBD];
    __shared__ float part_q[8][EMBD];
    __shared__ float sA_s[EMBD], sA_c[EMBD];
    __shared__ int dst_s[TE], src_s[TE];
    __shared__ float dist_s[TE];

    const int tid = threadIdx.x;
    const int r0 = blockIdx.x * TE;
    int valid = E - r0; if (valid > TE) valid = TE;

    if (tid < EMBD) {
        const float invE = 1.f / (float)E;
        LOAD_AFF(stats_in, g1, b1, sA_s, sA_c, invE);
    }
    EDGE_META(1);
    __syncthreads();

    const int e_st = tid >> 3, kl = (tid & 7) << 2;
    const int kw = tid >> 3, cw = (tid & 7) << 4;
    const int e4 = (tid >> 5) << 2, c4 = (tid & 31) << 2;
    const int grp = tid >> 5;

    float acc[4][4];
#pragma unroll
    for (int i = 0; i < 4; ++i)
#pragma unroll
        for (int j = 0; j < 4; ++j) acc[i][j] = 0.f;

    for (int k0 = 0; k0 < EMBD; k0 += KC) {
        REBUILD_XST(k0);
        STAGE_W(W2, k0);
        __syncthreads();
        MMA32();
        __syncthreads();
    }

    STATS_TO(stats_out);

#pragma unroll
    for (int i = 0; i < 4; ++i)
        if (e4 + i < valid)
            st4h(t2out + (size_t)(r0 + e4 + i) * EMBD + c4,
                 make_float4(acc[i][0], acc[i][1], acc[i][2], acc[i][3]));
}

// ================================================================== k_aggr
// GATHER aggregation: h_aggr[n] = sum_{e in in(n)} relu(bn2(t2_raw[e])).
// One wave per node, lane = 2 channels; zero float atomics.
__global__ __launch_bounds__(256) void k_aggr(
    const f16* __restrict__ t2, const int* __restrict__ offs,
    const int* __restrict__ eidx,
    const float* g2, const float* b2, const float* __restrict__ stats_in,
    float* __restrict__ h_aggr, float* trace, float bit, int E, int Nn)
{
    trace_mark(trace, bit);
    __shared__ float sB_s[EMBD], sB_c[EMBD];
    const int tid = threadIdx.x;
    if (tid < EMBD) {
        const float invE = 1.f / (float)E;
        LOAD_AFF(stats_in, g2, b2, sB_s, sB_c, invE);
    }
    __syncthreads();

    const int lane = tid & 63;
    const int node = blockIdx.x * 4 + (tid >> 6);
    if (node >= Nn) return;

    const int c0 = lane * 2;
    const float s0 = sB_s[c0], s1 = sB_s[c0 + 1];
    const float cc0 = sB_c[c0], cc1 = sB_c[c0 + 1];
    const int o0 = offs[node], o1 = offs[node + 1];

    float a0 = 0.f, a1 = 0.f;
    for (int k = o0; k < o1; ++k) {
        int e = eidx[k];
        f16x2 xv = *(const f16x2*)(t2 + (size_t)e * EMBD + c0);
        a0 += fmaxf(fmaf((float)xv.x, s0, cc0), 0.f);
        a1 += fmaxf(fmaf((float)xv.y, s1, cc1), 0.f);
    }
    *(float2*)(h_aggr + (size_t)node * EMBD + c0) = make_float2(a0, a1);
}

// ================================================================== k_g3
// Staged tier, ATOMIC-FREE: BN2+ReLU(t2_raw) @ Wp1 -> stats3, t3 in-place.
__global__ __launch_bounds__(256) void k_g3(
    const f16* __restrict__ tin, const float* __restrict__ W,
    const float* g2, const float* b2,
    const float* __restrict__ stats_in, float* stats_out,
    f16* __restrict__ tout, float* trace, float bit, int E)
{
    trace_mark(trace, bit);
    __shared__ float XsT[KC][TE];
    __shared__ float Ws[KC][EMBD];
    __shared__ float part_s[8][EMBD];
    __shared__ float part_q[8][EMBD];
    __shared__ float sB_s[EMBD], sB_c[EMBD];

    const int tid = threadIdx.x;
    const int r0 = blockIdx.x * TE;
    int valid = E - r0; if (valid > TE) valid = TE;

    if (tid < EMBD) {
        const float invE = 1.f / (float)E;
        LOAD_AFF(stats_in, g2, b2, sB_s, sB_c, invE);
    }
    __syncthreads();

    const int e_st = tid >> 3, kl = (tid & 7) << 2;
    const int kw = tid >> 3, cw = (tid & 7) << 4;
    const int e4 = (tid >> 5) << 2, c4 = (tid & 31) << 2;
    const int grp = tid >> 5;

    float acc[4][4];
#pragma unroll
    for (int i = 0; i < 4; ++i)
#pragma unroll
        for (int j = 0; j < 4; ++j) acc[i][j] = 0.f;

    for (int k0 = 0; k0 < EMBD; k0 += KC) {
        {
            int e = r0 + e_st; if (e >= E) e = E - 1;
            int k = k0 + kl;
            float4 x = ld4h(tin + (size_t)e * EMBD + k);
            XsT[kl + 0][e_st] = fmaxf(fmaf(x.x, sB_s[k + 0], sB_c[k + 0]), 0.f);
            XsT[kl + 1][e_st] = fmaxf(fmaf(x.y, sB_s[k + 1], sB_c[k + 1]), 0.f);
            XsT[kl + 2][e_st] = fmaxf(fmaf(x.z, sB_s[k + 2], sB_c[k + 2]), 0.f);
            XsT[kl + 3][e_st] = fmaxf(fmaf(x.w, sB_s[k + 3], sB_c[k + 3]), 0.f);
        }
        STAGE_W(W, k0);
        __syncthreads();
        MMA32();
        __syncthreads();
    }

    STATS_TO(stats_out);

#pragma unroll
    for (int i = 0; i < 4; ++i)
        if (e4 + i < valid)
            st4h(tout + (size_t)(r0 + e4 + i) * EMBD + c4,
                 make_float4(acc[i][0], acc[i][1], acc[i][2], acc[i][3]));
}

// ================================================================== k_dot
// Staged tier: t4 = relu(bn3(t3_raw)) . Wp2 ; scalar stats.
__global__ __launch_bounds__(256) void k_dot(
    const f16* __restrict__ t3, const float* __restrict__ Wp2,
    const float* g3, const float* b3,
    const float* __restrict__ stats_in, float* stats_out, float* t4,
    float* trace, float bit, int E)
{
    trace_mark(trace, bit);
    __shared__ float sC_s[EMBD], sC_c[EMBD];
    __shared__ float red[256];
    __shared__ float dotbuf[TE];

    const int tid = threadIdx.x;
    const int r0 = blockIdx.x * TE;
    int valid = E - r0; if (valid > TE) valid = TE;

    if (tid < EMBD) {
        const float invE = 1.f / (float)E;
        LOAD_AFF(stats_in, g3, b3, sC_s, sC_c, invE);
    }
    __syncthreads();

    const int row = tid >> 3, c0 = (tid & 7) << 4;
    int e = r0 + row; if (e >= E) e = E - 1;
    const f16* tp = t3 + (size_t)e * EMBD + c0;

    float part = 0.f;
#pragma unroll
    for (int q = 0; q < 4; ++q) {
        float4 x = ld4h(tp + q * 4);
        float4 w = *(const float4*)(Wp2 + c0 + q * 4);
        int c = c0 + q * 4;
        part = fmaf(fmaxf(fmaf(x.x, sC_s[c + 0], sC_c[c + 0]), 0.f), w.x, part);
        part = fmaf(fmaxf(fmaf(x.y, sC_s[c + 1], sC_c[c + 1]), 0.f), w.y, part);
        part = fmaf(fmaxf(fmaf(x.z, sC_s[c + 2], sC_c[c + 2]), 0.f), w.z, part);
        part = fmaf(fmaxf(fmaf(x.w, sC_s[c + 3], sC_c[c + 3]), 0.f), w.w, part);
    }
    red[tid] = part;
    __syncthreads();
    if ((tid & 7) == 0) {
        float dot = red[tid] + red[tid+1] + red[tid+2] + red[tid+3]
                  + red[tid+4] + red[tid+5] + red[tid+6] + red[tid+7];
        dotbuf[row] = dot;
        if (row < valid) t4[r0 + row] = dot;
    }
    __syncthreads();
    if (tid == 0) {
        float S = 0.f, Q = 0.f;
        for (int r = 0; r < valid; ++r) { float d = dotbuf[r]; S += d; Q += d * d; }
        atomicAdd(&stats_out[0], S);
        atomicAdd(&stats_out[EMBD], Q);
    }
}

// ============================================================= k_pos_aggr
// GATHER: x_aggr[n] = mean_{e in in(n)} (pos[src]-pos[n]) * relu(bn4(t4[e])).
// One wave per node; wave-reduce; zero atomics; writes the MEAN directly.
__global__ __launch_bounds__(256) void k_pos_aggr(
    const float* __restrict__ t4, const int* __restrict__ offs,
    const int* __restrict__ eidx, const int* __restrict__ srcI,
    const float* __restrict__ pos, const float* __restrict__ stats_base,
    const float* gp2, const float* bbp2,
    float* __restrict__ x_aggr, float* trace, float bit, int E, int Nn)
{
    trace_mark(trace, bit);
    const int tid = threadIdx.x;
    const int lane = tid & 63;
    const int node = blockIdx.x * 4 + (tid >> 6);
    if (node >= Nn) return;

    const float invE = 1.f / (float)E;
    float m = stats_base[768] * invE;
    float v = fmaxf(stats_base[768 + EMBD] * invE - m * m, 0.f);
    float s3 = gp2[0] * rsqrtf(v + BN_EPS);
    float c3 = bbp2[0] - m * s3;

    const int o0 = offs[node], o1 = offs[node + 1];
    float2 pi = *(const float2*)(pos + (size_t)node * 2);
    float ax = 0.f, ay = 0.f;
    for (int k = o0 + lane; k < o1; k += 64) {
        int e = eidx[k];
        float s = fmaxf(fmaf(t4[e], s3, c3), 0.f);
        int j = srcI[e];
        if ((u32)j >= (u32)Nn) j = 0;
        float2 pj = *(const float2*)(pos + (size_t)j * 2);
        ax += (pj.x - pi.x) * s;
        ay += (pj.y - pi.y) * s;
    }
#pragma unroll
    for (int off = 32; off; off >>= 1) {
        ax += __shfl_down(ax, off, 64);
        ay += __shfl_down(ay, off, 64);
    }
    if (lane == 0) {
        float inv = 1.f / fmaxf((float)(o1 - o0), 1.f);
        *(float2*)(x_aggr + (size_t)node * 2) = make_float2(ax * inv, ay * inv);
    }
}

// ============================================================== k_edge_rc
// Recompute tier (small ws): rebuild a1 from UV each launch, run GEMM2
// (DEPTH>=2), GEMM3 (DEPTH>=3, h_aggr atomics at ==3), dot (DEPTH==4).
template<int DEPTH>
__global__ __launch_bounds__(256) void k_edge_rc(
    const f16* __restrict__ uv,
    const int* __restrict__ srcI, const int* __restrict__ dstI,
    const float* __restrict__ pos,
    const float* __restrict__ W1, const float* __restrict__ W2,
    const float* __restrict__ W3, const float* __restrict__ Wp2,
    const float* g1, const float* b1, const float* g2, const float* b2,
    const float* g3, const float* b3,
    const float* __restrict__ stats_base, float* stats_out,
    float* h_aggr, float* t4_out,
    float* trace, float bit, int E, int Nn)
{
    trace_mark(trace, bit);
    __shared__ float XsT[KC][TE];
    __shared__ float Ws[KC][EMBD];
    __shared__ float A[(DEPTH >= 3) ? TE : 1][EMBD + 4];
    __shared__ float part_s[8][EMBD];
    __shared__ float part_q[8][EMBD];
    __shared__ float red[(DEPTH >= 4) ? 256 : 1];
    __shared__ float dotbuf[(DEPTH >= 4) ? TE : 1];
    __shared__ float sA_s[EMBD], sA_c[EMBD];
    __shared__ float sB_s[(DEPTH >= 3) ? EMBD : 1], sB_c[(DEPTH >= 3) ? EMBD : 1];
    __shared__ float sC_s[(DEPTH >= 4) ? EMBD : 1], sC_c[(DEPTH >= 4) ? EMBD : 1];
    __shared__ int dst_s[TE], src_s[TE];
    __shared__ float dist_s[TE];

    const int tid = threadIdx.x;
    const int r0 = blockIdx.x * TE;
    int valid = E - r0; if (valid > TE) valid = TE;

    if (tid < EMBD) {
        const float invE = 1.f / (float)E;
        LOAD_AFF(stats_base, g1, b1, sA_s, sA_c, invE);
        if (DEPTH >= 3) LOAD_AFF(stats_base + 256, g2, b2, sB_s, sB_c, invE);
        if (DEPTH >= 4) LOAD_AFF(stats_base + 512, g3, b3, sC_s, sC_c, invE);
    }
    EDGE_META(1);
    __syncthreads();

    const int e_st = tid >> 3, kl = (tid & 7) << 2;
    const int kw = tid >> 3, cw = (tid & 7) << 4;
    const int e4 = (tid >> 5) << 2, c4 = (tid & 31) << 2;
    const int grp = tid >> 5;

    float acc[4][4];
#pragma unroll
    for (int i = 0; i < 4; ++i)
#pragma unroll
        for (int j = 0; j < 4; ++j) acc[i][j] = 0.f;

    // rebuild a1 + GEMM2
    for (int k0 = 0; k0 < EMBD; k0 += KC) {
        REBUILD_XST(k0);
        STAGE_W(W2, k0);
        __syncthreads();
        MMA32();
        __syncthreads();
    }

    if (DEPTH == 2) { STATS_TO(stats_out); return; }

    // BN2 -> A (+aggr at DEPTH==3)
#pragma unroll
    for (int i = 0; i < 4; ++i) {
        float4 o;
#pragma unroll
        for (int j = 0; j < 4; ++j) {
            float v = fmaxf(fmaf(acc[i][j], sB_s[c4 + j], sB_c[c4 + j]), 0.f);
            (&o.x)[j] = v;
            if (DEPTH == 3 && (e4 + i) < valid)
                atomicAdd(&h_aggr[(size_t)dst_s[e4 + i] * EMBD + c4 + j], v);
        }
        *(float4*)&A[e4 + i][c4] = o;
    }
    __syncthreads();

    // GEMM3 from A
#pragma unroll
    for (int i = 0; i < 4; ++i)
#pragma unroll
        for (int j = 0; j < 4; ++j) acc[i][j] = 0.f;
    for (int k0 = 0; k0 < EMBD; k0 += KC) {
        STAGE_W(W3, k0);
        __syncthreads();
#pragma unroll 8
        for (int kk = 0; kk < KC; ++kk) {
            float4 wv4 = *(const float4*)&Ws[kk][c4];
            float wv[4] = {wv4.x, wv4.y, wv4.z, wv4.w};
            float xv[4];
#pragma unroll
            for (int i = 0; i < 4; ++i) xv[i] = A[e4 + i][k0 + kk];
#pragma unroll
            for (int i = 0; i < 4; ++i)
#pragma unroll
                for (int j = 0; j < 4; ++j) acc[i][j] = fmaf(xv[i], wv[j], acc[i][j]);
        }
        __syncthreads();
    }

    if (DEPTH == 3) { STATS_TO(stats_out); return; }

    // BN3 -> A, then dot with Wp2
#pragma unroll
    for (int i = 0; i < 4; ++i) {
        float4 o;
#pragma unroll
        for (int j = 0; j < 4; ++j)
            (&o.x)[j] = fmaxf(fmaf(acc[i][j], sC_s[c4 + j], sC_c[c4 + j]), 0.f);
        *(float4*)&A[e4 + i][c4] = o;
    }
    __syncthreads();

    {
        const int row = tid >> 3, c0 = (tid & 7) << 4;
        float w[16];
        *(float4*)(w + 0)  = *(const float4*)(Wp2 + c0);
        *(float4*)(w + 4)  = *(const float4*)(Wp2 + c0 + 4);
        *(float4*)(w + 8)  = *(const float4*)(Wp2 + c0 + 8);
        *(float4*)(w + 12) = *(const float4*)(Wp2 + c0 + 12);
        float part = 0.f;
#pragma unroll
        for (int c = 0; c < 16; ++c) part = fmaf(A[row][c0 + c], w[c], part);
        red[tid] = part;
        __syncthreads();
        if ((tid & 7) == 0) {
            float dot = red[tid] + red[tid+1] + red[tid+2] + red[tid+3]
                      + red[tid+4] + red[tid+5] + red[tid+6] + red[tid+7];
            dotbuf[row] = dot;
            if (row < valid) t4_out[r0 + row] = dot;
        }
        __syncthreads();
        if (tid == 0) {
            float S = 0.f, Q = 0.f;
            for (int r = 0; r < valid; ++r) { float d = dotbuf[r]; S += d; Q += d * d; }
            atomicAdd(&stats_out[0], S);
            atomicAdd(&stats_out[EMBD], Q);
        }
    }
}

// =============================================================== node GEMM
// t5 = [h, h_aggr] @ Wu1; stats -> stats_out; raw t5 into out (overwrites UV).
__global__ __launch_bounds__(256) void k_upd(
    const float* h, const float* h_aggr, const float* W,
    float* stats_out, float* t5, float* trace, float bit, int Nn)
{
    trace_mark(trace, bit);
    __shared__ float XsT[KC][TE];
    __shared__ float Ws[KC][EMBD];
    __shared__ float part_s[8][EMBD];
    __shared__ float part_q[8][EMBD];

    const int tid = threadIdx.x;
    const int r0 = blockIdx.x * TE;
    int valid = Nn - r0; if (valid > TE) valid = TE;

    float acc[4][4];
#pragma unroll
    for (int i = 0; i < 4; ++i)
#pragma unroll
        for (int j = 0; j < 4; ++j) acc[i][j] = 0.f;

    const int e_st = tid >> 3, kl = (tid & 7) << 2;
    const int kw = tid >> 3, cw = (tid & 7) << 4;
    const int e4 = (tid >> 5) << 2, c4 = (tid & 31) << 2;
    const int grp = tid >> 5;

    for (int k0 = 0; k0 < 2 * EMBD; k0 += KC) {
        {
            float4 x = make_float4(0.f, 0.f, 0.f, 0.f);
            if (e_st < valid) {
                int k = k0 + kl;
                int row = r0 + e_st;
                const float* base = (k < EMBD)
                    ? h + (size_t)row * EMBD + k
                    : h_aggr + (size_t)row * EMBD + (k - EMBD);
                x = *(const float4*)base;
            }
            XsT[kl + 0][e_st] = x.x; XsT[kl + 1][e_st] = x.y;
            XsT[kl + 2][e_st] = x.z; XsT[kl + 3][e_st] = x.w;
        }
        STAGE_W(W, k0);
        __syncthreads();
        MMA32();
        __syncthreads();
    }

    STATS_TO(stats_out);

#pragma unroll
    for (int i = 0; i < 4; ++i) {
        int row = r0 + e4 + i;
        if (e4 + i < valid)
            *(float4*)(t5 + (size_t)row * EMBD + c4) =
                make_float4(acc[i][0], acc[i][1], acc[i][2], acc[i][3]);
    }
}

// ---------------------------------------------------------------- epilogue
// x_aggr already holds the MEAN pos delta.
__global__ __launch_bounds__(256) void k_final(
    const float* h, const float* pos, const float* stats5,
    const float* gu1, const float* bbu1,
    const float* x_aggr, const float* trace,
    float* out, int N, float expect)
{
    __shared__ float s4[EMBD], cc4[EMBD];
    int tid = threadIdx.x;
    if (tid < EMBD) {
        const float invN = 1.f / (float)N;
        float m = stats5[tid] * invN;
        float v = fmaxf(stats5[EMBD + tid] * invN - m * m, 0.f);
        float s = gu1[tid] * rsqrtf(v + BN_EPS);
        s4[tid] = s; cc4[tid] = bbu1[tid] - m * s;
    }
    __syncthreads();
    int n = blockIdx.x * 2 + (tid >> 7);
    int c = tid & 127;
    if (n >= N) return;
    float hv = h[(size_t)n * EMBD + c];
    float t = out[(size_t)n * EMBD + c];
    float res = sane(hv + fmaxf(fmaf(t, s4[c], cc4[c]), 0.f), 100.f);
    if (n == 0 && c == 1) {
        float tr = trace[0];
        if (fabsf(tr - expect) > 0.5f) res = 1048576.0f + tr * 64.0f;
    }
    out[(size_t)n * EMBD + c] = res;
    if (c < 2) {
        float p = pos[(size_t)n * 2 + c];
        float xa = x_aggr[(size_t)n * 2 + c];
        out[(size_t)N * EMBD + (size_t)n * 2 + c] = sane(p + xa, 100.f);
    }
}

// ================================================================= launch
extern "C" void kernel_launch(void* const* d_in, const int* in_sizes, int n_in,
                              void* d_out, int out_size, void* d_ws, size_t ws_size,
                              hipStream_t stream)
{
    const float* h   = (const float*)d_in[0];
    const float* pos = (const float*)d_in[1];
    const int* ei    = (const int*)d_in[3];
    const float* Wm1 = (const float*)d_in[4];
    const float* gm1 = (const float*)d_in[6];
    const float* bbm1= (const float*)d_in[7];
    const float* Wm2 = (const float*)d_in[8];
    const float* gm2 = (const float*)d_in[10];
    const float* bbm2= (const float*)d_in[11];
    const float* Wp1 = (const float*)d_in[12];
    const float* gp1 = (const float*)d_in[14];
    const float* bbp1= (const float*)d_in[15];
    const float* Wp2 = (const float*)d_in[16];
    const float* gp2 = (const float*)d_in[18];
    const float* bbp2= (const float*)d_in[19];
    const float* Wu1 = (const float*)d_in[20];
    const float* gu1 = (const float*)d_in[22];
    const float* bbu1= (const float*)d_in[23];

    const int N = in_sizes[0] / EMBD;
    const int E = in_sizes[3] / 2;
    const int* srcI = ei;
    const int* dstI = ei + E;

    size_t off = 0;
    auto carve = [&](size_t bytes) -> size_t {
        size_t o = off; off += (bytes + 255) & ~(size_t)255; return o;
    };
    size_t o_stats  = carve(5 * 256 * sizeof(float));
    size_t o_trace  = carve(256);
    size_t o_cnti   = carve((size_t)N * sizeof(int));
    size_t o_haggr  = carve((size_t)N * EMBD * sizeof(float));
    size_t zero_need = off;                                  // ~25.9 MB
    size_t o_xaggr  = carve((size_t)N * 2 * sizeof(float));
    size_t o_t4     = carve((size_t)E * sizeof(float));
    size_t o_offs   = carve((size_t)(N + 1) * sizeof(int));
    size_t o_cursor = carve((size_t)N * sizeof(int));
    size_t o_eidx   = carve((size_t)E * sizeof(int));
    size_t base_need = off;                                  // ~31 MB
    size_t o_ebuf   = carve((size_t)E * EMBD * sizeof(f16)); // +128 MB
    size_t need_staged = off;

    float* out_f = (float*)d_out;

    if (ws_size < base_need) {
        k_fill<<<(out_size + 255) / 256, 256, 0, stream>>>(out_f, 12345678.0f, out_size);
        return;
    }

    char* wsb = (char*)d_ws;
    float* stats  = (float*)(wsb + o_stats);
    float* trace  = (float*)(wsb + o_trace);
    int*   cnti   = (int*)(wsb + o_cnti);
    float* h_aggr = (float*)(wsb + o_haggr);
    float* x_aggr = (float*)(wsb + o_xaggr);
    float* t4     = (float*)(wsb + o_t4);
    int*   offs   = (int*)(wsb + o_offs);
    int*   cursor = (int*)(wsb + o_cursor);
    int*   eidx   = (int*)(wsb + o_eidx);
    f16*   uv     = (f16*)d_out;   // N*256 fp16 = N*512B <= out bytes (N*520B)

    hipMemsetAsync(d_ws, 0, zero_need, stream);

    const int gPE = (E + 255) / 256;
    const int gE  = (E + TE - 1) / TE;
    const int gN  = (N + TE - 1) / TE;
    const int gS1 = (E + 127) / 128;
    const int gW  = (N + 3) / 4;

    k_uv<<<gN, 256, 0, stream>>>(h, Wm1, uv, trace, 1.0f, N);
    k_stats1<<<gS1, 256, 0, stream>>>(uv, pos, srcI, dstI, Wm1,
                                      stats, cnti, trace, 2.0f, E, N);
    k_scan<<<1, 1024, 0, stream>>>(cnti, offs, cursor, trace, 4.0f, N);
    k_scatter<<<gPE, 256, 0, stream>>>(dstI, cursor, eidx, trace, 8.0f, E, N);

    if (ws_size >= need_staged) {
        f16* eb = (f16*)(wsb + o_ebuf);
        k_g2<<<gE, 256, 0, stream>>>(uv, srcI, dstI, pos, Wm1, Wm2, gm1, bbm1,
                                     stats, stats + 256, eb, trace, 16.0f, E, N);
        k_aggr<<<gW, 256, 0, stream>>>(eb, offs, eidx, gm2, bbm2, stats + 256,
                                       h_aggr, trace, 32.0f, E, N);
        k_g3<<<gE, 256, 0, stream>>>(eb, Wp1, gm2, bbm2,
                                     stats + 256, stats + 512,
                                     eb, trace, 64.0f, E);
        k_dot<<<gE, 256, 0, stream>>>(eb, Wp2, gp1, bbp1,
                                      stats + 512, stats + 768, t4,
                                      trace, 128.0f, E);
    } else {
        k_edge_rc<2><<<gE, 256, 0, stream>>>(uv, srcI, dstI, pos,
                                             Wm1, Wm2, Wp1, Wp2,
                                             gm1, bbm1, gm2, bbm2, gp1, bbp1,
                                             stats, stats + 256, h_aggr, t4,
                                             trace, 16.0f, E, N);
        k_edge_rc<3><<<gE, 256, 0, stream>>>(uv, srcI, dstI, pos,
                                             Wm1, Wm2, Wp1, Wp2,
                                             gm1, bbm1, gm2, bbm2, gp1, bbp1,
                                             stats, stats + 512, h_aggr, t4,
                                             trace, 96.0f, E, N);
        k_edge_rc<4><<<gE, 256, 0, stream>>>(uv, srcI, dstI, pos,
                                             Wm1, Wm2, Wp1, Wp2,
                                             gm1, bbm1, gm2, bbm2, gp1, bbp1,
                                             stats, stats + 768, h_aggr, t4,
                                             trace, 128.0f, E, N);
    }

    k_pos_aggr<<<gW, 256, 0, stream>>>(t4, offs, eidx, srcI, pos,
                                       stats, gp2, bbp2, x_aggr,
                                       trace, 256.0f, E, N);
    k_upd<<<gN, 256, 0, stream>>>(h, h_aggr, Wu1, stats + 1024, out_f,
                                  trace, 512.0f, N);
    k_final<<<(N + 1) / 2, 256, 0, stream>>>(h, pos, stats + 1024, gu1, bbu1,
                                             x_aggr, trace, out_f, N, 1023.0f);
}

// Round 4
// 1225.227 us; speedup vs baseline: 3.1013x; 1.3380x over previous
//
#include <hip/hip_runtime.h>
#include <hip/hip_bf16.h>

// SpatialNCA, MI355X. R12: MFMA edge GEMMs. R11 counters: k_g3 464us @
// MfmaUtil 0, VALUBusy 32% — f32 VALU GEMM is the bottleneck and inputs are
// already fp16. k_g2m/k_g3m use v_mfma_f32_16x16x32_f16: A-frags built in
// registers (lane&15=row, lane>>4=k-octet), B pre-transposed to frag-slot
// order by k_prep (fp16, 32KB, LDS linear-staged), C repacked via LDS for
// coalesced stores, stats via shfl_xor butterflies. k_dot/k_aggr/CSR/epilogue
// unchanged from R11. Trace fail-closed: staged expect=2047, rc expect=1663.

#define EMBD 128
#define TE 32
#define KC 32
#define BN_EPS 1e-5f

typedef unsigned int u32;
typedef _Float16 f16;
typedef _Float16 hf8_t __attribute__((ext_vector_type(8)));
typedef float fx4_t __attribute__((ext_vector_type(4)));

__device__ __forceinline__ bool finitef(float f) {
    union { float f; u32 i; } v; v.f = f;
    return ((v.i >> 23) & 0xFFu) != 0xFFu;
}
__device__ __forceinline__ float sane(float f, float lim) {
    if (!finitef(f)) return 0.f;
    return fminf(fmaxf(f, -lim), lim);
}
__device__ __forceinline__ void trace_mark(float* tp, float bit) {
    if (blockIdx.x == 0 && threadIdx.x == 0) atomicAdd(tp, bit);
}

struct f16x4 { f16 a, b, c, d; };
struct alignas(4) f16x2 { f16 x, y; };
__device__ __forceinline__ float4 ld4h(const f16* p) {
    f16x4 t = *(const f16x4*)p;
    return make_float4((float)t.a, (float)t.b, (float)t.c, (float)t.d);
}
__device__ __forceinline__ void st4h(f16* p, float4 v) {
    f16x4 t; t.a = (f16)v.x; t.b = (f16)v.y; t.c = (f16)v.z; t.d = (f16)v.w;
    *(f16x4*)p = t;
}

// ---------------------------------------------------------------- sentinel
__global__ __launch_bounds__(256) void k_fill(float* out, float val, int n) {
    int i = blockIdx.x * 256 + threadIdx.x;
    if (i < n) out[i] = val;
}

// ------------------------------------------------------------ shared macros
#define STAGE_W(WPTR, K0) { \
        const float* wp = (WPTR) + (size_t)((K0) + kw) * EMBD + cw; \
        float4 wa = *(const float4*)wp; \
        float4 wb = *(const float4*)(wp + 4); \
        float4 wc = *(const float4*)(wp + 8); \
        float4 wdv = *(const float4*)(wp + 12); \
        float* wd = &Ws[kw][cw]; \
        *(float4*)(wd + 0) = wa; *(float4*)(wd + 4) = wb; \
        *(float4*)(wd + 8) = wc; *(float4*)(wd + 12) = wdv; }

#define MMA32() { \
        _Pragma("unroll 8") \
        for (int kk = 0; kk < KC; ++kk) { \
            float4 xv4 = *(const float4*)&XsT[kk][e4]; \
            float4 wv4 = *(const float4*)&Ws[kk][c4]; \
            float xv[4] = {xv4.x, xv4.y, xv4.z, xv4.w}; \
            float wv[4] = {wv4.x, wv4.y, wv4.z, wv4.w}; \
            for (int i = 0; i < 4; ++i) \
                for (int j = 0; j < 4; ++j) acc[i][j] = fmaf(xv[i], wv[j], acc[i][j]); } }

#define STATS_TO(SOUT) { \
        __syncthreads(); \
        for (int j = 0; j < 4; ++j) { \
            float s = 0.f, q = 0.f; \
            for (int i = 0; i < 4; ++i) \
                if (e4 + i < valid) { float a = acc[i][j]; s += a; q += a * a; } \
            part_s[grp][c4 + j] = s; part_q[grp][c4 + j] = q; \
        } \
        __syncthreads(); \
        if (tid < EMBD) { \
            float S = 0.f, Q = 0.f; \
            for (int g = 0; g < 8; ++g) { S += part_s[g][tid]; Q += part_q[g][tid]; } \
            atomicAdd(&(SOUT)[tid], S); \
            atomicAdd(&(SOUT)[EMBD + tid], Q); } }

#define LOAD_AFF(SRC, GG, BB, SS, CC, DEN) { \
        float m_ = (SRC)[tid] * (DEN); \
        float v_ = fmaxf((SRC)[EMBD + tid] * (DEN) - m_ * m_, 0.f); \
        float s_ = (GG)[tid] * rsqrtf(v_ + BN_EPS); \
        (SS)[tid] = s_; (CC)[tid] = (BB)[tid] - m_ * s_; }

// Rebuild post-BN1 a1 into XsT from UV (fp16) + dist.  (rc fallback only)
#define REBUILD_XST(K0) { \
        int k = (K0) + kl; \
        float4 u4 = ld4h(uv + (size_t)dst_s[e_st] * 256 + k); \
        float4 v4 = ld4h(uv + (size_t)src_s[e_st] * 256 + 128 + k); \
        float4 wd = *(const float4*)(W1 + (size_t)(2 * EMBD) * EMBD + k); \
        float dd_ = dist_s[e_st]; \
        float r0_ = fmaf(dd_, wd.x, u4.x + v4.x); \
        float r1_ = fmaf(dd_, wd.y, u4.y + v4.y); \
        float r2_ = fmaf(dd_, wd.z, u4.z + v4.z); \
        float r3_ = fmaf(dd_, wd.w, u4.w + v4.w); \
        XsT[kl + 0][e_st] = fmaxf(fmaf(r0_, sA_s[k + 0], sA_c[k + 0]), 0.f); \
        XsT[kl + 1][e_st] = fmaxf(fmaf(r1_, sA_s[k + 1], sA_c[k + 1]), 0.f); \
        XsT[kl + 2][e_st] = fmaxf(fmaf(r2_, sA_s[k + 2], sA_c[k + 2]), 0.f); \
        XsT[kl + 3][e_st] = fmaxf(fmaf(r3_, sA_s[k + 3], sA_c[k + 3]), 0.f); }

#define EDGE_META(WITH_SRC) { \
        if (tid < TE) { \
            int e = r0 + tid; if (e >= E) e = E - 1; \
            int dj = srcI[e], di = dstI[e]; \
            if ((u32)dj >= (u32)Nn) dj = 0; \
            if ((u32)di >= (u32)Nn) di = 0; \
            dst_s[tid] = di; \
            if (WITH_SRC) { \
                src_s[tid] = dj; \
                float2 pj = *(const float2*)(pos + (size_t)dj * 2); \
                float2 pi = *(const float2*)(pos + (size_t)di * 2); \
                float dx = pj.x - pi.x, dy = pj.y - pi.y; \
                dist_s[tid] = sqrtf(dx * dx + dy * dy); } } }

// ================================================================== k_uv
// U = h @ W1[0:128] (dst part), V = h @ W1[128:256] (src part), fp16 out.
__global__ __launch_bounds__(256) void k_uv(
    const float* __restrict__ h, const float* __restrict__ W1,
    f16* __restrict__ uv, float* trace, float bit, int Nn)
{
    trace_mark(trace, bit);
    __shared__ float XsT[KC][TE];
    __shared__ float Ws[KC][EMBD];

    const int tid = threadIdx.x;
    const int r0 = blockIdx.x * TE;
    int valid = Nn - r0; if (valid > TE) valid = TE;

    const int e_st = tid >> 3, kl = (tid & 7) << 2;
    const int kw = tid >> 3, cw = (tid & 7) << 4;
    const int e4 = (tid >> 5) << 2, c4 = (tid & 31) << 2;

    for (int pass = 0; pass < 2; ++pass) {
        float acc[4][4];
#pragma unroll
        for (int i = 0; i < 4; ++i)
#pragma unroll
            for (int j = 0; j < 4; ++j) acc[i][j] = 0.f;

        const float* Wp = W1 + (size_t)pass * EMBD * EMBD;
        for (int k0 = 0; k0 < EMBD; k0 += KC) {
            {
                float4 x = make_float4(0.f, 0.f, 0.f, 0.f);
                if (e_st < valid)
                    x = *(const float4*)(h + (size_t)(r0 + e_st) * EMBD + k0 + kl);
                XsT[kl + 0][e_st] = x.x; XsT[kl + 1][e_st] = x.y;
                XsT[kl + 2][e_st] = x.z; XsT[kl + 3][e_st] = x.w;
            }
            STAGE_W(Wp, k0);
            __syncthreads();
            MMA32();
            __syncthreads();
        }
#pragma unroll
        for (int i = 0; i < 4; ++i)
            if (e4 + i < valid)
                st4h(uv + (size_t)(r0 + e4 + i) * 256 + pass * EMBD + c4,
                     make_float4(acc[i][0], acc[i][1], acc[i][2], acc[i][3]));
    }
}

// =============================================================== k_stats1
// stats1 over t1[e] = U[dst]+V[src]+dist*w1d; int degree counts for CSR.
#define SB 128
__global__ __launch_bounds__(256) void k_stats1(
    const f16* __restrict__ uv, const float* __restrict__ pos,
    const int* __restrict__ srcI, const int* __restrict__ dstI,
    const float* __restrict__ W1, float* stats_out, int* cnti,
    float* trace, float bit, int E, int Nn)
{
    trace_mark(trace, bit);
    __shared__ int ds[SB], ss[SB];
    __shared__ float dd[SB];
    __shared__ float ps[2][EMBD], pq[2][EMBD];

    const int tid = threadIdx.x;
    const int r0 = blockIdx.x * SB;

    if (tid < SB) {
        int e = r0 + tid; bool v = e < E; if (e >= E) e = E - 1;
        int dj = srcI[e], di = dstI[e];
        if ((u32)dj >= (u32)Nn) dj = 0;
        if ((u32)di >= (u32)Nn) di = 0;
        ds[tid] = di; ss[tid] = dj;
        float2 pj = *(const float2*)(pos + (size_t)dj * 2);
        float2 pi = *(const float2*)(pos + (size_t)di * 2);
        float dx = pj.x - pi.x, dy = pj.y - pi.y;
        dd[tid] = sqrtf(dx * dx + dy * dy);
        if (v) atomicAdd(&cnti[di], 1);
    }
    __syncthreads();

    const int c = tid & 127, hh = tid >> 7;
    const float w1d = W1[(size_t)(2 * EMBD) * EMBD + c];
    float S = 0.f, Q = 0.f;
#pragma unroll 4
    for (int i = 0; i < 64; ++i) {
        int el = hh * 64 + i;
        int e = r0 + el;
        if (e < E) {
            float u = (float)uv[(size_t)ds[el] * 256 + c];
            float v = (float)uv[(size_t)ss[el] * 256 + 128 + c];
            float t = fmaf(dd[el], w1d, u + v);
            S += t; Q += t * t;
        }
    }
    ps[hh][c] = S; pq[hh][c] = Q;
    __syncthreads();
    if (tid < EMBD) {
        atomicAdd(&stats_out[tid], ps[0][tid] + ps[1][tid]);
        atomicAdd(&stats_out[EMBD + tid], pq[0][tid] + pq[1][tid]);
    }
}
#undef SB

// ================================================================== k_scan
__global__ __launch_bounds__(1024) void k_scan(
    const int* __restrict__ cnti, int* __restrict__ offs,
    int* __restrict__ cursor, float* trace, float bit, int Nn)
{
    trace_mark(trace, bit);
    __shared__ int buf[1024];
    __shared__ int carry_s;
    const int tid = threadIdx.x;
    if (tid == 0) carry_s = 0;
    __syncthreads();
    for (int base = 0; base < Nn; base += 1024) {
        int i = base + tid;
        int v = (i < Nn) ? cnti[i] : 0;
        buf[tid] = v;
        __syncthreads();
        for (int d = 1; d < 1024; d <<= 1) {
            int t = (tid >= d) ? buf[tid - d] : 0;
            __syncthreads();
            buf[tid] += t;
            __syncthreads();
        }
        int exc = buf[tid] - v + carry_s;
        if (i < Nn) { offs[i] = exc; cursor[i] = exc; }
        int total = buf[1023];
        __syncthreads();
        if (tid == 0) carry_s += total;
        __syncthreads();
    }
    if (tid == 0) offs[Nn] = carry_s;
}

// =============================================================== k_scatter
__global__ __launch_bounds__(256) void k_scatter(
    const int* __restrict__ dstI, int* __restrict__ cursor,
    int* __restrict__ eidx, float* trace, float bit, int E, int Nn)
{
    trace_mark(trace, bit);
    int e = blockIdx.x * 256 + threadIdx.x;
    if (e >= E) return;
    int di = dstI[e];
    if ((u32)di >= (u32)Nn) di = 0;
    int p = atomicAdd(&cursor[di], 1);
    eidx[p] = e;
}

// ================================================================== k_prep
// Transpose W2/Wp1 to fp16 MFMA B-frag-slot order:
//   wtf[((k>>3)*128 + n)*8 + (k&7)] = (f16)W[k*128 + n]
__global__ __launch_bounds__(256) void k_prep(
    const float* __restrict__ W2, const float* __restrict__ Wp1,
    f16* __restrict__ wtf2, f16* __restrict__ wtf3, float* trace, float bit)
{
    trace_mark(trace, bit);
    int id = blockIdx.x * 256 + threadIdx.x;   // 64 blocks -> 16384
    int k = id >> 7, n = id & 127;
    size_t s = ((size_t)(k >> 3) * 128 + n) * 8 + (k & 7);
    wtf2[s] = (f16)W2[(size_t)k * 128 + n];
    wtf3[s] = (f16)Wp1[(size_t)k * 128 + n];
}

// ================================================================== k_g2m
// MFMA GEMM2: a1 = relu(bn1(U[dst]+V[src]+dist*w1d)) built per-lane as
// A-frags; t2_raw = a1 @ W2 via mfma_f32_16x16x32_f16; stats2; t2 fp16 out.
// Block: 64 rows x 128 cols, 4 waves each 16 rows x 128 cols.
__global__ __launch_bounds__(256) void k_g2m(
    const f16* __restrict__ uv,
    const int* __restrict__ srcI, const int* __restrict__ dstI,
    const float* __restrict__ pos, const float* __restrict__ W1,
    const f16* __restrict__ wtf,
    const float* g1, const float* b1,
    const float* __restrict__ stats_in, float* stats_out,
    f16* __restrict__ t2out, float* trace, float bit, int E, int Nn)
{
    trace_mark(trace, bit);
    __shared__ __align__(16) f16 bsh[16384];           // B frags; reused as out-tile
    __shared__ float sA_s[EMBD], sA_c[EMBD], w1d_s[EMBD];
    __shared__ float ps[4][EMBD], pq[4][EMBD];
    __shared__ int dst_s[64], src_s[64];
    __shared__ float dist_s[64];

    const int tid = threadIdx.x;
    const int r0 = blockIdx.x * 64;

    if (tid < EMBD) {
        const float invE = 1.f / (float)E;
        LOAD_AFF(stats_in, g1, b1, sA_s, sA_c, invE);
        w1d_s[tid] = W1[(size_t)(2 * EMBD) * EMBD + tid];
    }
    if (tid < 64) {
        int e = r0 + tid; if (e >= E) e = E - 1;
        int dj = srcI[e], di = dstI[e];
        if ((u32)dj >= (u32)Nn) dj = 0;
        if ((u32)di >= (u32)Nn) di = 0;
        dst_s[tid] = di; src_s[tid] = dj;
        float2 pj = *(const float2*)(pos + (size_t)dj * 2);
        float2 pi = *(const float2*)(pos + (size_t)di * 2);
        float dx = pj.x - pi.x, dy = pj.y - pi.y;
        dist_s[tid] = sqrtf(dx * dx + dy * dy);
    }
    {   // stage frag-ordered weights, 32 KB linear
        const float4* s4 = (const float4*)wtf;
        float4* d4 = (float4*)bsh;
#pragma unroll
        for (int i = 0; i < 8; ++i) d4[i * 256 + tid] = s4[i * 256 + tid];
    }
    __syncthreads();

    const int wv = tid >> 6, lane = tid & 63;
    const int lm = lane & 15, lg = lane >> 4;
    const int rl = wv * 16 + lm;                      // A-frag local row
    const int dn = dst_s[rl], sn = src_s[rl];
    const float dd = dist_s[rl];

    fx4_t acc[8];
#pragma unroll
    for (int c = 0; c < 8; ++c) acc[c] = (fx4_t){0.f, 0.f, 0.f, 0.f};

#pragma unroll
    for (int ks = 0; ks < 4; ++ks) {
        const int k0 = ks * 32 + lg * 8;
        hf8_t u8 = *(const hf8_t*)(uv + (size_t)dn * 256 + k0);
        hf8_t v8 = *(const hf8_t*)(uv + (size_t)sn * 256 + 128 + k0);
        hf8_t af;
#pragma unroll
        for (int e = 0; e < 8; ++e) {
            int k = k0 + e;
            float raw = fmaf(dd, w1d_s[k], (float)u8[e] + (float)v8[e]);
            af[e] = (f16)fmaxf(fmaf(raw, sA_s[k], sA_c[k]), 0.f);
        }
        const f16* bb = bsh + (size_t)(ks * 4 + lg) * 128 * 8;
#pragma unroll
        for (int c = 0; c < 8; ++c) {
            hf8_t bf = *(const hf8_t*)(bb + (size_t)(c * 16 + lm) * 8);
            acc[c] = __builtin_amdgcn_mfma_f32_16x16x32_f16(af, bf, acc[c], 0, 0, 0);
        }
    }

    // per-column stats from C-frags (col=lane&15, row=(lane>>4)*4+reg)
    const int rbase = wv * 16 + lg * 4;
#pragma unroll
    for (int c = 0; c < 8; ++c) {
        float s = 0.f, q = 0.f;
#pragma unroll
        for (int r = 0; r < 4; ++r)
            if (r0 + rbase + r < E) { float a = acc[c][r]; s += a; q += a * a; }
        s += __shfl_xor(s, 16, 64); q += __shfl_xor(q, 16, 64);
        s += __shfl_xor(s, 32, 64); q += __shfl_xor(q, 32, 64);
        if (lg == 0) { ps[wv][c * 16 + lm] = s; pq[wv][c * 16 + lm] = q; }
    }
    __syncthreads();          // all MFMA reads of bsh complete; ps/pq ready
    if (tid < EMBD) {
        atomicAdd(&stats_out[tid], ps[0][tid] + ps[1][tid] + ps[2][tid] + ps[3][tid]);
        atomicAdd(&stats_out[EMBD + tid], pq[0][tid] + pq[1][tid] + pq[2][tid] + pq[3][tid]);
    }

    // repack C-frags through LDS (reuse bsh) -> coalesced 16B stores
    f16* otile = bsh;         // [64][136]
#pragma unroll
    for (int c = 0; c < 8; ++c) {
        int col = c * 16 + lm;
#pragma unroll
        for (int r = 0; r < 4; ++r)
            otile[(size_t)(rbase + r) * 136 + col] = (f16)acc[c][r];
    }
    __syncthreads();
#pragma unroll
    for (int it = 0; it < 4; ++it) {
        int row = it * 16 + (tid >> 4), ch = tid & 15;
        int gr = r0 + row;
        if (gr < E)
            *(float4*)(t2out + (size_t)gr * 128 + ch * 8) =
                *(const float4*)(otile + (size_t)row * 136 + ch * 8);
    }
}

// ================================================================== k_g3m
// MFMA GEMM3: a2 = relu(bn2(t2_raw)); t3_raw = a2 @ Wp1; stats3; in-place.
__global__ __launch_bounds__(256) void k_g3m(
    const f16* __restrict__ tin, const f16* __restrict__ wtf,
    const float* g2, const float* b2,
    const float* __restrict__ stats_in, float* stats_out,
    f16* __restrict__ tout, float* trace, float bit, int E)
{
    trace_mark(trace, bit);
    __shared__ __align__(16) f16 bsh[16384];
    __shared__ float sB_s[EMBD], sB_c[EMBD];
    __shared__ float ps[4][EMBD], pq[4][EMBD];

    const int tid = threadIdx.x;
    const int r0 = blockIdx.x * 64;

    if (tid < EMBD) {
        const float invE = 1.f / (float)E;
        LOAD_AFF(stats_in, g2, b2, sB_s, sB_c, invE);
    }
    {
        const float4* s4 = (const float4*)wtf;
        float4* d4 = (float4*)bsh;
#pragma unroll
        for (int i = 0; i < 8; ++i) d4[i * 256 + tid] = s4[i * 256 + tid];
    }
    __syncthreads();

    const int wv = tid >> 6, lane = tid & 63;
    const int lm = lane & 15, lg = lane >> 4;
    int grA = r0 + wv * 16 + lm; if (grA >= E) grA = E - 1;

    fx4_t acc[8];
#pragma unroll
    for (int c = 0; c < 8; ++c) acc[c] = (fx4_t){0.f, 0.f, 0.f, 0.f};

#pragma unroll
    for (int ks = 0; ks < 4; ++ks) {
        const int k0 = ks * 32 + lg * 8;
        hf8_t x8 = *(const hf8_t*)(tin + (size_t)grA * 128 + k0);
        hf8_t af;
#pragma unroll
        for (int e = 0; e < 8; ++e) {
            int k = k0 + e;
            af[e] = (f16)fmaxf(fmaf((float)x8[e], sB_s[k], sB_c[k]), 0.f);
        }
        const f16* bb = bsh + (size_t)(ks * 4 + lg) * 128 * 8;
#pragma unroll
        for (int c = 0; c < 8; ++c) {
            hf8_t bf = *(const hf8_t*)(bb + (size_t)(c * 16 + lm) * 8);
            acc[c] = __builtin_amdgcn_mfma_f32_16x16x32_f16(af, bf, acc[c], 0, 0, 0);
        }
    }

    const int rbase = wv * 16 + lg * 4;
#pragma unroll
    for (int c = 0; c < 8; ++c) {
        float s = 0.f, q = 0.f;
#pragma unroll
        for (int r = 0; r < 4; ++r)
            if (r0 + rbase + r < E) { float a = acc[c][r]; s += a; q += a * a; }
        s += __shfl_xor(s, 16, 64); q += __shfl_xor(q, 16, 64);
        s += __shfl_xor(s, 32, 64); q += __shfl_xor(q, 32, 64);
        if (lg == 0) { ps[wv][c * 16 + lm] = s; pq[wv][c * 16 + lm] = q; }
    }
    __syncthreads();
    if (tid < EMBD) {
        atomicAdd(&stats_out[tid], ps[0][tid] + ps[1][tid] + ps[2][tid] + ps[3][tid]);
        atomicAdd(&stats_out[EMBD + tid], pq[0][tid] + pq[1][tid] + pq[2][tid] + pq[3][tid]);
    }

    f16* otile = bsh;
#pragma unroll
    for (int c = 0; c < 8; ++c) {
        int col = c * 16 + lm;
#pragma unroll
        for (int r = 0; r < 4; ++r)
            otile[(size_t)(rbase + r) * 136 + col] = (f16)acc[c][r];
    }
    __syncthreads();
#pragma unroll
    for (int it = 0; it < 4; ++it) {
        int row = it * 16 + (tid >> 4), ch = tid & 15;
        int gr = r0 + row;
        if (gr < E)
            *(float4*)(tout + (size_t)gr * 128 + ch * 8) =
                *(const float4*)(otile + (size_t)row * 136 + ch * 8);
    }
}

// ================================================================== k_aggr
// GATHER: h_aggr[n] = sum relu(bn2(t2_raw[e])) over in-edges; 0 atomics.
__global__ __launch_bounds__(256) void k_aggr(
    const f16* __restrict__ t2, const int* __restrict__ offs,
    const int* __restrict__ eidx,
    const float* g2, const float* b2, const float* __restrict__ stats_in,
    float* __restrict__ h_aggr, float* trace, float bit, int E, int Nn)
{
    trace_mark(trace, bit);
    __shared__ float sB_s[EMBD], sB_c[EMBD];
    const int tid = threadIdx.x;
    if (tid < EMBD) {
        const float invE = 1.f / (float)E;
        LOAD_AFF(stats_in, g2, b2, sB_s, sB_c, invE);
    }
    __syncthreads();

    const int lane = tid & 63;
    const int node = blockIdx.x * 4 + (tid >> 6);
    if (node >= Nn) return;

    const int c0 = lane * 2;
    const float s0 = sB_s[c0], s1 = sB_s[c0 + 1];
    const float cc0 = sB_c[c0], cc1 = sB_c[c0 + 1];
    const int o0 = offs[node], o1 = offs[node + 1];

    float a0 = 0.f, a1 = 0.f;
    for (int k = o0; k < o1; ++k) {
        int e = eidx[k];
        f16x2 xv = *(const f16x2*)(t2 + (size_t)e * EMBD + c0);
        a0 += fmaxf(fmaf((float)xv.x, s0, cc0), 0.f);
        a1 += fmaxf(fmaf((float)xv.y, s1, cc1), 0.f);
    }
    *(float2*)(h_aggr + (size_t)node * EMBD + c0) = make_float2(a0, a1);
}

// ================================================================== k_dot
__global__ __launch_bounds__(256) void k_dot(
    const f16* __restrict__ t3, const float* __restrict__ Wp2,
    const float* g3, const float* b3,
    const float* __restrict__ stats_in, float* stats_out, float* t4,
    float* trace, float bit, int E)
{
    trace_mark(trace, bit);
    __shared__ float sC_s[EMBD], sC_c[EMBD];
    __shared__ float red[256];
    __shared__ float dotbuf[TE];

    const int tid = threadIdx.x;
    const int r0 = blockIdx.x * TE;
    int valid = E - r0; if (valid > TE) valid = TE;

    if (tid < EMBD) {
        const float invE = 1.f / (float)E;
        LOAD_AFF(stats_in, g3, b3, sC_s, sC_c, invE);
    }
    __syncthreads();

    const int row = tid >> 3, c0 = (tid & 7) << 4;
    int e = r0 + row; if (e >= E) e = E - 1;
    const f16* tp = t3 + (size_t)e * EMBD + c0;

    float part = 0.f;
#pragma unroll
    for (int q = 0; q < 4; ++q) {
        float4 x = ld4h(tp + q * 4);
        float4 w = *(const float4*)(Wp2 + c0 + q * 4);
        int c = c0 + q * 4;
        part = fmaf(fmaxf(fmaf(x.x, sC_s[c + 0], sC_c[c + 0]), 0.f), w.x, part);
        part = fmaf(fmaxf(fmaf(x.y, sC_s[c + 1], sC_c[c + 1]), 0.f), w.y, part);
        part = fmaf(fmaxf(fmaf(x.z, sC_s[c + 2], sC_c[c + 2]), 0.f), w.z, part);
        part = fmaf(fmaxf(fmaf(x.w, sC_s[c + 3], sC_c[c + 3]), 0.f), w.w, part);
    }
    red[tid] = part;
    __syncthreads();
    if ((tid & 7) == 0) {
        float dot = red[tid] + red[tid+1] + red[tid+2] + red[tid+3]
                  + red[tid+4] + red[tid+5] + red[tid+6] + red[tid+7];
        dotbuf[row] = dot;
        if (row < valid) t4[r0 + row] = dot;
    }
    __syncthreads();
    if (tid == 0) {
        float S = 0.f, Q = 0.f;
        for (int r = 0; r < valid; ++r) { float d = dotbuf[r]; S += d; Q += d * d; }
        atomicAdd(&stats_out[0], S);
        atomicAdd(&stats_out[EMBD], Q);
    }
}

// ============================================================= k_pos_aggr
__global__ __launch_bounds__(256) void k_pos_aggr(
    const float* __restrict__ t4, const int* __restrict__ offs,
    const int* __restrict__ eidx, const int* __restrict__ srcI,
    const float* __restrict__ pos, const float* __restrict__ stats_base,
    const float* gp2, const float* bbp2,
    float* __restrict__ x_aggr, float* trace, float bit, int E, int Nn)
{
    trace_mark(trace, bit);
    const int tid = threadIdx.x;
    const int lane = tid & 63;
    const int node = blockIdx.x * 4 + (tid >> 6);
    if (node >= Nn) return;

    const float invE = 1.f / (float)E;
    float m = stats_base[768] * invE;
    float v = fmaxf(stats_base[768 + EMBD] * invE - m * m, 0.f);
    float s3 = gp2[0] * rsqrtf(v + BN_EPS);
    float c3 = bbp2[0] - m * s3;

    const int o0 = offs[node], o1 = offs[node + 1];
    float2 pi = *(const float2*)(pos + (size_t)node * 2);
    float ax = 0.f, ay = 0.f;
    for (int k = o0 + lane; k < o1; k += 64) {
        int e = eidx[k];
        float s = fmaxf(fmaf(t4[e], s3, c3), 0.f);
        int j = srcI[e];
        if ((u32)j >= (u32)Nn) j = 0;
        float2 pj = *(const float2*)(pos + (size_t)j * 2);
        ax += (pj.x - pi.x) * s;
        ay += (pj.y - pi.y) * s;
    }
#pragma unroll
    for (int off = 32; off; off >>= 1) {
        ax += __shfl_down(ax, off, 64);
        ay += __shfl_down(ay, off, 64);
    }
    if (lane == 0) {
        float inv = 1.f / fmaxf((float)(o1 - o0), 1.f);
        *(float2*)(x_aggr + (size_t)node * 2) = make_float2(ax * inv, ay * inv);
    }
}

// ============================================================== k_edge_rc
// Recompute tier (small ws) — unchanged from R11.
template<int DEPTH>
__global__ __launch_bounds__(256) void k_edge_rc(
    const f16* __restrict__ uv,
    const int* __restrict__ srcI, const int* __restrict__ dstI,
    const float* __restrict__ pos,
    const float* __restrict__ W1, const float* __restrict__ W2,
    const float* __restrict__ W3, const float* __restrict__ Wp2,
    const float* g1, const float* b1, const float* g2, const float* b2,
    const float* g3, const float* b3,
    const float* __restrict__ stats_base, float* stats_out,
    float* h_aggr, float* t4_out,
    float* trace, float bit, int E, int Nn)
{
    trace_mark(trace, bit);
    __shared__ float XsT[KC][TE];
    __shared__ float Ws[KC][EMBD];
    __shared__ float A[(DEPTH >= 3) ? TE : 1][EMBD + 4];
    __shared__ float part_s[8][EMBD];
    __shared__ float part_q[8][EMBD];
    __shared__ float red[(DEPTH >= 4) ? 256 : 1];
    __shared__ float dotbuf[(DEPTH >= 4) ? TE : 1];
    __shared__ float sA_s[EMBD], sA_c[EMBD];
    __shared__ float sB_s[(DEPTH >= 3) ? EMBD : 1], sB_c[(DEPTH >= 3) ? EMBD : 1];
    __shared__ float sC_s[(DEPTH >= 4) ? EMBD : 1], sC_c[(DEPTH >= 4) ? EMBD : 1];
    __shared__ int dst_s[TE], src_s[TE];
    __shared__ float dist_s[TE];

    const int tid = threadIdx.x;
    const int r0 = blockIdx.x * TE;
    int valid = E - r0; if (valid > TE) valid = TE;

    if (tid < EMBD) {
        const float invE = 1.f / (float)E;
        LOAD_AFF(stats_base, g1, b1, sA_s, sA_c, invE);
        if (DEPTH >= 3) LOAD_AFF(stats_base + 256, g2, b2, sB_s, sB_c, invE);
        if (DEPTH >= 4) LOAD_AFF(stats_base + 512, g3, b3, sC_s, sC_c, invE);
    }
    EDGE_META(1);
    __syncthreads();

    const int e_st = tid >> 3, kl = (tid & 7) << 2;
    const int kw = tid >> 3, cw = (tid & 7) << 4;
    const int e4 = (tid >> 5) << 2, c4 = (tid & 31) << 2;
    const int grp = tid >> 5;

    float acc[4][4];
#pragma unroll
    for (int i = 0; i < 4; ++i)
#pragma unroll
        for (int j = 0; j < 4; ++j) acc[i][j] = 0.f;

    for (int k0 = 0; k0 < EMBD; k0 += KC) {
        REBUILD_XST(k0);
        STAGE_W(W2, k0);
        __syncthreads();
        MMA32();
        __syncthreads();
    }

    if (DEPTH == 2) { STATS_TO(stats_out); return; }

#pragma unroll
    for (int i = 0; i < 4; ++i) {
        float4 o;
#pragma unroll
        for (int j = 0; j < 4; ++j) {
            float v = fmaxf(fmaf(acc[i][j], sB_s[c4 + j], sB_c[c4 + j]), 0.f);
            (&o.x)[j] = v;
            if (DEPTH == 3 && (e4 + i) < valid)
                atomicAdd(&h_aggr[(size_t)dst_s[e4 + i] * EMBD + c4 + j], v);
        }
        *(float4*)&A[e4 + i][c4] = o;
    }
    __syncthreads();

#pragma unroll
    for (int i = 0; i < 4; ++i)
#pragma unroll
        for (int j = 0; j < 4; ++j) acc[i][j] = 0.f;
    for (int k0 = 0; k0 < EMBD; k0 += KC) {
        STAGE_W(W3, k0);
        __syncthreads();
#pragma unroll 8
        for (int kk = 0; kk < KC; ++kk) {
            float4 wv4 = *(const float4*)&Ws[kk][c4];
            float wv[4] = {wv4.x, wv4.y, wv4.z, wv4.w};
            float xv[4];
#pragma unroll
            for (int i = 0; i < 4; ++i) xv[i] = A[e4 + i][k0 + kk];
#pragma unroll
            for (int i = 0; i < 4; ++i)
#pragma unroll
                for (int j = 0; j < 4; ++j) acc[i][j] = fmaf(xv[i], wv[j], acc[i][j]);
        }
        __syncthreads();
    }

    if (DEPTH == 3) { STATS_TO(stats_out); return; }

#pragma unroll
    for (int i = 0; i < 4; ++i) {
        float4 o;
#pragma unroll
        for (int j = 0; j < 4; ++j)
            (&o.x)[j] = fmaxf(fmaf(acc[i][j], sC_s[c4 + j], sC_c[c4 + j]), 0.f);
        *(float4*)&A[e4 + i][c4] = o;
    }
    __syncthreads();

    {
        const int row = tid >> 3, c0 = (tid & 7) << 4;
        float w[16];
        *(float4*)(w + 0)  = *(const float4*)(Wp2 + c0);
        *(float4*)(w + 4)  = *(const float4*)(Wp2 + c0 + 4);
        *(float4*)(w + 8)  = *(const float4*)(Wp2 + c0 + 8);
        *(float4*)(w + 12) = *(const float4*)(Wp2 + c0 + 12);
        float part = 0.f;
#pragma unroll
        for (int c = 0; c < 16; ++c) part = fmaf(A[row][c0 + c], w[c], part);
        red[tid] = part;
        __syncthreads();
        if ((tid & 7) == 0) {
            float dot = red[tid] + red[tid+1] + red[tid+2] + red[tid+3]
                      + red[tid+4] + red[tid+5] + red[tid+6] + red[tid+7];
            dotbuf[row] = dot;
            if (row < valid) t4_out[r0 + row] = dot;
        }
        __syncthreads();
        if (tid == 0) {
            float S = 0.f, Q = 0.f;
            for (int r = 0; r < valid; ++r) { float d = dotbuf[r]; S += d; Q += d * d; }
            atomicAdd(&stats_out[0], S);
            atomicAdd(&stats_out[EMBD], Q);
        }
    }
}

// =============================================================== node GEMM
__global__ __launch_bounds__(256) void k_upd(
    const float* h, const float* h_aggr, const float* W,
    float* stats_out, float* t5, float* trace, float bit, int Nn)
{
    trace_mark(trace, bit);
    __shared__ float XsT[KC][TE];
    __shared__ float Ws[KC][EMBD];
    __shared__ float part_s[8][EMBD];
    __shared__ float part_q[8][EMBD];

    const int tid = threadIdx.x;
    const int r0 = blockIdx.x * TE;
    int valid = Nn - r0; if (valid > TE) valid = TE;

    float acc[4][4];
#pragma unroll
    for (int i = 0; i < 4; ++i)
#pragma unroll
        for (int j = 0; j < 4; ++j) acc[i][j] = 0.f;

    const int e_st = tid >> 3, kl = (tid & 7) << 2;
    const int kw = tid >> 3, cw = (tid & 7) << 4;
    const int e4 = (tid >> 5) << 2, c4 = (tid & 31) << 2;
    const int grp = tid >> 5;

    for (int k0 = 0; k0 < 2 * EMBD; k0 += KC) {
        {
            float4 x = make_float4(0.f, 0.f, 0.f, 0.f);
            if (e_st < valid) {
                int k = k0 + kl;
                int row = r0 + e_st;
                const float* base = (k < EMBD)
                    ? h + (size_t)row * EMBD + k
                    : h_aggr + (size_t)row * EMBD + (k - EMBD);
                x = *(const float4*)base;
            }
            XsT[kl + 0][e_st] = x.x; XsT[kl + 1][e_st] = x.y;
            XsT[kl + 2][e_st] = x.z; XsT[kl + 3][e_st] = x.w;
        }
        STAGE_W(W, k0);
        __syncthreads();
        MMA32();
        __syncthreads();
    }

    STATS_TO(stats_out);

#pragma unroll
    for (int i = 0; i < 4; ++i) {
        int row = r0 + e4 + i;
        if (e4 + i < valid)
            *(float4*)(t5 + (size_t)row * EMBD + c4) =
                make_float4(acc[i][0], acc[i][1], acc[i][2], acc[i][3]);
    }
}

// ---------------------------------------------------------------- epilogue
__global__ __launch_bounds__(256) void k_final(
    const float* h, const float* pos, const float* stats5,
    const float* gu1, const float* bbu1,
    const float* x_aggr, const float* trace,
    float* out, int N, float expect)
{
    __shared__ float s4[EMBD], cc4[EMBD];
    int tid = threadIdx.x;
    if (tid < EMBD) {
        const float invN = 1.f / (float)N;
        float m = stats5[tid] * invN;
        float v = fmaxf(stats5[EMBD + tid] * invN - m * m, 0.f);
        float s = gu1[tid] * rsqrtf(v + BN_EPS);
        s4[tid] = s; cc4[tid] = bbu1[tid] - m * s;
    }
    __syncthreads();
    int n = blockIdx.x * 2 + (tid >> 7);
    int c = tid & 127;
    if (n >= N) return;
    float hv = h[(size_t)n * EMBD + c];
    float t = out[(size_t)n * EMBD + c];
    float res = sane(hv + fmaxf(fmaf(t, s4[c], cc4[c]), 0.f), 100.f);
    if (n == 0 && c == 1) {
        float tr = trace[0];
        if (fabsf(tr - expect) > 0.5f) res = 1048576.0f + tr * 64.0f;
    }
    out[(size_t)n * EMBD + c] = res;
    if (c < 2) {
        float p = pos[(size_t)n * 2 + c];
        float xa = x_aggr[(size_t)n * 2 + c];
        out[(size_t)N * EMBD + (size_t)n * 2 + c] = sane(p + xa, 100.f);
    }
}

// ================================================================= launch
extern "C" void kernel_launch(void* const* d_in, const int* in_sizes, int n_in,
                              void* d_out, int out_size, void* d_ws, size_t ws_size,
                              hipStream_t stream)
{
    const float* h   = (const float*)d_in[0];
    const float* pos = (const float*)d_in[1];
    const int* ei    = (const int*)d_in[3];
    const float* Wm1 = (const float*)d_in[4];
    const float* gm1 = (const float*)d_in[6];
    const float* bbm1= (const float*)d_in[7];
    const float* Wm2 = (const float*)d_in[8];
    const float* gm2 = (const float*)d_in[10];
    const float* bbm2= (const float*)d_in[11];
    const float* Wp1 = (const float*)d_in[12];
    const float* gp1 = (const float*)d_in[14];
    const float* bbp1= (const float*)d_in[15];
    const float* Wp2 = (const float*)d_in[16];
    const float* gp2 = (const float*)d_in[18];
    const float* bbp2= (const float*)d_in[19];
    const float* Wu1 = (const float*)d_in[20];
    const float* gu1 = (const float*)d_in[22];
    const float* bbu1= (const float*)d_in[23];

    const int N = in_sizes[0] / EMBD;
    const int E = in_sizes[3] / 2;
    const int* srcI = ei;
    const int* dstI = ei + E;

    size_t off = 0;
    auto carve = [&](size_t bytes) -> size_t {
        size_t o = off; off += (bytes + 255) & ~(size_t)255; return o;
    };
    size_t o_stats  = carve(5 * 256 * sizeof(float));
    size_t o_trace  = carve(256);
    size_t o_cnti   = carve((size_t)N * sizeof(int));
    size_t zero_small = off;
    size_t o_haggr  = carve((size_t)N * EMBD * sizeof(float));
    size_t zero_need = off;                                  // ~25.9 MB
    size_t o_xaggr  = carve((size_t)N * 2 * sizeof(float));
    size_t o_t4     = carve((size_t)E * sizeof(float));
    size_t o_offs   = carve((size_t)(N + 1) * sizeof(int));
    size_t o_cursor = carve((size_t)N * sizeof(int));
    size_t o_eidx   = carve((size_t)E * sizeof(int));
    size_t o_wtf2   = carve(16384 * sizeof(f16));
    size_t o_wtf3   = carve(16384 * sizeof(f16));
    size_t base_need = off;                                  // ~31 MB
    size_t o_ebuf   = carve((size_t)E * EMBD * sizeof(f16)); // +128 MB
    size_t need_staged = off;

    float* out_f = (float*)d_out;

    if (ws_size < base_need) {
        k_fill<<<(out_size + 255) / 256, 256, 0, stream>>>(out_f, 12345678.0f, out_size);
        return;
    }

    char* wsb = (char*)d_ws;
    float* stats  = (float*)(wsb + o_stats);
    float* trace  = (float*)(wsb + o_trace);
    int*   cnti   = (int*)(wsb + o_cnti);
    float* h_aggr = (float*)(wsb + o_haggr);
    float* x_aggr = (float*)(wsb + o_xaggr);
    float* t4     = (float*)(wsb + o_t4);
    int*   offs   = (int*)(wsb + o_offs);
    int*   cursor = (int*)(wsb + o_cursor);
    int*   eidx   = (int*)(wsb + o_eidx);
    f16*   wtf2   = (f16*)(wsb + o_wtf2);
    f16*   wtf3   = (f16*)(wsb + o_wtf3);
    f16*   uv     = (f16*)d_out;   // N*256 fp16 = N*512B <= out bytes

    const bool staged = (ws_size >= need_staged);
    // staged path: h_aggr fully overwritten by k_aggr -> skip its memset
    hipMemsetAsync(d_ws, 0, staged ? zero_small : zero_need, stream);

    const int gPE  = (E + 255) / 256;
    const int gE   = (E + TE - 1) / TE;
    const int gE64 = (E + 63) / 64;
    const int gN   = (N + TE - 1) / TE;
    const int gS1  = (E + 127) / 128;
    const int gW   = (N + 3) / 4;

    k_uv<<<gN, 256, 0, stream>>>(h, Wm1, uv, trace, 1.0f, N);
    k_stats1<<<gS1, 256, 0, stream>>>(uv, pos, srcI, dstI, Wm1,
                                      stats, cnti, trace, 2.0f, E, N);
    k_scan<<<1, 1024, 0, stream>>>(cnti, offs, cursor, trace, 4.0f, N);
    k_scatter<<<gPE, 256, 0, stream>>>(dstI, cursor, eidx, trace, 8.0f, E, N);

    if (staged) {
        f16* eb = (f16*)(wsb + o_ebuf);
        k_prep<<<64, 256, 0, stream>>>(Wm2, Wp1, wtf2, wtf3, trace, 16.0f);
        k_g2m<<<gE64, 256, 0, stream>>>(uv, srcI, dstI, pos, Wm1, wtf2,
                                        gm1, bbm1, stats, stats + 256,
                                        eb, trace, 32.0f, E, N);
        k_aggr<<<gW, 256, 0, stream>>>(eb, offs, eidx, gm2, bbm2, stats + 256,
                                       h_aggr, trace, 64.0f, E, N);
        k_g3m<<<gE64, 256, 0, stream>>>(eb, wtf3, gm2, bbm2,
                                        stats + 256, stats + 512,
                                        eb, trace, 128.0f, E);
        k_dot<<<gE, 256, 0, stream>>>(eb, Wp2, gp1, bbp1,
                                      stats + 512, stats + 768, t4,
                                      trace, 256.0f, E);
    } else {
        k_edge_rc<2><<<gE, 256, 0, stream>>>(uv, srcI, dstI, pos,
                                             Wm1, Wm2, Wp1, Wp2,
                                             gm1, bbm1, gm2, bbm2, gp1, bbp1,
                                             stats, stats + 256, h_aggr, t4,
                                             trace, 16.0f, E, N);
        k_edge_rc<3><<<gE, 256, 0, stream>>>(uv, srcI, dstI, pos,
                                             Wm1, Wm2, Wp1, Wp2,
                                             gm1, bbm1, gm2, bbm2, gp1, bbp1,
                                             stats, stats + 512, h_aggr, t4,
                                             trace, 32.0f, E, N);
        k_edge_rc<4><<<gE, 256, 0, stream>>>(uv, srcI, dstI, pos,
                                             Wm1, Wm2, Wp1, Wp2,
                                             gm1, bbm1, gm2, bbm2, gp1, bbp1,
                                             stats, stats + 768, h_aggr, t4,
                                             trace, 64.0f, E, N);
    }

    k_pos_aggr<<<gW, 256, 0, stream>>>(t4, offs, eidx, srcI, pos,
                                       stats, gp2, bbp2, x_aggr,
                                       trace, 512.0f, E, N);
    k_upd<<<gN, 256, 0, stream>>>(h, h_aggr, Wu1, stats + 1024, out_f,
                                  trace, 1024.0f, N);
    k_final<<<(N + 1) / 2, 256, 0, stream>>>(h, pos, stats + 1024, gu1, bbu1,
                                             x_aggr, trace, out_f, N,
                                             staged ? 2047.0f : 1663.0f);
}

// Round 5
// 1215.616 us; speedup vs baseline: 3.1258x; 1.0079x over previous
//
#include <hip/hip_runtime.h>
#include <hip/hip_bf16.h>

// SpatialNCA, MI355X. R13: CSR-permuted edge axis. R12 counters: k_g2m 232us
// @ HBM 14%/VALU 13%/Mfma 3% => gather-latency bound (random UV rows, 25.6MB
// > 4MB per-XCD L2). Edges now processed in dst-sorted order (srcp/dstp from
// k_scatter): dst-side gathers become ~10-way clustered; t2/t3/t4 stored
// permuted so k_aggr is a contiguous segment-sum and k_pos_aggr streams.
// k_count split out so CSR precedes all permuted kernels. Trace fail-closed:
// staged expect=4095, rc expect=3327.

#define EMBD 128
#define TE 32
#define KC 32
#define BN_EPS 1e-5f

typedef unsigned int u32;
typedef _Float16 f16;
typedef _Float16 hf8_t __attribute__((ext_vector_type(8)));
typedef float fx4_t __attribute__((ext_vector_type(4)));

__device__ __forceinline__ bool finitef(float f) {
    union { float f; u32 i; } v; v.f = f;
    return ((v.i >> 23) & 0xFFu) != 0xFFu;
}
__device__ __forceinline__ float sane(float f, float lim) {
    if (!finitef(f)) return 0.f;
    return fminf(fmaxf(f, -lim), lim);
}
__device__ __forceinline__ void trace_mark(float* tp, float bit) {
    if (blockIdx.x == 0 && threadIdx.x == 0) atomicAdd(tp, bit);
}

struct f16x4 { f16 a, b, c, d; };
struct alignas(4) f16x2 { f16 x, y; };
__device__ __forceinline__ float4 ld4h(const f16* p) {
    f16x4 t = *(const f16x4*)p;
    return make_float4((float)t.a, (float)t.b, (float)t.c, (float)t.d);
}
__device__ __forceinline__ void st4h(f16* p, float4 v) {
    f16x4 t; t.a = (f16)v.x; t.b = (f16)v.y; t.c = (f16)v.z; t.d = (f16)v.w;
    *(f16x4*)p = t;
}

// ---------------------------------------------------------------- sentinel
__global__ __launch_bounds__(256) void k_fill(float* out, float val, int n) {
    int i = blockIdx.x * 256 + threadIdx.x;
    if (i < n) out[i] = val;
}

// ------------------------------------------------------------ shared macros
#define STAGE_W(WPTR, K0) { \
        const float* wp = (WPTR) + (size_t)((K0) + kw) * EMBD + cw; \
        float4 wa = *(const float4*)wp; \
        float4 wb = *(const float4*)(wp + 4); \
        float4 wc = *(const float4*)(wp + 8); \
        float4 wdv = *(const float4*)(wp + 12); \
        float* wd = &Ws[kw][cw]; \
        *(float4*)(wd + 0) = wa; *(float4*)(wd + 4) = wb; \
        *(float4*)(wd + 8) = wc; *(float4*)(wd + 12) = wdv; }

#define MMA32() { \
        _Pragma("unroll 8") \
        for (int kk = 0; kk < KC; ++kk) { \
            float4 xv4 = *(const float4*)&XsT[kk][e4]; \
            float4 wv4 = *(const float4*)&Ws[kk][c4]; \
            float xv[4] = {xv4.x, xv4.y, xv4.z, xv4.w}; \
            float wv[4] = {wv4.x, wv4.y, wv4.z, wv4.w}; \
            for (int i = 0; i < 4; ++i) \
                for (int j = 0; j < 4; ++j) acc[i][j] = fmaf(xv[i], wv[j], acc[i][j]); } }

#define STATS_TO(SOUT) { \
        __syncthreads(); \
        for (int j = 0; j < 4; ++j) { \
            float s = 0.f, q = 0.f; \
            for (int i = 0; i < 4; ++i) \
                if (e4 + i < valid) { float a = acc[i][j]; s += a; q += a * a; } \
            part_s[grp][c4 + j] = s; part_q[grp][c4 + j] = q; \
        } \
        __syncthreads(); \
        if (tid < EMBD) { \
            float S = 0.f, Q = 0.f; \
            for (int g = 0; g < 8; ++g) { S += part_s[g][tid]; Q += part_q[g][tid]; } \
            atomicAdd(&(SOUT)[tid], S); \
            atomicAdd(&(SOUT)[EMBD + tid], Q); } }

#define LOAD_AFF(SRC, GG, BB, SS, CC, DEN) { \
        float m_ = (SRC)[tid] * (DEN); \
        float v_ = fmaxf((SRC)[EMBD + tid] * (DEN) - m_ * m_, 0.f); \
        float s_ = (GG)[tid] * rsqrtf(v_ + BN_EPS); \
        (SS)[tid] = s_; (CC)[tid] = (BB)[tid] - m_ * s_; }

// Rebuild post-BN1 a1 into XsT from UV (fp16) + dist.  (rc fallback only)
#define REBUILD_XST(K0) { \
        int k = (K0) + kl; \
        float4 u4 = ld4h(uv + (size_t)dst_s[e_st] * 256 + k); \
        float4 v4 = ld4h(uv + (size_t)src_s[e_st] * 256 + 128 + k); \
        float4 wd = *(const float4*)(W1 + (size_t)(2 * EMBD) * EMBD + k); \
        float dd_ = dist_s[e_st]; \
        float r0_ = fmaf(dd_, wd.x, u4.x + v4.x); \
        float r1_ = fmaf(dd_, wd.y, u4.y + v4.y); \
        float r2_ = fmaf(dd_, wd.z, u4.z + v4.z); \
        float r3_ = fmaf(dd_, wd.w, u4.w + v4.w); \
        XsT[kl + 0][e_st] = fmaxf(fmaf(r0_, sA_s[k + 0], sA_c[k + 0]), 0.f); \
        XsT[kl + 1][e_st] = fmaxf(fmaf(r1_, sA_s[k + 1], sA_c[k + 1]), 0.f); \
        XsT[kl + 2][e_st] = fmaxf(fmaf(r2_, sA_s[k + 2], sA_c[k + 2]), 0.f); \
        XsT[kl + 3][e_st] = fmaxf(fmaf(r3_, sA_s[k + 3], sA_c[k + 3]), 0.f); }

#define EDGE_META(WITH_SRC) { \
        if (tid < TE) { \
            int e = r0 + tid; if (e >= E) e = E - 1; \
            int dj = srcI[e], di = dstI[e]; \
            if ((u32)dj >= (u32)Nn) dj = 0; \
            if ((u32)di >= (u32)Nn) di = 0; \
            dst_s[tid] = di; \
            if (WITH_SRC) { \
                src_s[tid] = dj; \
                float2 pj = *(const float2*)(pos + (size_t)dj * 2); \
                float2 pi = *(const float2*)(pos + (size_t)di * 2); \
                float dx = pj.x - pi.x, dy = pj.y - pi.y; \
                dist_s[tid] = sqrtf(dx * dx + dy * dy); } } }

// ================================================================== k_uv
// U = h @ W1[0:128] (dst part), V = h @ W1[128:256] (src part), fp16 out.
__global__ __launch_bounds__(256) void k_uv(
    const float* __restrict__ h, const float* __restrict__ W1,
    f16* __restrict__ uv, float* trace, float bit, int Nn)
{
    trace_mark(trace, bit);
    __shared__ float XsT[KC][TE];
    __shared__ float Ws[KC][EMBD];

    const int tid = threadIdx.x;
    const int r0 = blockIdx.x * TE;
    int valid = Nn - r0; if (valid > TE) valid = TE;

    const int e_st = tid >> 3, kl = (tid & 7) << 2;
    const int kw = tid >> 3, cw = (tid & 7) << 4;
    const int e4 = (tid >> 5) << 2, c4 = (tid & 31) << 2;

    for (int pass = 0; pass < 2; ++pass) {
        float acc[4][4];
#pragma unroll
        for (int i = 0; i < 4; ++i)
#pragma unroll
            for (int j = 0; j < 4; ++j) acc[i][j] = 0.f;

        const float* Wp = W1 + (size_t)pass * EMBD * EMBD;
        for (int k0 = 0; k0 < EMBD; k0 += KC) {
            {
                float4 x = make_float4(0.f, 0.f, 0.f, 0.f);
                if (e_st < valid)
                    x = *(const float4*)(h + (size_t)(r0 + e_st) * EMBD + k0 + kl);
                XsT[kl + 0][e_st] = x.x; XsT[kl + 1][e_st] = x.y;
                XsT[kl + 2][e_st] = x.z; XsT[kl + 3][e_st] = x.w;
            }
            STAGE_W(Wp, k0);
            __syncthreads();
            MMA32();
            __syncthreads();
        }
#pragma unroll
        for (int i = 0; i < 4; ++i)
            if (e4 + i < valid)
                st4h(uv + (size_t)(r0 + e4 + i) * 256 + pass * EMBD + c4,
                     make_float4(acc[i][0], acc[i][1], acc[i][2], acc[i][3]));
    }
}

// ================================================================== k_count
__global__ __launch_bounds__(256) void k_count(
    const int* __restrict__ dstI, int* __restrict__ cnti,
    float* trace, float bit, int E, int Nn)
{
    trace_mark(trace, bit);
    int e = blockIdx.x * 256 + threadIdx.x;
    if (e >= E) return;
    int di = dstI[e];
    if ((u32)di >= (u32)Nn) di = 0;
    atomicAdd(&cnti[di], 1);
}

// ================================================================== k_scan
__global__ __launch_bounds__(1024) void k_scan(
    const int* __restrict__ cnti, int* __restrict__ offs,
    int* __restrict__ cursor, float* trace, float bit, int Nn)
{
    trace_mark(trace, bit);
    __shared__ int buf[1024];
    __shared__ int carry_s;
    const int tid = threadIdx.x;
    if (tid == 0) carry_s = 0;
    __syncthreads();
    for (int base = 0; base < Nn; base += 1024) {
        int i = base + tid;
        int v = (i < Nn) ? cnti[i] : 0;
        buf[tid] = v;
        __syncthreads();
        for (int d = 1; d < 1024; d <<= 1) {
            int t = (tid >= d) ? buf[tid - d] : 0;
            __syncthreads();
            buf[tid] += t;
            __syncthreads();
        }
        int exc = buf[tid] - v + carry_s;
        if (i < Nn) { offs[i] = exc; cursor[i] = exc; }
        int total = buf[1023];
        __syncthreads();
        if (tid == 0) carry_s += total;
        __syncthreads();
    }
    if (tid == 0) offs[Nn] = carry_s;
}

// =============================================================== k_scatter
// Permutation: p = cursor[dst]++ ; srcp[p]/dstp[p] = endpoints ; eidx for rc.
__global__ __launch_bounds__(256) void k_scatter(
    const int* __restrict__ srcI, const int* __restrict__ dstI,
    int* __restrict__ cursor, int* __restrict__ eidx,
    int* __restrict__ srcp, int* __restrict__ dstp,
    float* trace, float bit, int E, int Nn)
{
    trace_mark(trace, bit);
    int e = blockIdx.x * 256 + threadIdx.x;
    if (e >= E) return;
    int di = dstI[e], sj = srcI[e];
    if ((u32)di >= (u32)Nn) di = 0;
    if ((u32)sj >= (u32)Nn) sj = 0;
    int p = atomicAdd(&cursor[di], 1);
    eidx[p] = e;
    srcp[p] = sj;
    dstp[p] = di;
}

// =============================================================== k_stats1
// stats1 over permuted t1[k] = U[dstp]+V[srcp]+dist*w1d (dst clustered).
#define SB 128
__global__ __launch_bounds__(256) void k_stats1(
    const f16* __restrict__ uv, const float* __restrict__ pos,
    const int* __restrict__ srcp, const int* __restrict__ dstp,
    const float* __restrict__ W1, float* stats_out,
    float* trace, float bit, int E, int Nn)
{
    trace_mark(trace, bit);
    __shared__ int ds[SB], ss[SB];
    __shared__ float dd[SB];
    __shared__ float ps[2][EMBD], pq[2][EMBD];

    const int tid = threadIdx.x;
    const int r0 = blockIdx.x * SB;

    if (tid < SB) {
        int e = r0 + tid; if (e >= E) e = E - 1;
        int dj = srcp[e], di = dstp[e];
        ds[tid] = di; ss[tid] = dj;
        float2 pj = *(const float2*)(pos + (size_t)dj * 2);
        float2 pi = *(const float2*)(pos + (size_t)di * 2);
        float dx = pj.x - pi.x, dy = pj.y - pi.y;
        dd[tid] = sqrtf(dx * dx + dy * dy);
    }
    __syncthreads();

    const int c = tid & 127, hh = tid >> 7;
    const float w1d = W1[(size_t)(2 * EMBD) * EMBD + c];
    float S = 0.f, Q = 0.f;
#pragma unroll 4
    for (int i = 0; i < 64; ++i) {
        int el = hh * 64 + i;
        int e = r0 + el;
        if (e < E) {
            float u = (float)uv[(size_t)ds[el] * 256 + c];
            float v = (float)uv[(size_t)ss[el] * 256 + 128 + c];
            float t = fmaf(dd[el], w1d, u + v);
            S += t; Q += t * t;
        }
    }
    ps[hh][c] = S; pq[hh][c] = Q;
    __syncthreads();
    if (tid < EMBD) {
        atomicAdd(&stats_out[tid], ps[0][tid] + ps[1][tid]);
        atomicAdd(&stats_out[EMBD + tid], pq[0][tid] + pq[1][tid]);
    }
}
#undef SB

// ================================================================== k_prep
// Transpose W2/Wp1 to fp16 MFMA B-frag-slot order.
__global__ __launch_bounds__(256) void k_prep(
    const float* __restrict__ W2, const float* __restrict__ Wp1,
    f16* __restrict__ wtf2, f16* __restrict__ wtf3, float* trace, float bit)
{
    trace_mark(trace, bit);
    int id = blockIdx.x * 256 + threadIdx.x;   // 64 blocks -> 16384
    int k = id >> 7, n = id & 127;
    size_t s = ((size_t)(k >> 3) * 128 + n) * 8 + (k & 7);
    wtf2[s] = (f16)W2[(size_t)k * 128 + n];
    wtf3[s] = (f16)Wp1[(size_t)k * 128 + n];
}

// ================================================================== k_g2m
// MFMA GEMM2 over PERMUTED edges: dst gathers clustered; t2 stored permuted.
__global__ __launch_bounds__(256) void k_g2m(
    const f16* __restrict__ uv,
    const int* __restrict__ srcp, const int* __restrict__ dstp,
    const float* __restrict__ pos, const float* __restrict__ W1,
    const f16* __restrict__ wtf,
    const float* g1, const float* b1,
    const float* __restrict__ stats_in, float* stats_out,
    f16* __restrict__ t2out, float* trace, float bit, int E, int Nn)
{
    trace_mark(trace, bit);
    __shared__ __align__(16) f16 bsh[16384];           // B frags; reused as out-tile
    __shared__ float sA_s[EMBD], sA_c[EMBD], w1d_s[EMBD];
    __shared__ float ps[4][EMBD], pq[4][EMBD];
    __shared__ int dst_s[64], src_s[64];
    __shared__ float dist_s[64];

    const int tid = threadIdx.x;
    const int r0 = blockIdx.x * 64;

    if (tid < EMBD) {
        const float invE = 1.f / (float)E;
        LOAD_AFF(stats_in, g1, b1, sA_s, sA_c, invE);
        w1d_s[tid] = W1[(size_t)(2 * EMBD) * EMBD + tid];
    }
    if (tid < 64) {
        int e = r0 + tid; if (e >= E) e = E - 1;
        int dj = srcp[e], di = dstp[e];
        dst_s[tid] = di; src_s[tid] = dj;
        float2 pj = *(const float2*)(pos + (size_t)dj * 2);
        float2 pi = *(const float2*)(pos + (size_t)di * 2);
        float dx = pj.x - pi.x, dy = pj.y - pi.y;
        dist_s[tid] = sqrtf(dx * dx + dy * dy);
    }
    {   // stage frag-ordered weights, 32 KB linear
        const float4* s4 = (const float4*)wtf;
        float4* d4 = (float4*)bsh;
#pragma unroll
        for (int i = 0; i < 8; ++i) d4[i * 256 + tid] = s4[i * 256 + tid];
    }
    __syncthreads();

    const int wv = tid >> 6, lane = tid & 63;
    const int lm = lane & 15, lg = lane >> 4;
    const int rl = wv * 16 + lm;                      // A-frag local row
    const int dn = dst_s[rl], sn = src_s[rl];
    const float dd = dist_s[rl];

    fx4_t acc[8];
#pragma unroll
    for (int c = 0; c < 8; ++c) acc[c] = (fx4_t){0.f, 0.f, 0.f, 0.f};

#pragma unroll
    for (int ks = 0; ks < 4; ++ks) {
        const int k0 = ks * 32 + lg * 8;
        hf8_t u8 = *(const hf8_t*)(uv + (size_t)dn * 256 + k0);
        hf8_t v8 = *(const hf8_t*)(uv + (size_t)sn * 256 + 128 + k0);
        hf8_t af;
#pragma unroll
        for (int e = 0; e < 8; ++e) {
            int k = k0 + e;
            float raw = fmaf(dd, w1d_s[k], (float)u8[e] + (float)v8[e]);
            af[e] = (f16)fmaxf(fmaf(raw, sA_s[k], sA_c[k]), 0.f);
        }
        const f16* bb = bsh + (size_t)(ks * 4 + lg) * 128 * 8;
#pragma unroll
        for (int c = 0; c < 8; ++c) {
            hf8_t bf = *(const hf8_t*)(bb + (size_t)(c * 16 + lm) * 8);
            acc[c] = __builtin_amdgcn_mfma_f32_16x16x32_f16(af, bf, acc[c], 0, 0, 0);
        }
    }

    // per-column stats from C-frags (col=lane&15, row=(lane>>4)*4+reg)
    const int rbase = wv * 16 + lg * 4;
#pragma unroll
    for (int c = 0; c < 8; ++c) {
        float s = 0.f, q = 0.f;
#pragma unroll
        for (int r = 0; r < 4; ++r)
            if (r0 + rbase + r < E) { float a = acc[c][r]; s += a; q += a * a; }
        s += __shfl_xor(s, 16, 64); q += __shfl_xor(q, 16, 64);
        s += __shfl_xor(s, 32, 64); q += __shfl_xor(q, 32, 64);
        if (lg == 0) { ps[wv][c * 16 + lm] = s; pq[wv][c * 16 + lm] = q; }
    }
    __syncthreads();          // all MFMA reads of bsh complete; ps/pq ready
    if (tid < EMBD) {
        atomicAdd(&stats_out[tid], ps[0][tid] + ps[1][tid] + ps[2][tid] + ps[3][tid]);
        atomicAdd(&stats_out[EMBD + tid], pq[0][tid] + pq[1][tid] + pq[2][tid] + pq[3][tid]);
    }

    // repack C-frags through LDS (reuse bsh) -> coalesced 16B stores
    f16* otile = bsh;         // [64][136]
#pragma unroll
    for (int c = 0; c < 8; ++c) {
        int col = c * 16 + lm;
#pragma unroll
        for (int r = 0; r < 4; ++r)
            otile[(size_t)(rbase + r) * 136 + col] = (f16)acc[c][r];
    }
    __syncthreads();
#pragma unroll
    for (int it = 0; it < 4; ++it) {
        int row = it * 16 + (tid >> 4), ch = tid & 15;
        int gr = r0 + row;
        if (gr < E)
            *(float4*)(t2out + (size_t)gr * 128 + ch * 8) =
                *(const float4*)(otile + (size_t)row * 136 + ch * 8);
    }
}

// ================================================================== k_g3m
// MFMA GEMM3: a2 = relu(bn2(t2_raw)); t3_raw = a2 @ Wp1; stats3; in-place.
__global__ __launch_bounds__(256) void k_g3m(
    const f16* __restrict__ tin, const f16* __restrict__ wtf,
    const float* g2, const float* b2,
    const float* __restrict__ stats_in, float* stats_out,
    f16* __restrict__ tout, float* trace, float bit, int E)
{
    trace_mark(trace, bit);
    __shared__ __align__(16) f16 bsh[16384];
    __shared__ float sB_s[EMBD], sB_c[EMBD];
    __shared__ float ps[4][EMBD], pq[4][EMBD];

    const int tid = threadIdx.x;
    const int r0 = blockIdx.x * 64;

    if (tid < EMBD) {
        const float invE = 1.f / (float)E;
        LOAD_AFF(stats_in, g2, b2, sB_s, sB_c, invE);
    }
    {
        const float4* s4 = (const float4*)wtf;
        float4* d4 = (float4*)bsh;
#pragma unroll
        for (int i = 0; i < 8; ++i) d4[i * 256 + tid] = s4[i * 256 + tid];
    }
    __syncthreads();

    const int wv = tid >> 6, lane = tid & 63;
    const int lm = lane & 15, lg = lane >> 4;
    int grA = r0 + wv * 16 + lm; if (grA >= E) grA = E - 1;

    fx4_t acc[8];
#pragma unroll
    for (int c = 0; c < 8; ++c) acc[c] = (fx4_t){0.f, 0.f, 0.f, 0.f};

#pragma unroll
    for (int ks = 0; ks < 4; ++ks) {
        const int k0 = ks * 32 + lg * 8;
        hf8_t x8 = *(const hf8_t*)(tin + (size_t)grA * 128 + k0);
        hf8_t af;
#pragma unroll
        for (int e = 0; e < 8; ++e) {
            int k = k0 + e;
            af[e] = (f16)fmaxf(fmaf((float)x8[e], sB_s[k], sB_c[k]), 0.f);
        }
        const f16* bb = bsh + (size_t)(ks * 4 + lg) * 128 * 8;
#pragma unroll
        for (int c = 0; c < 8; ++c) {
            hf8_t bf = *(const hf8_t*)(bb + (size_t)(c * 16 + lm) * 8);
            acc[c] = __builtin_amdgcn_mfma_f32_16x16x32_f16(af, bf, acc[c], 0, 0, 0);
        }
    }

    const int rbase = wv * 16 + lg * 4;
#pragma unroll
    for (int c = 0; c < 8; ++c) {
        float s = 0.f, q = 0.f;
#pragma unroll
        for (int r = 0; r < 4; ++r)
            if (r0 + rbase + r < E) { float a = acc[c][r]; s += a; q += a * a; }
        s += __shfl_xor(s, 16, 64); q += __shfl_xor(q, 16, 64);
        s += __shfl_xor(s, 32, 64); q += __shfl_xor(q, 32, 64);
        if (lg == 0) { ps[wv][c * 16 + lm] = s; pq[wv][c * 16 + lm] = q; }
    }
    __syncthreads();
    if (tid < EMBD) {
        atomicAdd(&stats_out[tid], ps[0][tid] + ps[1][tid] + ps[2][tid] + ps[3][tid]);
        atomicAdd(&stats_out[EMBD + tid], pq[0][tid] + pq[1][tid] + pq[2][tid] + pq[3][tid]);
    }

    f16* otile = bsh;
#pragma unroll
    for (int c = 0; c < 8; ++c) {
        int col = c * 16 + lm;
#pragma unroll
        for (int r = 0; r < 4; ++r)
            otile[(size_t)(rbase + r) * 136 + col] = (f16)acc[c][r];
    }
    __syncthreads();
#pragma unroll
    for (int it = 0; it < 4; ++it) {
        int row = it * 16 + (tid >> 4), ch = tid & 15;
        int gr = r0 + row;
        if (gr < E)
            *(float4*)(tout + (size_t)gr * 128 + ch * 8) =
                *(const float4*)(otile + (size_t)row * 136 + ch * 8);
    }
}

// ================================================================== k_aggr
// Contiguous segment-sum over permuted t2: h_aggr[n] = sum relu(bn2(t2[k]))
// for k in [offs[n], offs[n+1]).  Streaming reads, zero atomics.
__global__ __launch_bounds__(256) void k_aggr(
    const f16* __restrict__ t2, const int* __restrict__ offs,
    const float* g2, const float* b2, const float* __restrict__ stats_in,
    float* __restrict__ h_aggr, float* trace, float bit, int E, int Nn)
{
    trace_mark(trace, bit);
    __shared__ float sB_s[EMBD], sB_c[EMBD];
    const int tid = threadIdx.x;
    if (tid < EMBD) {
        const float invE = 1.f / (float)E;
        LOAD_AFF(stats_in, g2, b2, sB_s, sB_c, invE);
    }
    __syncthreads();

    const int lane = tid & 63;
    const int node = blockIdx.x * 4 + (tid >> 6);
    if (node >= Nn) return;

    const int c0 = lane * 2;
    const float s0 = sB_s[c0], s1 = sB_s[c0 + 1];
    const float cc0 = sB_c[c0], cc1 = sB_c[c0 + 1];
    const int o0 = offs[node], o1 = offs[node + 1];

    float a0 = 0.f, a1 = 0.f;
    for (int k = o0; k < o1; ++k) {
        f16x2 xv = *(const f16x2*)(t2 + (size_t)k * EMBD + c0);
        a0 += fmaxf(fmaf((float)xv.x, s0, cc0), 0.f);
        a1 += fmaxf(fmaf((float)xv.y, s1, cc1), 0.f);
    }
    *(float2*)(h_aggr + (size_t)node * EMBD + c0) = make_float2(a0, a1);
}

// ================================================================== k_dot
__global__ __launch_bounds__(256) void k_dot(
    const f16* __restrict__ t3, const float* __restrict__ Wp2,
    const float* g3, const float* b3,
    const float* __restrict__ stats_in, float* stats_out, float* t4,
    float* trace, float bit, int E)
{
    trace_mark(trace, bit);
    __shared__ float sC_s[EMBD], sC_c[EMBD];
    __shared__ float red[256];
    __shared__ float dotbuf[TE];

    const int tid = threadIdx.x;
    const int r0 = blockIdx.x * TE;
    int valid = E - r0; if (valid > TE) valid = TE;

    if (tid < EMBD) {
        const float invE = 1.f / (float)E;
        LOAD_AFF(stats_in, g3, b3, sC_s, sC_c, invE);
    }
    __syncthreads();

    const int row = tid >> 3, c0 = (tid & 7) << 4;
    int e = r0 + row; if (e >= E) e = E - 1;
    const f16* tp = t3 + (size_t)e * EMBD + c0;

    float part = 0.f;
#pragma unroll
    for (int q = 0; q < 4; ++q) {
        float4 x = ld4h(tp + q * 4);
        float4 w = *(const float4*)(Wp2 + c0 + q * 4);
        int c = c0 + q * 4;
        part = fmaf(fmaxf(fmaf(x.x, sC_s[c + 0], sC_c[c + 0]), 0.f), w.x, part);
        part = fmaf(fmaxf(fmaf(x.y, sC_s[c + 1], sC_c[c + 1]), 0.f), w.y, part);
        part = fmaf(fmaxf(fmaf(x.z, sC_s[c + 2], sC_c[c + 2]), 0.f), w.z, part);
        part = fmaf(fmaxf(fmaf(x.w, sC_s[c + 3], sC_c[c + 3]), 0.f), w.w, part);
    }
    red[tid] = part;
    __syncthreads();
    if ((tid & 7) == 0) {
        float dot = red[tid] + red[tid+1] + red[tid+2] + red[tid+3]
                  + red[tid+4] + red[tid+5] + red[tid+6] + red[tid+7];
        dotbuf[row] = dot;
        if (row < valid) t4[r0 + row] = dot;
    }
    __syncthreads();
    if (tid == 0) {
        float S = 0.f, Q = 0.f;
        for (int r = 0; r < valid; ++r) { float d = dotbuf[r]; S += d; Q += d * d; }
        atomicAdd(&stats_out[0], S);
        atomicAdd(&stats_out[EMBD], Q);
    }
}

// ============================================================= k_pos_aggr
// PERM=1: t4/srcp permuted (streaming). PERM=0: rc tier via eidx.
template<int PERM>
__global__ __launch_bounds__(256) void k_pos_aggr(
    const float* __restrict__ t4, const int* __restrict__ offs,
    const int* __restrict__ eidx, const int* __restrict__ srcp,
    const int* __restrict__ srcI,
    const float* __restrict__ pos, const float* __restrict__ stats_base,
    const float* gp2, const float* bbp2,
    float* __restrict__ x_aggr, float* trace, float bit, int E, int Nn)
{
    trace_mark(trace, bit);
    const int tid = threadIdx.x;
    const int lane = tid & 63;
    const int node = blockIdx.x * 4 + (tid >> 6);
    if (node >= Nn) return;

    const float invE = 1.f / (float)E;
    float m = stats_base[768] * invE;
    float v = fmaxf(stats_base[768 + EMBD] * invE - m * m, 0.f);
    float s3 = gp2[0] * rsqrtf(v + BN_EPS);
    float c3 = bbp2[0] - m * s3;

    const int o0 = offs[node], o1 = offs[node + 1];
    float2 pi = *(const float2*)(pos + (size_t)node * 2);
    float ax = 0.f, ay = 0.f;
    for (int k = o0 + lane; k < o1; k += 64) {
        float s; int j;
        if (PERM) {
            s = fmaxf(fmaf(t4[k], s3, c3), 0.f);
            j = srcp[k];
        } else {
            int e = eidx[k];
            s = fmaxf(fmaf(t4[e], s3, c3), 0.f);
            j = srcI[e];
            if ((u32)j >= (u32)Nn) j = 0;
        }
        float2 pj = *(const float2*)(pos + (size_t)j * 2);
        ax += (pj.x - pi.x) * s;
        ay += (pj.y - pi.y) * s;
    }
#pragma unroll
    for (int off = 32; off; off >>= 1) {
        ax += __shfl_down(ax, off, 64);
        ay += __shfl_down(ay, off, 64);
    }
    if (lane == 0) {
        float inv = 1.f / fmaxf((float)(o1 - o0), 1.f);
        *(float2*)(x_aggr + (size_t)node * 2) = make_float2(ax * inv, ay * inv);
    }
}

// ============================================================== k_edge_rc
// Recompute tier (small ws) — original edge order, unchanged from R11.
template<int DEPTH>
__global__ __launch_bounds__(256) void k_edge_rc(
    const f16* __restrict__ uv,
    const int* __restrict__ srcI, const int* __restrict__ dstI,
    const float* __restrict__ pos,
    const float* __restrict__ W1, const float* __restrict__ W2,
    const float* __restrict__ W3, const float* __restrict__ Wp2,
    const float* g1, const float* b1, const float* g2, const float* b2,
    const float* g3, const float* b3,
    const float* __restrict__ stats_base, float* stats_out,
    float* h_aggr, float* t4_out,
    float* trace, float bit, int E, int Nn)
{
    trace_mark(trace, bit);
    __shared__ float XsT[KC][TE];
    __shared__ float Ws[KC][EMBD];
    __shared__ float A[(DEPTH >= 3) ? TE : 1][EMBD + 4];
    __shared__ float part_s[8][EMBD];
    __shared__ float part_q[8][EMBD];
    __shared__ float red[(DEPTH >= 4) ? 256 : 1];
    __shared__ float dotbuf[(DEPTH >= 4) ? TE : 1];
    __shared__ float sA_s[EMBD], sA_c[EMBD];
    __shared__ float sB_s[(DEPTH >= 3) ? EMBD : 1], sB_c[(DEPTH >= 3) ? EMBD : 1];
    __shared__ float sC_s[(DEPTH >= 4) ? EMBD : 1], sC_c[(DEPTH >= 4) ? EMBD : 1];
    __shared__ int dst_s[TE], src_s[TE];
    __shared__ float dist_s[TE];

    const int tid = threadIdx.x;
    const int r0 = blockIdx.x * TE;
    int valid = E - r0; if (valid > TE) valid = TE;

    if (tid < EMBD) {
        const float invE = 1.f / (float)E;
        LOAD_AFF(stats_base, g1, b1, sA_s, sA_c, invE);
        if (DEPTH >= 3) LOAD_AFF(stats_base + 256, g2, b2, sB_s, sB_c, invE);
        if (DEPTH >= 4) LOAD_AFF(stats_base + 512, g3, b3, sC_s, sC_c, invE);
    }
    EDGE_META(1);
    __syncthreads();

    const int e_st = tid >> 3, kl = (tid & 7) << 2;
    const int kw = tid >> 3, cw = (tid & 7) << 4;
    const int e4 = (tid >> 5) << 2, c4 = (tid & 31) << 2;
    const int grp = tid >> 5;

    float acc[4][4];
#pragma unroll
    for (int i = 0; i < 4; ++i)
#pragma unroll
        for (int j = 0; j < 4; ++j) acc[i][j] = 0.f;

    for (int k0 = 0; k0 < EMBD; k0 += KC) {
        REBUILD_XST(k0);
        STAGE_W(W2, k0);
        __syncthreads();
        MMA32();
        __syncthreads();
    }

    if (DEPTH == 2) { STATS_TO(stats_out); return; }

#pragma unroll
    for (int i = 0; i < 4; ++i) {
        float4 o;
#pragma unroll
        for (int j = 0; j < 4; ++j) {
            float v = fmaxf(fmaf(acc[i][j], sB_s[c4 + j], sB_c[c4 + j]), 0.f);
            (&o.x)[j] = v;
            if (DEPTH == 3 && (e4 + i) < valid)
                atomicAdd(&h_aggr[(size_t)dst_s[e4 + i] * EMBD + c4 + j], v);
        }
        *(float4*)&A[e4 + i][c4] = o;
    }
    __syncthreads();

#pragma unroll
    for (int i = 0; i < 4; ++i)
#pragma unroll
        for (int j = 0; j < 4; ++j) acc[i][j] = 0.f;
    for (int k0 = 0; k0 < EMBD; k0 += KC) {
        STAGE_W(W3, k0);
        __syncthreads();
#pragma unroll 8
        for (int kk = 0; kk < KC; ++kk) {
            float4 wv4 = *(const float4*)&Ws[kk][c4];
            float wv[4] = {wv4.x, wv4.y, wv4.z, wv4.w};
            float xv[4];
#pragma unroll
            for (int i = 0; i < 4; ++i) xv[i] = A[e4 + i][k0 + kk];
#pragma unroll
            for (int i = 0; i < 4; ++i)
#pragma unroll
                for (int j = 0; j < 4; ++j) acc[i][j] = fmaf(xv[i], wv[j], acc[i][j]);
        }
        __syncthreads();
    }

    if (DEPTH == 3) { STATS_TO(stats_out); return; }

#pragma unroll
    for (int i = 0; i < 4; ++i) {
        float4 o;
#pragma unroll
        for (int j = 0; j < 4; ++j)
            (&o.x)[j] = fmaxf(fmaf(acc[i][j], sC_s[c4 + j], sC_c[c4 + j]), 0.f);
        *(float4*)&A[e4 + i][c4] = o;
    }
    __syncthreads();

    {
        const int row = tid >> 3, c0 = (tid & 7) << 4;
        float w[16];
        *(float4*)(w + 0)  = *(const float4*)(Wp2 + c0);
        *(float4*)(w + 4)  = *(const float4*)(Wp2 + c0 + 4);
        *(float4*)(w + 8)  = *(const float4*)(Wp2 + c0 + 8);
        *(float4*)(w + 12) = *(const float4*)(Wp2 + c0 + 12);
        float part = 0.f;
#pragma unroll
        for (int c = 0; c < 16; ++c) part = fmaf(A[row][c0 + c], w[c], part);
        red[tid] = part;
        __syncthreads();
        if ((tid & 7) == 0) {
            float dot = red[tid] + red[tid+1] + red[tid+2] + red[tid+3]
                      + red[tid+4] + red[tid+5] + red[tid+6] + red[tid+7];
            dotbuf[row] = dot;
            if (row < valid) t4_out[r0 + row] = dot;
        }
        __syncthreads();
        if (tid == 0) {
            float S = 0.f, Q = 0.f;
            for (int r = 0; r < valid; ++r) { float d = dotbuf[r]; S += d; Q += d * d; }
            atomicAdd(&stats_out[0], S);
            atomicAdd(&stats_out[EMBD], Q);
        }
    }
}

// =============================================================== node GEMM
__global__ __launch_bounds__(256) void k_upd(
    const float* h, const float* h_aggr, const float* W,
    float* stats_out, float* t5, float* trace, float bit, int Nn)
{
    trace_mark(trace, bit);
    __shared__ float XsT[KC][TE];
    __shared__ float Ws[KC][EMBD];
    __shared__ float part_s[8][EMBD];
    __shared__ float part_q[8][EMBD];

    const int tid = threadIdx.x;
    const int r0 = blockIdx.x * TE;
    int valid = Nn - r0; if (valid > TE) valid = TE;

    float acc[4][4];
#pragma unroll
    for (int i = 0; i < 4; ++i)
#pragma unroll
        for (int j = 0; j < 4; ++j) acc[i][j] = 0.f;

    const int e_st = tid >> 3, kl = (tid & 7) << 2;
    const int kw = tid >> 3, cw = (tid & 7) << 4;
    const int e4 = (tid >> 5) << 2, c4 = (tid & 31) << 2;
    const int grp = tid >> 5;

    for (int k0 = 0; k0 < 2 * EMBD; k0 += KC) {
        {
            float4 x = make_float4(0.f, 0.f, 0.f, 0.f);
            if (e_st < valid) {
                int k = k0 + kl;
                int row = r0 + e_st;
                const float* base = (k < EMBD)
                    ? h + (size_t)row * EMBD + k
                    : h_aggr + (size_t)row * EMBD + (k - EMBD);
                x = *(const float4*)base;
            }
            XsT[kl + 0][e_st] = x.x; XsT[kl + 1][e_st] = x.y;
            XsT[kl + 2][e_st] = x.z; XsT[kl + 3][e_st] = x.w;
        }
        STAGE_W(W, k0);
        __syncthreads();
        MMA32();
        __syncthreads();
    }

    STATS_TO(stats_out);

#pragma unroll
    for (int i = 0; i < 4; ++i) {
        int row = r0 + e4 + i;
        if (e4 + i < valid)
            *(float4*)(t5 + (size_t)row * EMBD + c4) =
                make_float4(acc[i][0], acc[i][1], acc[i][2], acc[i][3]);
    }
}

// ---------------------------------------------------------------- epilogue
__global__ __launch_bounds__(256) void k_final(
    const float* h, const float* pos, const float* stats5,
    const float* gu1, const float* bbu1,
    const float* x_aggr, const float* trace,
    float* out, int N, float expect)
{
    __shared__ float s4[EMBD], cc4[EMBD];
    int tid = threadIdx.x;
    if (tid < EMBD) {
        const float invN = 1.f / (float)N;
        float m = stats5[tid] * invN;
        float v = fmaxf(stats5[EMBD + tid] * invN - m * m, 0.f);
        float s = gu1[tid] * rsqrtf(v + BN_EPS);
        s4[tid] = s; cc4[tid] = bbu1[tid] - m * s;
    }
    __syncthreads();
    int n = blockIdx.x * 2 + (tid >> 7);
    int c = tid & 127;
    if (n >= N) return;
    float hv = h[(size_t)n * EMBD + c];
    float t = out[(size_t)n * EMBD + c];
    float res = sane(hv + fmaxf(fmaf(t, s4[c], cc4[c]), 0.f), 100.f);
    if (n == 0 && c == 1) {
        float tr = trace[0];
        if (fabsf(tr - expect) > 0.5f) res = 1048576.0f + tr * 64.0f;
    }
    out[(size_t)n * EMBD + c] = res;
    if (c < 2) {
        float p = pos[(size_t)n * 2 + c];
        float xa = x_aggr[(size_t)n * 2 + c];
        out[(size_t)N * EMBD + (size_t)n * 2 + c] = sane(p + xa, 100.f);
    }
}

// ================================================================= launch
extern "C" void kernel_launch(void* const* d_in, const int* in_sizes, int n_in,
                              void* d_out, int out_size, void* d_ws, size_t ws_size,
                              hipStream_t stream)
{
    const float* h   = (const float*)d_in[0];
    const float* pos = (const float*)d_in[1];
    const int* ei    = (const int*)d_in[3];
    const float* Wm1 = (const float*)d_in[4];
    const float* gm1 = (const float*)d_in[6];
    const float* bbm1= (const float*)d_in[7];
    const float* Wm2 = (const float*)d_in[8];
    const float* gm2 = (const float*)d_in[10];
    const float* bbm2= (const float*)d_in[11];
    const float* Wp1 = (const float*)d_in[12];
    const float* gp1 = (const float*)d_in[14];
    const float* bbp1= (const float*)d_in[15];
    const float* Wp2 = (const float*)d_in[16];
    const float* gp2 = (const float*)d_in[18];
    const float* bbp2= (const float*)d_in[19];
    const float* Wu1 = (const float*)d_in[20];
    const float* gu1 = (const float*)d_in[22];
    const float* bbu1= (const float*)d_in[23];

    const int N = in_sizes[0] / EMBD;
    const int E = in_sizes[3] / 2;
    const int* srcI = ei;
    const int* dstI = ei + E;

    size_t off = 0;
    auto carve = [&](size_t bytes) -> size_t {
        size_t o = off; off += (bytes + 255) & ~(size_t)255; return o;
    };
    size_t o_stats  = carve(5 * 256 * sizeof(float));
    size_t o_trace  = carve(256);
    size_t o_cnti   = carve((size_t)N * sizeof(int));
    size_t zero_small = off;
    size_t o_haggr  = carve((size_t)N * EMBD * sizeof(float));
    size_t zero_need = off;                                  // ~25.9 MB
    size_t o_xaggr  = carve((size_t)N * 2 * sizeof(float));
    size_t o_t4     = carve((size_t)E * sizeof(float));
    size_t o_offs   = carve((size_t)(N + 1) * sizeof(int));
    size_t o_cursor = carve((size_t)N * sizeof(int));
    size_t o_eidx   = carve((size_t)E * sizeof(int));
    size_t o_srcp   = carve((size_t)E * sizeof(int));
    size_t o_dstp   = carve((size_t)E * sizeof(int));
    size_t o_wtf2   = carve(16384 * sizeof(f16));
    size_t o_wtf3   = carve(16384 * sizeof(f16));
    size_t base_need = off;                                  // ~35 MB
    size_t o_ebuf   = carve((size_t)E * EMBD * sizeof(f16)); // +128 MB
    size_t need_staged = off;

    float* out_f = (float*)d_out;

    if (ws_size < base_need) {
        k_fill<<<(out_size + 255) / 256, 256, 0, stream>>>(out_f, 12345678.0f, out_size);
        return;
    }

    char* wsb = (char*)d_ws;
    float* stats  = (float*)(wsb + o_stats);
    float* trace  = (float*)(wsb + o_trace);
    int*   cnti   = (int*)(wsb + o_cnti);
    float* h_aggr = (float*)(wsb + o_haggr);
    float* x_aggr = (float*)(wsb + o_xaggr);
    float* t4     = (float*)(wsb + o_t4);
    int*   offs   = (int*)(wsb + o_offs);
    int*   cursor = (int*)(wsb + o_cursor);
    int*   eidx   = (int*)(wsb + o_eidx);
    int*   srcp   = (int*)(wsb + o_srcp);
    int*   dstp   = (int*)(wsb + o_dstp);
    f16*   wtf2   = (f16*)(wsb + o_wtf2);
    f16*   wtf3   = (f16*)(wsb + o_wtf3);
    f16*   uv     = (f16*)d_out;   // N*256 fp16 = N*512B <= out bytes

    const bool staged = (ws_size >= need_staged);
    // staged path: h_aggr fully overwritten by k_aggr -> skip its memset
    hipMemsetAsync(d_ws, 0, staged ? zero_small : zero_need, stream);

    const int gPE  = (E + 255) / 256;
    const int gE   = (E + TE - 1) / TE;
    const int gE64 = (E + 63) / 64;
    const int gN   = (N + TE - 1) / TE;
    const int gS1  = (E + 127) / 128;
    const int gW   = (N + 3) / 4;

    k_uv<<<gN, 256, 0, stream>>>(h, Wm1, uv, trace, 1.0f, N);
    k_count<<<gPE, 256, 0, stream>>>(dstI, cnti, trace, 2.0f, E, N);
    k_scan<<<1, 1024, 0, stream>>>(cnti, offs, cursor, trace, 4.0f, N);
    k_scatter<<<gPE, 256, 0, stream>>>(srcI, dstI, cursor, eidx, srcp, dstp,
                                       trace, 8.0f, E, N);
    k_stats1<<<gS1, 256, 0, stream>>>(uv, pos, srcp, dstp, Wm1,
                                      stats, trace, 16.0f, E, N);

    if (staged) {
        f16* eb = (f16*)(wsb + o_ebuf);
        k_prep<<<64, 256, 0, stream>>>(Wm2, Wp1, wtf2, wtf3, trace, 32.0f);
        k_g2m<<<gE64, 256, 0, stream>>>(uv, srcp, dstp, pos, Wm1, wtf2,
                                        gm1, bbm1, stats, stats + 256,
                                        eb, trace, 64.0f, E, N);
        k_aggr<<<gW, 256, 0, stream>>>(eb, offs, gm2, bbm2, stats + 256,
                                       h_aggr, trace, 128.0f, E, N);
        k_g3m<<<gE64, 256, 0, stream>>>(eb, wtf3, gm2, bbm2,
                                        stats + 256, stats + 512,
                                        eb, trace, 256.0f, E);
        k_dot<<<gE, 256, 0, stream>>>(eb, Wp2, gp1, bbp1,
                                      stats + 512, stats + 768, t4,
                                      trace, 512.0f, E);
        k_pos_aggr<1><<<gW, 256, 0, stream>>>(t4, offs, eidx, srcp, srcI, pos,
                                              stats, gp2, bbp2, x_aggr,
                                              trace, 1024.0f, E, N);
    } else {
        k_edge_rc<2><<<gE, 256, 0, stream>>>(uv, srcI, dstI, pos,
                                             Wm1, Wm2, Wp1, Wp2,
                                             gm1, bbm1, gm2, bbm2, gp1, bbp1,
                                             stats, stats + 256, h_aggr, t4,
                                             trace, 32.0f, E, N);
        k_edge_rc<3><<<gE, 256, 0, stream>>>(uv, srcI, dstI, pos,
                                             Wm1, Wm2, Wp1, Wp2,
                                             gm1, bbm1, gm2, bbm2, gp1, bbp1,
                                             stats, stats + 512, h_aggr, t4,
                                             trace, 64.0f, E, N);
        k_edge_rc<4><<<gE, 256, 0, stream>>>(uv, srcI, dstI, pos,
                                             Wm1, Wm2, Wp1, Wp2,
                                             gm1, bbm1, gm2, bbm2, gp1, bbp1,
                                             stats, stats + 768, h_aggr, t4,
                                             trace, 128.0f, E, N);
        k_pos_aggr<0><<<gW, 256, 0, stream>>>(t4, offs, eidx, srcp, srcI, pos,
                                              stats, gp2, bbp2, x_aggr,
                                              trace, 1024.0f, E, N);
    }

    k_upd<<<gN, 256, 0, stream>>>(h, h_aggr, Wu1, stats + 1024, out_f,
                                  trace, 2048.0f, N);
    k_final<<<(N + 1) / 2, 256, 0, stream>>>(h, pos, stats + 1024, gu1, bbu1,
                                             x_aggr, trace, out_f, N,
                                             staged ? 4095.0f : 3327.0f);
}